// Round 5
// baseline (876.896 us; speedup 1.0000x reference)
//
#include <hip/hip_runtime.h>

// Problem constants
#define NB    128
#define NC    256
#define NPOS  196
#define NHEAD 8
#define NAG   49
#define YSTR  150528      // 768*196 per-batch y floats
#define VOFF  50176       // v_raw offset inside y (256*196)
#define QOFF  100352      // q_raw offset inside y (512*196)
#define SCL   0.17677669529663687f   // 32^-0.5

// Workspace layout (floats). Total = 38,885,440 floats = 155.5 MB.
#define WS_Y    0u
#define WS_V5   19267584u
#define WS_AT   25690112u
#define WS_ATK  27295744u
#define WS_CHG  28901376u
#define WS_CMAP 28934144u
#define WS_PBT  28966912u
#define WS_AB   29043744u
#define WS_X1S  29120576u
#define WS_AGV  29153344u
#define WS_XO   30758976u
#define WS_WT   37181504u
#define WS_CWT  37247040u   // Wh: 1.6M ushort (fp16 conv5 weights, [tap][co][ci])
// VA/VB (fp16 transposed v copies) live in the XO region: XO is only written
// by k_xo1/k_dwc, which launch AFTER the last reader (k_agentv). Stream order
// guarantees no overlap. VA = 6,422,528 ushorts, VB same.

typedef __attribute__((ext_vector_type(8))) _Float16 half8;
typedef __attribute__((ext_vector_type(8))) short short8;
typedef __attribute__((ext_vector_type(4))) short short4v;
typedef __attribute__((ext_vector_type(4))) float f32x4;
typedef unsigned short ushort_t;
typedef unsigned int uint_t;

__device__ __forceinline__ float sigmoidf_(float x){ return 1.0f/(1.0f+__expf(-x)); }

__device__ __forceinline__ ushort_t f2h(float x){
  _Float16 h = (_Float16)x; return __builtin_bit_cast(ushort_t, h);
}
__device__ __forceinline__ float h2f(ushort_t u){
  return (float)__builtin_bit_cast(_Float16, u);
}

// bilinear upsample 7x7 -> 14x14 sample at (i,j), matching reference grid()
__device__ __forceinline__ float bilin7(const float* __restrict__ src, int i, int j){
  float pi = fmaxf(0.5f*(float)i - 0.25f, 0.f);
  int i0 = (int)pi; if (i0 > 6) i0 = 6;
  int i1 = i0 + 1;  if (i1 > 6) i1 = 6;
  float li = pi - (float)i0;
  float pj = fmaxf(0.5f*(float)j - 0.25f, 0.f);
  int j0 = (int)pj; if (j0 > 6) j0 = 6;
  int j1 = j0 + 1;  if (j1 > 6) j1 = 6;
  float lj = pj - (float)j0;
  float v00 = src[i0*7+j0], v01 = src[i0*7+j1];
  float v10 = src[i1*7+j0], v11 = src[i1*7+j1];
  float t0 = v00*(1.f-lj) + v01*lj;
  float t1 = v10*(1.f-lj) + v11*lj;
  return t0*(1.f-li) + t1*li;
}

// 5x5 conv over a zero-padded [18][20] plane, producing one 14-wide output row r.
__device__ __forceinline__ void conv5x5_row(const float* __restrict__ plane, int r,
                                            const float* __restrict__ w25, float* acc14){
  #pragma unroll
  for (int di = 0; di < 5; ++di){
    const float4* pr = (const float4*)(plane + (r+di)*20);
    float4 p0 = pr[0], p1 = pr[1], p2 = pr[2], p3 = pr[3], p4 = pr[4];
    float row[20] = {p0.x,p0.y,p0.z,p0.w, p1.x,p1.y,p1.z,p1.w, p2.x,p2.y,p2.z,p2.w,
                     p3.x,p3.y,p3.z,p3.w, p4.x,p4.y,p4.z,p4.w};
    #pragma unroll
    for (int dj = 0; dj < 5; ++dj){
      float w = w25[di*5+dj];
      #pragma unroll
      for (int j = 0; j < 14; ++j) acc14[j] = fmaf(row[j+dj], w, acc14[j]);
    }
  }
}

// ---------- prep kernels ----------
__global__ void k_pb(const float* __restrict__ an, const float* __restrict__ ah,
                     const float* __restrict__ aw, float* __restrict__ PBT){
  int t = blockIdx.x*256 + threadIdx.x;
  if (t >= NHEAD*NPOS*NAG) return;
  int a = t % NAG;
  int r = t / NAG;
  int n = r % NPOS;
  int h = r / NPOS;
  int i = n/14, j = n - (n/14)*14;
  float v = bilin7(an + ((size_t)h*NAG + a)*49, i, j);
  v += ah[((size_t)h*NAG + a)*14 + i] + aw[((size_t)h*NAG + a)*14 + j];
  PBT[t] = v;   // [h][n][a]
}

__global__ void k_ab(const float* __restrict__ na, const float* __restrict__ ha,
                     const float* __restrict__ wa, float* __restrict__ AB){
  int t = blockIdx.x*256 + threadIdx.x;
  if (t >= NHEAD*NPOS*NAG) return;
  int a = t % NAG;
  int r = t / NAG;
  int n = r % NPOS;
  int h = r / NPOS;
  int i = n/14, j = n - (n/14)*14;
  float v = bilin7(na + ((size_t)h*NAG + a)*49, i, j);
  v += ha[((size_t)h*14 + i)*NAG + a] + wa[((size_t)h*14 + j)*NAG + a];
  AB[t] = v;    // [h][n][a]
}

__global__ void k_wt(const float* __restrict__ pw, float* __restrict__ WT){
  int t = blockIdx.x*256 + threadIdx.x;
  if (t >= 65536) return;
  int k = t >> 8, c = t & 255;
  WT[t] = pw[c*256 + k];          // WT[k][c] = proj_w[c][k]
}

// conv5 weights -> fp16, layout [tap][co][ci]
__global__ void k_cw2(const float* __restrict__ cw, ushort_t* __restrict__ Wh){
  int t = blockIdx.x*256 + threadIdx.x;
  if (t >= 1638400) return;
  int ci = t & 255;
  int r  = t >> 8;
  int co = r & 255;
  int tap = r >> 8;
  Wh[t] = f2h(cw[((size_t)co*256 + ci)*25 + tap]);
}

// ---------- lka depthwise-ish conv (groups=256, 3 outputs per input channel) ----------
__global__ __launch_bounds__(256) void k_lka(const float* __restrict__ x, const float* __restrict__ lw,
                                             const float* __restrict__ lb, float* __restrict__ Y){
  int b = blockIdx.x >> 3, gb = blockIdx.x & 7;
  int g0 = gb*32;                               // input channels [g0,g0+32)
  __shared__ __align__(16) float pl[32*360];    // [ch][18*20] padded planes
  int tid = threadIdx.x;
  for (int t = tid; t < 32*360; t += 256) pl[t] = 0.f;
  __syncthreads();
  for (int t = tid; t < 32*196; t += 256){
    int gl = t & 31, s = t >> 5;
    int i = s/14, j = s - i*14;
    pl[gl*360 + (i+2)*20 + j + 2] = x[((size_t)b*196 + s)*256 + g0 + gl];
  }
  __syncthreads();
  for (int t = tid; t < 96*14; t += 256){
    int ocl = t/14, r = t - ocl*14;
    int o  = g0*3 + ocl;          // output channel; uses input channel o/3
    int gl = ocl/3;
    float w25[25];
    #pragma unroll
    for (int u = 0; u < 25; ++u) w25[u] = lw[o*25 + u];
    float acc[14];
    float bv = lb[o];
    #pragma unroll
    for (int j = 0; j < 14; ++j) acc[j] = bv;
    conv5x5_row(&pl[gl*360], r, w25, acc);
    float* dst = Y + ((size_t)b*768 + o)*196 + r*14;
    #pragma unroll
    for (int j = 0; j < 14; ++j) dst[j] = acc[j];
  }
}

// ---------- dual fp16 transpose of the v region ----------
// VA[pos][ci] = v_raw[ci][pos]        (conv5 implicit-GEMM A operand layout)
// VB[c'][n']  = v_flat[n'*256 + c']   (transpose of the flat-[n][256] reshape
//                                      the reference applies; agentv pass1 B)
// which = bid&1 selects output; both halves load the full 50176-elem region.
__global__ __launch_bounds__(256) void k_vt(const float* __restrict__ Y,
    ushort_t* __restrict__ VA, ushort_t* __restrict__ VB){
  int b = blockIdx.x >> 1, which = blockIdx.x & 1;
  __shared__ ushort_t L[256*200];        // [ci][pos] fp16, pad to 200
  int tid = threadIdx.x;
  const float* src = Y + (size_t)b*YSTR + VOFF;
  for (int t = tid; t < 25088; t += 256){
    int f = 2*t;
    int ci = f/196, pos = f - ci*196;
    float2 v = *(const float2*)(src + f);
    *(uint_t*)&L[ci*200 + pos] = (uint_t)f2h(v.x) | ((uint_t)f2h(v.y) << 16);
  }
  __syncthreads();
  if (which == 0){
    // VA: [pos][ci], ushort8 chunks along ci
    for (int t = tid; t < 6272; t += 256){
      int pos = t >> 5, ck = (t & 31) << 3;
      short8 o;
      #pragma unroll
      for (int k = 0; k < 8; ++k) o[k] = (short)L[(ck+k)*200 + pos];
      *(short8*)(VA + (size_t)b*50176 + pos*256 + ck) = o;
    }
  } else {
    // VB: [c'][n'], ushort4 chunks along n' (196 = 49*4)
    for (int t = tid; t < 12544; t += 256){
      int cp = t / 49, n0 = (t - cp*49)*4;
      short4v o;
      #pragma unroll
      for (int k = 0; k < 4; ++k){
        int f = (n0+k)*256 + cp;
        int ci = f/196;
        o[k] = (short)L[ci*200 + (f - ci*196)];
      }
      *(short4v*)(VB + (size_t)b*50176 + cp*196 + n0) = o;
    }
  }
}

// ---------- conv5 via fp16 MFMA implicit GEMM ----------
// Round-4 structure (124.9us winner). A-staging now reads the pre-transposed
// fp16 VA[pos][ci]: one coalesced dwordx4 load + one b128 LDS store per item
// (was 8 scalar strided loads + 8 cvt + pack). Natural 80B-row addressing:
// 16B-slot of a b128 access at (row, chunk) is (5*row + chunk) mod 8.
__global__ __launch_bounds__(256, 2) void k_conv5(const ushort_t* __restrict__ VA,
    const ushort_t* __restrict__ Wh, const float* __restrict__ cb, float* __restrict__ V5){
  int b = blockIdx.x >> 2, cog = blockIdx.x & 3;
  int co0 = cog*64;
  __shared__ __align__(16) ushort_t Pt[360*40];     // fp16 A: [pos][4 chunks of 8ci + pad]
  __shared__ __align__(16) ushort_t Wsm[5*64*40];   // fp16 B: [tap-of-row][co][4 chunks + pad]
  __shared__ float T[32*200];                       // epilogue transpose
  int tid  = threadIdx.x;
  int lane = tid & 63, wv = tid >> 6;
  int mrow = lane & 15, quad = lane >> 4;

  // zero-fill Pt once; borders stay zero across chunks
  for (int t = tid; t < 7200; t += 256) ((uint_t*)Pt)[t] = 0;

  // per-lane A plane-row base per m-tile (unpadded base; taps add di*20+dj)
  int prow[4];
  #pragma unroll
  for (int mt = 0; mt < 4; ++mt){
    int s = wv*64 + mt*16 + mrow;
    int p0 = 0;
    if (s < 196){ int i = s/14, j = s - i*14; p0 = i*20 + j; }
    prow[mt] = p0;
  }

  f32x4 acc[4][4];
  #pragma unroll
  for (int mt = 0; mt < 4; ++mt)
    #pragma unroll
    for (int nt = 0; nt < 4; ++nt) acc[mt][nt] = (f32x4){0.f,0.f,0.f,0.f};

  const ushort_t* asrc = VA + (size_t)b*50176;    // [pos][ci] fp16
  int wco = tid >> 2, wpart = tid & 3;            // W-staging roles

  #pragma unroll 1
  for (int cc = 0; cc < 8; ++cc){
    __syncthreads();              // Pt free to overwrite (prev chunk's reads done)
    // stage A: 784 (pos, chunk) items; 1 dwordx4 load + 1 b128 store each.
    for (int t = tid; t < 784; t += 256){
      int pos = t >> 2, ch = t & 3;
      int i = pos/14, j = pos - i*14;
      int p = (i+2)*20 + j + 2;
      short8 pk = *(const short8*)(asrc + pos*256 + cc*32 + ch*8);
      *(short8*)&Pt[p*40 + ch*8] = pk;
    }
    #pragma unroll 1
    for (int di = 0; di < 5; ++di){
      __syncthreads();      // Wsm free to overwrite; also fences A writes (di=0)
      // stage W: taps di*5..di*5+4, 64 co x 32 ci fp16 each, natural layout
      #pragma unroll
      for (int tp = 0; tp < 5; ++tp){
        int tap = di*5 + tp;
        const short8 g = *(const short8*)(Wh + ((size_t)tap*256 + co0 + wco)*256 + cc*32 + wpart*8);
        *(short8*)&Wsm[(tp*64 + wco)*40 + wpart*8] = g;
      }
      __syncthreads();
      #pragma unroll
      for (int dj = 0; dj < 5; ++dj){
        half8 a[4], bb[4];
        #pragma unroll
        for (int nt = 0; nt < 4; ++nt){
          int co = nt*16 + mrow;
          bb[nt] = *(const half8*)&Wsm[(dj*64 + co)*40 + quad*8];
        }
        #pragma unroll
        for (int mt = 0; mt < 4; ++mt){
          int p = prow[mt] + di*20 + dj;
          a[mt] = *(const half8*)&Pt[p*40 + quad*8];
        }
        #pragma unroll
        for (int mt = 0; mt < 4; ++mt)
          #pragma unroll
          for (int nt = 0; nt < 4; ++nt)
            acc[mt][nt] = __builtin_amdgcn_mfma_f32_16x16x32_f16(a[mt], bb[nt], acc[mt][nt], 0, 0, 0);
      }
    }
  }

  // epilogue: transpose through LDS, then stores into scrambled v5
  #pragma unroll
  for (int hf = 0; hf < 2; ++hf){
    __syncthreads();
    #pragma unroll
    for (int ntl = 0; ntl < 2; ++ntl){
      int nt = hf*2 + ntl;
      int col = ntl*16 + mrow;            // co local within half (0..31)
      #pragma unroll
      for (int mt = 0; mt < 4; ++mt){
        int sbase = wv*64 + mt*16 + quad*4;
        #pragma unroll
        for (int r = 0; r < 4; ++r){
          int s = sbase + r;
          if (s < 196) T[col*200 + s] = acc[mt][nt][r];
        }
      }
    }
    __syncthreads();
    for (int t = tid; t < 6272; t += 256){
      int cl = t / 196;                   // co local 0..31
      int f = (co0 + hf*32)*196 + t;
      float val = T[t + cl*4] + cb[co0 + hf*32 + cl];
      V5[(size_t)b*50176 + (size_t)(f & 255)*196 + (f >> 8)] = val;
    }
  }
}

// ---------- agent token pooling: at = 2x2-mean of q_raw, atk = 2x2-max of k_raw ----------
__global__ __launch_bounds__(256) void k_pool(const float* __restrict__ Y, float* __restrict__ AT, float* __restrict__ ATK){
  int b = blockIdx.x; int c = threadIdx.x;
  const float* qp = Y + ((size_t)b*768 + 512 + c)*196;
  const float* kp = Y + ((size_t)b*768 + c)*196;
  for (int a = 0; a < 49; ++a){
    int p1 = a/7, p2 = a - p1*7;
    int s = p1*28 + p2*2;
    float q0 = qp[s], q1 = qp[s+1], q2 = qp[s+14], q3 = qp[s+15];
    AT[((size_t)b*49 + a)*256 + c] = 0.25f*(q0+q1+q2+q3);
    float k0 = kp[s], k1 = kp[s+1], k2 = kp[s+14], k3 = kp[s+15];
    ATK[((size_t)b*49 + a)*256 + c] = fmaxf(fmaxf(k0,k1), fmaxf(k2,k3));
  }
}

// ---------- fused cbam: channel gate + spatial gate, one kernel ----------
// Phase 1: coalesced load of V5[c][196] with in-flight per-channel sum/max
// (fp32, exact) and an fp16 LDS cache. Phase 2: channel MLPs -> chg[c].
// Phase 3: spatial mean/max over channels from the fp16 cache (mask input
// only -- precision impact negligible behind sigmoid). Phase 4: exact final
// gate from an fp32 re-read (L2-resident) * chg * mask, stored fp32.
__global__ __launch_bounds__(256) void k_cbam(float* __restrict__ V5,
    const float* __restrict__ caa1w, const float* __restrict__ caa1b,
    const float* __restrict__ caa2w, const float* __restrict__ caa2b,
    const float* __restrict__ cam1w, const float* __restrict__ cam1b,
    const float* __restrict__ cam2w, const float* __restrict__ cam2b,
    const float* __restrict__ saw, const float* __restrict__ sab){
  int b = blockIdx.x;
  __shared__ ushort_t vh[256*200];            // fp16 cache [c][pos]
  __shared__ float avg[256], mx[256], t1[16], t2[16], chg[256];
  __shared__ float mp[22*22], xp[22*22];
  __shared__ __align__(16) float mk[196];
  int tid = threadIdx.x, wv = tid >> 6, lane = tid & 63;
  float* v5b = V5 + (size_t)b*50176;

  for (int t = tid; t < 484; t += 256){ mp[t] = 0.f; xp[t] = 0.f; }

  // phase 1: load + per-channel stats (lane<49: 49*4 = 196 positions)
  for (int c = wv; c < 256; c += 4){
    float s, m;
    if (lane < 49){
      float4 v = *(const float4*)(v5b + c*196 + lane*4);
      s = v.x + v.y + v.z + v.w;
      m = fmaxf(fmaxf(v.x, v.y), fmaxf(v.z, v.w));
      short4v pk;
      pk[0] = (short)f2h(v.x); pk[1] = (short)f2h(v.y);
      pk[2] = (short)f2h(v.z); pk[3] = (short)f2h(v.w);
      *(short4v*)&vh[c*200 + lane*4] = pk;
    } else { s = 0.f; m = -1e30f; }
    #pragma unroll
    for (int off = 1; off < 64; off <<= 1){
      s += __shfl_xor(s, off);
      m = fmaxf(m, __shfl_xor(m, off));
    }
    if (lane == 0){ avg[c] = s*(1.0f/196.0f); mx[c] = m; }
  }
  __syncthreads();

  // phase 2: channel MLPs
  if (tid < 16){
    float a1 = caa1b[tid], a2 = cam1b[tid];
    #pragma unroll 4
    for (int k = 0; k < 256; ++k){
      a1 = fmaf(caa1w[(tid*256 + k)*9 + 4], avg[k], a1);   // 3x3 center tap
      a2 = fmaf(cam1w[tid*256 + k], mx[k], a2);            // 1x1
    }
    t1[tid] = fmaxf(a1, 0.f);
    t2[tid] = fmaxf(a2, 0.f);
  }
  __syncthreads();
  {
    float y1 = caa2b[tid], y2 = cam2b[tid];
    #pragma unroll
    for (int k = 0; k < 16; ++k){
      y1 = fmaf(caa2w[(tid*16 + k)*9 + 4], t1[k], y1);
      y2 = fmaf(cam2w[tid*16 + k], t2[k], y2);
    }
    chg[tid] = sigmoidf_(sigmoidf_(y1) + sigmoidf_(y2));
  }
  __syncthreads();

  // phase 3: spatial mean/max over channels (fp16 cache), pad, 9x9 conv
  if (tid < 196){
    int i = tid/14, j = tid - i*14;
    float s = 0.f, m = -1e30f;
    #pragma unroll 4
    for (int c = 0; c < 256; ++c){
      float v = chg[c] * h2f(vh[c*200 + tid]);
      s += v; m = fmaxf(m, v);
    }
    mp[(i+4)*22 + j+4] = s*(1.f/256.f);
    xp[(i+4)*22 + j+4] = m;
  }
  __syncthreads();
  if (tid < 196){
    int i = tid/14, j = tid - i*14;
    float acc = sab[0];
    for (int di = 0; di < 9; ++di){
      #pragma unroll
      for (int dj = 0; dj < 9; ++dj){
        acc = fmaf(mp[(i+di)*22 + j+dj], saw[di*9+dj], acc);
        acc = fmaf(xp[(i+di)*22 + j+dj], saw[81 + di*9+dj], acc);
      }
    }
    mk[tid] = sigmoidf_(acc);
  }
  __syncthreads();

  // phase 4: exact gate from fp32 re-read (L2-hot), store fp32
  for (int c = wv; c < 256; c += 4){
    if (lane < 49){
      float4 v = *(const float4*)(v5b + c*196 + lane*4);
      float4 mkv = *(const float4*)&mk[lane*4];
      float g = chg[c];
      v.x = g*v.x*mkv.x; v.y = g*v.y*mkv.y;
      v.z = g*v.z*mkv.z; v.w = g*v.w*mkv.w;
      *(float4*)(v5b + c*196 + lane*4) = v;
    }
  }
}

// ---------- big NxN attention via MFMA; only mean over n of x1 is needed ----------
// x1s[c] = (1/196) sum_j w[j] V[j][c],  w[j] = sum_n e[n][j] / l[n].
// Pass A: S^T tiles via mfma (A=K rows j, B=Q cols n); e = exp(S + rpb) stored
// fp16 in E[n][j]; l[n] reduced in-register (quad shfl). Then w via grouped
// column reduction of E weighted by 1/l, then a 196x32 matvec against V.
__global__ __launch_bounds__(512, 1) void k_attn2(const float* __restrict__ Y,
    const float* __restrict__ rpbt, float* __restrict__ X1S){
  int b = blockIdx.x >> 3, h = blockIdx.x & 7;
  __shared__ __align__(16) ushort_t Qh[208*32];    // fp16 q*SCL rows, chunk-swizzled
  __shared__ __align__(16) ushort_t Kh[208*32];    // fp16 k rows, chunk-swizzled
  __shared__ __align__(16) ushort_t E[196*208];    // fp16 exp-scores [n][j]
  __shared__ float rp[736];                        // rpb table for h (729 used)
  __shared__ int   rpo[208];                       // (j/14)*27 + j%14 (j clamped)
  __shared__ float lnn[208];
  __shared__ float invl[196];
  __shared__ float wj[208];
  __shared__ float wpart[14][208];
  __shared__ float xpart[16][32];
  int tid = threadIdx.x, wv = tid >> 6, lane = tid & 63;
  int mrow = lane & 15, quad = lane >> 4;
  int sw8 = ((quad ^ ((mrow >> 1) & 3)) << 3);     // 64B-row read swizzle
  const float* yb = Y + (size_t)b*YSTR;

  // ---- tables + staging ----
  for (int t = tid; t < 736; t += 512) rp[t] = (t < 729) ? rpbt[t*8 + h] : 0.f;
  for (int j = tid; j < 208; j += 512){
    int jc = (j < 196) ? j : 195;
    int rj = jc/14;
    rpo[j] = rj*27 + (jc - rj*14);
  }
  for (int t = tid; t < 384; t += 512){            // zero rows 196..207 (12 rows x 16 uints x 2)
    int arr = t >= 192; int u = t - arr*192;
    ((uint_t*)(arr ? Kh : Qh))[3136 + u] = 0;
  }
  for (int t = tid; t < 3136; t += 512){
    int n = t >> 4, w = t & 15;
    int ws = (((w >> 2) ^ ((n >> 1) & 3)) << 2) | (w & 3);
    const float2 qv = *(const float2*)(yb + QOFF + (size_t)n*256 + h*32 + (w << 1));
    ((uint_t*)Qh)[n*16 + ws] = (uint_t)f2h(qv.x*SCL) | ((uint_t)f2h(qv.y*SCL) << 16);
    const float2 kv = *(const float2*)(yb + (size_t)n*256 + h*32 + (w << 1));
    ((uint_t*)Kh)[n*16 + ws] = (uint_t)f2h(kv.x) | ((uint_t)f2h(kv.y) << 16);
  }
  __syncthreads();

  // ---- pass A: e + E-store + row sums l[n] ----
  #pragma unroll 1
  for (int nc = wv; nc < 13; nc += 8){
    int n = nc*16 + mrow;                          // B col (query index)
    half8 bfr = *(const half8*)&Qh[n*32 + sw8];
    int nclamp = (n < 196) ? n : 195;
    int rin = nclamp/14, cin = nclamp - rin*14;
    int bidxn = (rin + 13)*27 + (cin + 13);
    float lsum = 0.f;
    #pragma unroll 1
    for (int mt = 0; mt < 13; ++mt){
      half8 afr = *(const half8*)&Kh[(mt*16 + mrow)*32 + sw8];
      f32x4 c = (f32x4){0.f,0.f,0.f,0.f};
      c = __builtin_amdgcn_mfma_f32_16x16x32_f16(afr, bfr, c, 0, 0, 0);
      int j0 = mt*16 + quad*4;
      int4 ro = *(const int4*)&rpo[j0];
      short4v pk;
      #pragma unroll
      for (int r = 0; r < 4; ++r){
        int j = j0 + r;
        int roff = (r == 0) ? ro.x : (r == 1) ? ro.y : (r == 2) ? ro.z : ro.w;
        float e = (j < 196) ? __expf(c[r] + rp[bidxn - roff]) : 0.f;
        lsum += e;
        pk[r] = (short)f2h(e);
      }
      if (n < 196) *(short4v*)&E[n*208 + j0] = pk;
    }
    lsum += __shfl_xor(lsum, 16);
    lsum += __shfl_xor(lsum, 32);
    if (quad == 0) lnn[n] = lsum;
  }
  __syncthreads();
  for (int n = tid; n < 196; n += 512) invl[n] = 1.f/lnn[n];
  __syncthreads();

  // ---- w[j] = sum_n E[n][j]*invl[n]: 14 groups of 32 lanes, 14 n's each ----
  {
    int g = tid >> 5, lj = tid & 31;
    int j0 = lj*8;
    if (g < 14 && j0 < 208){
      float a0=0.f,a1=0.f,a2=0.f,a3=0.f,a4=0.f,a5=0.f,a6=0.f,a7=0.f;
      #pragma unroll 1
      for (int u = 0; u < 14; ++u){
        int n = g*14 + u;
        float iv = invl[n];
        short8 ev = *(const short8*)&E[n*208 + j0];
        a0 = fmaf(h2f((ushort_t)ev[0]), iv, a0);
        a1 = fmaf(h2f((ushort_t)ev[1]), iv, a1);
        a2 = fmaf(h2f((ushort_t)ev[2]), iv, a2);
        a3 = fmaf(h2f((ushort_t)ev[3]), iv, a3);
        a4 = fmaf(h2f((ushort_t)ev[4]), iv, a4);
        a5 = fmaf(h2f((ushort_t)ev[5]), iv, a5);
        a6 = fmaf(h2f((ushort_t)ev[6]), iv, a6);
        a7 = fmaf(h2f((ushort_t)ev[7]), iv, a7);
      }
      *(f32x4*)&wpart[g][j0]   = (f32x4){a0,a1,a2,a3};
      *(f32x4*)&wpart[g][j0+4] = (f32x4){a4,a5,a6,a7};
    }
  }
  __syncthreads();
  for (int j = tid; j < 208; j += 512){
    float s = 0.f;
    #pragma unroll
    for (int g2 = 0; g2 < 14; ++g2) s += wpart[g2][j];
    wj[j] = (j < 196) ? s : 0.f;
  }
  __syncthreads();

  // ---- X1S[c] = (1/196) sum_j wj[j] * V[j][c] ----
  {
    int d = tid & 31, g = tid >> 5;                // 16 groups x 13 j's
    float s = 0.f;
    #pragma unroll 1
    for (int u = 0; u < 13; ++u){
      int j = g*13 + u;
      s = fmaf(wj[j], yb[VOFF + (size_t)j*256 + h*32 + d], s);
    }
    xpart[g][d] = s;
  }
  __syncthreads();
  if (tid < 32){
    float s = 0.f;
    #pragma unroll
    for (int g2 = 0; g2 < 16; ++g2) s += xpart[g2][tid];
    X1S[(size_t)b*256 + h*32 + tid] = s*(1.f/196.f);
  }
}

// ---------- chan_inter on x1 mean -> sigmoid gate CMAP ----------
__global__ __launch_bounds__(256) void k_cinter(const float* __restrict__ X1S,
    const float* __restrict__ ci1w, const float* __restrict__ ci1b,
    const float* __restrict__ bng, const float* __restrict__ bnb,
    const float* __restrict__ ci2w, const float* __restrict__ ci2b, float* __restrict__ CMAP){
  int b = blockIdx.x, c = threadIdx.x;
  __shared__ float p[256], tt[16];
  p[c] = X1S[b*256 + c];
  __syncthreads();
  if (c < 16){
    float a = ci1b[c];
    #pragma unroll 4
    for (int k = 0; k < 256; ++k) a = fmaf(ci1w[(c*256+k)*25 + 12], p[k], a);  // 5x5 center
    const float invs = 0.9999950000375f;   // 1/sqrt(1+1e-5)
    tt[c] = fmaxf(fmaf(bng[c]*invs, a, bnb[c]), 0.f);
  }
  __syncthreads();
  float a = ci2b[c];
  #pragma unroll
  for (int k = 0; k < 16; ++k) a = fmaf(ci2w[(c*16+k)*25 + 12], tt[k], a);
  CMAP[b*256 + c] = sigmoidf_(a);
}

// ---------- agent_v via fp16 MFMA ----------
// Kh/Ah rows are 64B (even stride): reads use a bijective chunk swizzle
// chunk ^= (row>>1)&3 (write side mirrors it) so an 8-lane b128 phase hits
// 8 distinct 16B slots. Pass1 V now staged from the pre-transposed VB
// (coalesced uint copies, no cvt, no strided scalar gather).
__global__ __launch_bounds__(256) void k_agentv(const float* __restrict__ Y, const float* __restrict__ V5,
    const ushort_t* __restrict__ VB,
    const float* __restrict__ AT, const float* __restrict__ ATK,
    const float* __restrict__ PBT, float* __restrict__ AGV){
  int b = blockIdx.x >> 3, h = blockIdx.x & 7;
  __shared__ __align__(16) ushort_t ST[64*232];   // exp-scores, [a][n pad 232]
  __shared__ __align__(16) ushort_t R[8704];      // staging region (17408 B)
  __shared__ float psum[4*64];
  __shared__ float inv0s[64], inv1s[64];
  int tid = threadIdx.x, wv = tid >> 6, lane = tid & 63;
  int mrow = lane & 15, quad = lane >> 4;
  int sw8 = ((quad ^ ((mrow >> 1) & 3)) << 3);    // read-side chunk swizzle (rows = 16*t + mrow)
  const float* yb = Y + (size_t)b*YSTR;
  ushort_t* Kh = R;            // [208][32] fp16 rows (K or Q), chunk-swizzled
  ushort_t* Ah = R + 6656;     // [64][32] fp16 rows (AT or ATK), chunk-swizzled
  ushort_t* Vt = R;            // [32][232] fp16 rows (V1 or V)
  f32x4 out0[2], out1[2];

  // ---- one-time zero fills: ST cols 208..223 (cols 224-231 never read) ----
  for (int t = tid; t < 512; t += 256){      // 64 rows x 16 cols /2 per uint
    int a = t >> 3, c2 = 208 + ((t & 7) << 1);
    *(uint_t*)&ST[a*232 + c2] = 0;
  }

  #pragma unroll 1
  for (int pass = 0; pass < 2; ++pass){
    // ---- stage rows (K|Q into Kh; AT|ATK into Ah), zero pads ----
    for (int t = tid; t < 192; t += 256) ((uint_t*)Kh)[3136 + t] = 0;   // rows 196-207
    for (int t = tid; t < 240; t += 256) ((uint_t*)Ah)[784 + t] = 0;    // rows 49-63
    {
      const float* rsrc = yb + (pass ? QOFF : 0) + h*32;
      for (int t = tid; t < 3136; t += 256){
        int n = t >> 4, w = t & 15;
        const float2 v = *(const float2*)(rsrc + (size_t)n*256 + (w << 1));
        int ws = (((w >> 2) ^ ((n >> 1) & 3)) << 2) | (w & 3);
        ((uint_t*)Kh)[n*16 + ws] = (uint_t)f2h(v.x) | ((uint_t)f2h(v.y) << 16);
      }
      const float* asrc = (pass ? ATK : AT) + (size_t)b*49*256 + h*32;
      for (int t = tid; t < 784; t += 256){
        int a = t >> 4, w = t & 15;
        const float2 v = *(const float2*)(asrc + (size_t)a*256 + (w << 1));
        int ws = (((w >> 2) ^ ((a >> 1) & 3)) << 2) | (w & 3);
        ((uint_t*)Ah)[a*16 + ws] = (uint_t)f2h(v.x) | ((uint_t)f2h(v.y) << 16);
      }
    }
    __syncthreads();
    // ---- logits: ntile = wv; 13 mtiles; exp(+pb) -> ST[a][n] ----
    {
      float lscl = pass ? 0.03125f : SCL;
      int ag = wv*16 + mrow;                 // agent (C col)
      half8 bfr = *(const half8*)&Ah[ag*32 + sw8];
      #pragma unroll 1
      for (int mt = 0; mt < 13; ++mt){
        half8 afr = *(const half8*)&Kh[(mt*16 + mrow)*32 + sw8];
        f32x4 c = (f32x4){0.f,0.f,0.f,0.f};
        c = __builtin_amdgcn_mfma_f32_16x16x32_f16(afr, bfr, c, 0, 0, 0);
        int n0 = mt*16 + quad*4;
        short4v pk;
        #pragma unroll
        for (int r = 0; r < 4; ++r){
          int n = n0 + r;
          float pb = PBT[((size_t)h*196 + n)*49 + ag];
          float e = (n < 196) ? __expf(fmaf(c[r], lscl, pb)) : 0.f;
          pk[r] = (short)f2h(e);
        }
        *(short4v*)&ST[ag*232 + n0] = pk;
      }
    }
    __syncthreads();
    // ---- denominators + stage V ----
    {
      int a = tid >> 2, q = tid & 3;
      float s = 0.f;
      #pragma unroll
      for (int u = 0; u < 7; ++u){
        short8 v8 = *(const short8*)&ST[a*232 + q*56 + u*8];
        #pragma unroll
        for (int e = 0; e < 8; ++e) s += h2f((ushort_t)v8[e]);
      }
      psum[q*64 + a] = s;
    }
    if (pass == 0){
      const float* vsrc = V5 + (size_t)b*50176 + h*32*196;   // [d][196]
      for (int t = tid; t < 3136; t += 256){
        int d = t / 98, np = t - (t/98)*98;
        const float2 v = *(const float2*)(vsrc + (size_t)d*196 + 2*np);
        *(uint_t*)&Vt[d*232 + 2*np] = (uint_t)f2h(v.x) | ((uint_t)f2h(v.y) << 16);
      }
    } else {
      const ushort_t* vsrc = VB + (size_t)b*50176 + (h*32)*196;  // [d][196] fp16
      for (int t = tid; t < 3136; t += 256){
        int d = t / 98, np = t - (t/98)*98;
        *(uint_t*)&Vt[d*232 + 2*np] = *(const uint_t*)(vsrc + d*196 + 2*np);
      }
    }
    for (int t = tid; t < 448; t += 256){    // zero V cols 196..223
      int d = t / 14, c2 = 196 + 2*(t - (t/14)*14);
      *(uint_t*)&Vt[d*232 + c2] = 0;
    }
    __syncthreads();
    // ---- PV: mtile = wv (a rows); ntile 0..1 (d cols); 7 k-steps ----
    {
      f32x4* outp = pass ? out1 : out0;
      #pragma unroll
      for (int nt = 0; nt < 2; ++nt){
        f32x4 c = (f32x4){0.f,0.f,0.f,0.f};
        #pragma unroll
        for (int ks = 0; ks < 7; ++ks){
          half8 afr = *(const half8*)&ST[(wv*16 + mrow)*232 + ks*32 + quad*8];
          half8 bfr = *(const half8*)&Vt[(nt*16 + mrow)*232 + ks*32 + quad*8];
          c = __builtin_amdgcn_mfma_f32_16x16x32_f16(afr, bfr, c, 0, 0, 0);
        }
        outp[nt] = c;
      }
      if (tid < 64){
        float s = psum[tid] + psum[64+tid] + psum[128+tid] + psum[192+tid];
        float* invp = pass ? inv1s : inv0s;
        invp[tid] = 1.f / s;
      }
    }
    __syncthreads();   // ST/Vt free for next pass; inv visible
  }
  // ---- epilogue: combine + scatter ----
  #pragma unroll
  for (int nt = 0; nt < 2; ++nt){
    int d = nt*16 + mrow;
    #pragma unroll
    for (int r = 0; r < 4; ++r){
      int a = wv*16 + quad*4 + r;
      if (a < 49)
        AGV[(((size_t)(b*8 + h)*49) + a)*32 + d] = out0[nt][r]*inv0s[a] + out1[nt][r]*inv1s[a];
    }
  }
}

// ---------- xo1 via fp16 MFMA ----------
// Per (b,h), pass p in {q,k}: S[196][49] = rows . agents^T (one 16x16x32 MFMA
// per tile, K=32 exact); e = exp(S*lscl + AB) -> ST[n][a] fp16 (stride 72);
// row sums -> invs[n]; out[196][32] += invs[n] * (ST . AGV^T) (K=64, 2 steps).
// Kh/Ah use the 64B-row chunk swizzle; AGVt rows are 128B: chunk ^= row&7.
__global__ __launch_bounds__(256) void k_xo1(const float* __restrict__ Y,
    const float* __restrict__ AT, const float* __restrict__ ATK,
    const float* __restrict__ AB, const float* __restrict__ AGV, float* __restrict__ XO){
  int b = blockIdx.x >> 3, h = blockIdx.x & 7;
  __shared__ __align__(16) ushort_t ST[208*72];   // exp-scores [n][a pad 72]
  __shared__ __align__(16) ushort_t Kh[208*32];   // Q or K rows fp16, chunk-swizzled
  __shared__ __align__(16) ushort_t Ah[64*32];    // AT or ATK rows fp16, chunk-swizzled
  __shared__ __align__(16) ushort_t AGVt[32*64];  // AGV^T [d][a], chunk-swizzled
  __shared__ float invs[208];
  int tid = threadIdx.x, wv = tid >> 6, lane = tid & 63;
  int mrow = lane & 15, quad = lane >> 4;
  int sw8 = ((quad ^ ((mrow >> 1) & 3)) << 3);    // 64B-row read swizzle
  const float* yb = Y + (size_t)b*YSTR;
  f32x4 acc[4][2];
  #pragma unroll
  for (int i = 0; i < 4; ++i){
    acc[i][0] = (f32x4){0.f,0.f,0.f,0.f};
    acc[i][1] = (f32x4){0.f,0.f,0.f,0.f};
  }

  // one-time: zero ST cols 48..63 (a-pad = K-dim of PV; col 48 rewritten by
  // logits each pass), stage AGV^T with a-pad zeros
  for (int t = tid; t < 1664; t += 256){
    int rw = t >> 3, c2 = 48 + ((t & 7) << 1);
    *(uint_t*)&ST[rw*72 + c2] = 0;
  }
  {
    const float* agvb = AGV + (size_t)(b*8 + h)*49*32;
    for (int t = tid; t < 2048; t += 256){
      int d = t >> 6, a = t & 63;
      int as = ((((a >> 3) ^ (d & 7)) & 7) << 3) | (a & 7);
      AGVt[d*64 + as] = (a < 49) ? f2h(agvb[a*32 + d]) : (ushort_t)0;
    }
  }

  #pragma unroll 1
  for (int pass = 0; pass < 2; ++pass){
    // ---- stage rows: pass0 = Q rows + AT agents; pass1 = K rows + ATK ----
    {
      const float* rsrc = yb + (pass ? 0 : QOFF) + h*32;
      for (int t = tid; t < 3136; t += 256){
        int n = t >> 4, w = t & 15;
        const float2 v = *(const float2*)(rsrc + (size_t)n*256 + (w << 1));
        int ws = (((w >> 2) ^ ((n >> 1) & 3)) << 2) | (w & 3);
        ((uint_t*)Kh)[n*16 + ws] = (uint_t)f2h(v.x) | ((uint_t)f2h(v.y) << 16);
      }
      const float* asrc = (pass ? ATK : AT) + (size_t)b*49*256 + h*32;
      for (int t = tid; t < 784; t += 256){
        int a = t >> 4, w = t & 15;
        const float2 v = *(const float2*)(asrc + (size_t)a*256 + (w << 1));
        int ws = (((w >> 2) ^ ((a >> 1) & 3)) << 2) | (w & 3);
        ((uint_t*)Ah)[a*16 + ws] = (uint_t)f2h(v.x) | ((uint_t)f2h(v.y) << 16);
      }
    }
    __syncthreads();
    // ---- logits: ag = wv*16+mrow (C col); 13 mtiles; e -> ST[n][ag] ----
    {
      float lscl = pass ? SCL : 0.03125f;
      int ag = wv*16 + mrow;
      half8 bfr = *(const half8*)&Ah[ag*32 + sw8];
      #pragma unroll 1
      for (int mt = 0; mt < 13; ++mt){
        half8 afr = *(const half8*)&Kh[(mt*16 + mrow)*32 + sw8];
        f32x4 c = (f32x4){0.f,0.f,0.f,0.f};
        c = __builtin_amdgcn_mfma_f32_16x16x32_f16(afr, bfr, c, 0, 0, 0);
        #pragma unroll
        for (int r = 0; r < 4; ++r){
          int n = mt*16 + quad*4 + r;
          if (n < 196 && ag < 49){
            float e = __expf(fmaf(c[r], lscl, AB[((size_t)h*196 + n)*49 + ag]));
            ST[n*72 + ag] = f2h(e);
          }
        }
      }
    }
    __syncthreads();
    // ---- row sums over agents -> invs[n] (cols 49..55 are zeros) ----
    if (tid < 196){
      float s = 0.f;
      #pragma unroll
      for (int u = 0; u < 7; ++u){
        short8 v8 = *(const short8*)&ST[tid*72 + u*8];
        #pragma unroll
        for (int e = 0; e < 8; ++e) s += h2f((ushort_t)v8[e]);
      }
      invs[tid] = 1.f / s;
    }
    __syncthreads();
    // ---- PV: wave strides mtiles; 2 ntiles x 2 ksteps; acc += c*invs[n] ----
    {
      int i = 0;
      #pragma unroll 1
      for (int mt = wv; mt < 13; mt += 4, ++i){
        #pragma unroll
        for (int nt = 0; nt < 2; ++nt){
          f32x4 c = (f32x4){0.f,0.f,0.f,0.f};
          #pragma unroll
          for (int ks = 0; ks < 2; ++ks){
            half8 afr = *(const half8*)&ST[(mt*16 + mrow)*72 + ks*32 + quad*8];
            half8 bfr = *(const half8*)&AGVt[(nt*16 + mrow)*64 + ((((ks*4 + quad) ^ (mrow & 7)) & 7) << 3)];
            c = __builtin_amdgcn_mfma_f32_16x16x32_f16(afr, bfr, c, 0, 0, 0);
          }
          #pragma unroll
          for (int r = 0; r < 4; ++r){
            int n = mt*16 + quad*4 + r;
            if (n < 196) acc[i][nt][r] = fmaf(c[r], invs[n], acc[i][nt][r]);
          }
        }
      }
    }
    __syncthreads();   // ST/Kh/Ah/invs free for next pass
  }
  // ---- store XO ----
  {
    int i = 0;
    #pragma unroll 1
    for (int mt = wv; mt < 13; mt += 4, ++i){
      #pragma unroll
      for (int nt = 0; nt < 2; ++nt){
        #pragma unroll
        for (int r = 0; r < 4; ++r){
          int n = mt*16 + quad*4 + r;
          if (n < 196)
            XO[((size_t)b*196 + n)*256 + h*32 + nt*16 + mrow] = acc[i][nt][r];
        }
      }
    }
  }
}

// ---------- fused depthwise conv: dwc(conv_x2 + qc), bias 2*dwc_b, accumulated into XO ----------
__global__ __launch_bounds__(256) void k_dwc(const float* __restrict__ Y, const float* __restrict__ CMAP,
    const float* __restrict__ dw, const float* __restrict__ db, float* __restrict__ XO){
  int b = blockIdx.x >> 3, cg = blockIdx.x & 7;
  int c0 = cg*32;
  __shared__ __align__(16) float pl[32*360];
  int tid = threadIdx.x;
  for (int t = tid; t < 32*360; t += 256) pl[t] = 0.f;
  __syncthreads();
  const float* yq = Y + (size_t)b*YSTR + QOFF;
  for (int t = tid; t < 32*196; t += 256){
    int cl = t & 31, s = t >> 5;
    int c = c0 + cl;
    int G = s*256 + c;                 // head-major flat index for conv_x2's scramble
    int hh = G / 6272;
    int rem = G - hh*6272;
    int n = rem >> 5, d = rem & 31;
    float cx2 = CMAP[b*256 + c] * yq[n*256 + hh*32 + d];   // sigmoid(cmap)*qs
    float qc  = yq[G];                                     // qc collapses to identity gather
    float v = SCL*(cx2 + qc);
    int i = s/14, j = s - i*14;
    pl[cl*360 + (i+2)*20 + j + 2] = v;
  }
  __syncthreads();
  for (int t = tid; t < 32*14; t += 256){
    int cl = t/14, r = t - cl*14;
    int c = c0 + cl;
    float w25[25];
    #pragma unroll
    for (int u = 0; u < 25; ++u) w25[u] = dw[c*25 + u];
    float acc[14];
    float b2 = 2.f*db[c];
    #pragma unroll
    for (int j = 0; j < 14; ++j) acc[j] = b2;
    conv5x5_row(&pl[cl*360], r, w25, acc);
    float* dst = XO + ((size_t)b*196 + r*14)*256 + c;
    #pragma unroll
    for (int j = 0; j < 14; ++j) dst[j*256] += acc[j];
  }
}

// ---------- final projection: out = XO @ proj_w^T + proj_b ----------
__global__ __launch_bounds__(256) void k_proj(const float* __restrict__ XO, const float* __restrict__ WT,
    const float* __restrict__ pbias, float* __restrict__ OUT){
  int bb = blockIdx.x / 7, nt = blockIdx.x % 7;
  int n0 = nt*28;
  int c = threadIdx.x;
  const float* xb = XO + ((size_t)bb*196 + n0)*256;
  float acc[28];
  #pragma unroll
  for (int r = 0; r < 28; ++r) acc[r] = 0.f;
  for (int k = 0; k < 256; k += 4){
    float w0 = WT[(k+0)*256 + c];
    float w1 = WT[(k+1)*256 + c];
    float w2 = WT[(k+2)*256 + c];
    float w3 = WT[(k+3)*256 + c];
    #pragma unroll
    for (int r = 0; r < 28; ++r){
      float4 xv = *(const float4*)(xb + r*256 + k);   // uniform address -> scalar/L1 path
      acc[r] = fmaf(xv.x, w0, fmaf(xv.y, w1, fmaf(xv.z, w2, fmaf(xv.w, w3, acc[r]))));
    }
  }
  float bv = pbias[c];
  float* dst = OUT + ((size_t)bb*196 + n0)*256 + c;
  #pragma unroll
  for (int r = 0; r < 28; ++r) dst[r*256] = acc[r] + bv;
}

extern "C" void kernel_launch(void* const* d_in, const int* in_sizes, int n_in,
                              void* d_out, int out_size, void* d_ws, size_t ws_size,
                              hipStream_t stream){
  (void)in_sizes; (void)n_in; (void)out_size; (void)ws_size;
  const float* x       = (const float*)d_in[0];
  const float* lka_w   = (const float*)d_in[3];
  const float* lka_b   = (const float*)d_in[4];
  const float* conv5_w = (const float*)d_in[5];
  const float* conv5_b = (const float*)d_in[6];
  const float* caa1_w  = (const float*)d_in[7];
  const float* caa1_b  = (const float*)d_in[8];
  const float* caa2_w  = (const float*)d_in[9];
  const float* caa2_b  = (const float*)d_in[10];
  const float* cam1_w  = (const float*)d_in[11];
  const float* cam1_b  = (const float*)d_in[12];
  const float* cam2_w  = (const float*)d_in[13];
  const float* cam2_b  = (const float*)d_in[14];
  const float* sa_w    = (const float*)d_in[15];
  const float* sa_b    = (const float*)d_in[16];
  const float* ci1_w   = (const float*)d_in[17];
  const float* ci1_b   = (const float*)d_in[18];
  const float* bn_g    = (const float*)d_in[19];
  const float* bn_b    = (const float*)d_in[20];
  const float* ci2_w   = (const float*)d_in[21];
  const float* ci2_b   = (const float*)d_in[22];
  const float* rpbt    = (const float*)d_in[23];
  const float* an_bias = (const float*)d_in[24];
  const float* na_bias = (const float*)d_in[25];
  const float* ah_bias = (const float*)d_in[26];
  const float* aw_bias = (const float*)d_in[27];
  const float* ha_bias = (const float*)d_in[28];
  const float* wa_bias = (const float*)d_in[29];
  const float* dwc_w   = (const float*)d_in[30];
  const float* dwc_b   = (const float*)d_in[31];
  const float* proj_w  = (const float*)d_in[32];
  const float* proj_b  = (const float*)d_in[33];
  float* out = (float*)d_out;
  float* ws = (float*)d_ws;

  float* Y    = ws + WS_Y;
  float* V5   = ws + WS_V5;
  float* AT   = ws + WS_AT;
  float* ATK  = ws + WS_ATK;
  float* CMAP = ws + WS_CMAP;
  float* PBT  = ws + WS_PBT;
  float* AB   = ws + WS_AB;
  float* X1S  = ws + WS_X1S;
  float* AGV  = ws + WS_AGV;
  float* XO   = ws + WS_XO;
  float* WT   = ws + WS_WT;
  ushort_t* Wh = (ushort_t*)(ws + WS_CWT);
  ushort_t* VA = (ushort_t*)(ws + WS_XO);              // 6,422,528 ushorts
  ushort_t* VB = (ushort_t*)(ws + WS_XO + 3211264u);   // 6,422,528 ushorts
  // VA/VB die before k_xo1/k_dwc write XO (stream-ordered).

  k_pb   <<<301, 256, 0, stream>>>(an_bias, ah_bias, aw_bias, PBT);
  k_ab   <<<301, 256, 0, stream>>>(na_bias, ha_bias, wa_bias, AB);
  k_wt   <<<256, 256, 0, stream>>>(proj_w, WT);
  k_cw2  <<<6400, 256, 0, stream>>>(conv5_w, Wh);
  k_lka  <<<1024, 256, 0, stream>>>(x, lka_w, lka_b, Y);
  k_vt   <<<256, 256, 0, stream>>>(Y, VA, VB);
  k_conv5<<<512, 256, 0, stream>>>(VA, Wh, conv5_b, V5);
  k_pool <<<128, 256, 0, stream>>>(Y, AT, ATK);
  k_cbam <<<128, 256, 0, stream>>>(V5, caa1_w, caa1_b, caa2_w, caa2_b,
                                   cam1_w, cam1_b, cam2_w, cam2_b, sa_w, sa_b);
  k_attn2<<<1024, 512, 0, stream>>>(Y, rpbt, X1S);
  k_cinter<<<128, 256, 0, stream>>>(X1S, ci1_w, ci1_b, bn_g, bn_b, ci2_w, ci2_b, CMAP);
  k_agentv<<<1024, 256, 0, stream>>>(Y, V5, VB, AT, ATK, PBT, AGV);
  k_xo1  <<<1024, 256, 0, stream>>>(Y, AT, ATK, AB, AGV, XO);
  k_dwc  <<<1024, 256, 0, stream>>>(Y, CMAP, dwc_w, dwc_b, XO);
  k_proj <<<896, 256, 0, stream>>>(XO, WT, proj_b, out);
}

// Round 6
// 812.413 us; speedup vs baseline: 1.0794x; 1.0794x over previous
//
#include <hip/hip_runtime.h>

// Problem constants
#define NB    128
#define NC    256
#define NPOS  196
#define NHEAD 8
#define NAG   49
#define YSTR  150528      // 768*196 per-batch y floats
#define VOFF  50176       // v_raw offset inside y (256*196)
#define QOFF  100352      // q_raw offset inside y (512*196)
#define SCL   0.17677669529663687f   // 32^-0.5

// Workspace layout (floats). Total = 38,885,440 floats = 155.5 MB.
#define WS_Y    0u
#define WS_V5   19267584u
#define WS_AT   25690112u
#define WS_ATK  27295744u
#define WS_CHG  28901376u
#define WS_CMAP 28934144u
#define WS_PBT  28966912u
#define WS_AB   29043744u
#define WS_X1S  29120576u
#define WS_AGV  29153344u
#define WS_XO   30758976u
#define WS_WT   37181504u
#define WS_CWT  37247040u   // Wh: 1.6M ushort (fp16 conv5 weights, [tap][co][ci])

typedef __attribute__((ext_vector_type(8))) _Float16 half8;
typedef __attribute__((ext_vector_type(8))) short short8;
typedef __attribute__((ext_vector_type(4))) short short4v;
typedef __attribute__((ext_vector_type(4))) float f32x4;
typedef unsigned short ushort_t;
typedef unsigned int uint_t;

__device__ __forceinline__ float sigmoidf_(float x){ return 1.0f/(1.0f+__expf(-x)); }

__device__ __forceinline__ ushort_t f2h(float x){
  _Float16 h = (_Float16)x; return __builtin_bit_cast(ushort_t, h);
}
__device__ __forceinline__ float h2f(ushort_t u){
  return (float)__builtin_bit_cast(_Float16, u);
}

// bilinear upsample 7x7 -> 14x14 sample at (i,j), matching reference grid()
__device__ __forceinline__ float bilin7(const float* __restrict__ src, int i, int j){
  float pi = fmaxf(0.5f*(float)i - 0.25f, 0.f);
  int i0 = (int)pi; if (i0 > 6) i0 = 6;
  int i1 = i0 + 1;  if (i1 > 6) i1 = 6;
  float li = pi - (float)i0;
  float pj = fmaxf(0.5f*(float)j - 0.25f, 0.f);
  int j0 = (int)pj; if (j0 > 6) j0 = 6;
  int j1 = j0 + 1;  if (j1 > 6) j1 = 6;
  float lj = pj - (float)j0;
  float v00 = src[i0*7+j0], v01 = src[i0*7+j1];
  float v10 = src[i1*7+j0], v11 = src[i1*7+j1];
  float t0 = v00*(1.f-lj) + v01*lj;
  float t1 = v10*(1.f-lj) + v11*lj;
  return t0*(1.f-li) + t1*li;
}

// 5x5 conv over a zero-padded [18][20] plane, producing one 14-wide output row r.
__device__ __forceinline__ void conv5x5_row(const float* __restrict__ plane, int r,
                                            const float* __restrict__ w25, float* acc14){
  #pragma unroll
  for (int di = 0; di < 5; ++di){
    const float4* pr = (const float4*)(plane + (r+di)*20);
    float4 p0 = pr[0], p1 = pr[1], p2 = pr[2], p3 = pr[3], p4 = pr[4];
    float row[20] = {p0.x,p0.y,p0.z,p0.w, p1.x,p1.y,p1.z,p1.w, p2.x,p2.y,p2.z,p2.w,
                     p3.x,p3.y,p3.z,p3.w, p4.x,p4.y,p4.z,p4.w};
    #pragma unroll
    for (int dj = 0; dj < 5; ++dj){
      float w = w25[di*5+dj];
      #pragma unroll
      for (int j = 0; j < 14; ++j) acc14[j] = fmaf(row[j+dj], w, acc14[j]);
    }
  }
}

// ---------- prep kernels ----------
// merged pb+ab: blocks [0,301) -> PBT, [301,602) -> AB
__global__ void k_pbab(const float* __restrict__ an, const float* __restrict__ ah,
                       const float* __restrict__ aw, const float* __restrict__ na,
                       const float* __restrict__ ha, const float* __restrict__ wa,
                       float* __restrict__ PBT, float* __restrict__ AB){
  int bid = blockIdx.x;
  int which = (bid >= 301);
  int t = (which ? bid - 301 : bid)*256 + threadIdx.x;
  if (t >= NHEAD*NPOS*NAG) return;
  int a = t % NAG;
  int r = t / NAG;
  int n = r % NPOS;
  int h = r / NPOS;
  int i = n/14, j = n - (n/14)*14;
  if (!which){
    float v = bilin7(an + ((size_t)h*NAG + a)*49, i, j);
    v += ah[((size_t)h*NAG + a)*14 + i] + aw[((size_t)h*NAG + a)*14 + j];
    PBT[t] = v;   // [h][n][a]
  } else {
    float v = bilin7(na + ((size_t)h*NAG + a)*49, i, j);
    v += ha[((size_t)h*14 + i)*NAG + a] + wa[((size_t)h*14 + j)*NAG + a];
    AB[t] = v;    // [h][n][a]
  }
}

__global__ void k_wt(const float* __restrict__ pw, float* __restrict__ WT){
  int t = blockIdx.x*256 + threadIdx.x;
  if (t >= 65536) return;
  int k = t >> 8, c = t & 255;
  WT[t] = pw[c*256 + k];          // WT[k][c] = proj_w[c][k]
}

// conv5 weights -> fp16, layout [tap][co][ci]
__global__ void k_cw2(const float* __restrict__ cw, ushort_t* __restrict__ Wh){
  int t = blockIdx.x*256 + threadIdx.x;
  if (t >= 1638400) return;
  int ci = t & 255;
  int r  = t >> 8;
  int co = r & 255;
  int tap = r >> 8;
  Wh[t] = f2h(cw[((size_t)co*256 + ci)*25 + tap]);
}

// ---------- lka depthwise-ish conv (groups=256, 3 outputs per input channel) ----------
__global__ __launch_bounds__(256) void k_lka(const float* __restrict__ x, const float* __restrict__ lw,
                                             const float* __restrict__ lb, float* __restrict__ Y){
  int b = blockIdx.x >> 3, gb = blockIdx.x & 7;
  int g0 = gb*32;                               // input channels [g0,g0+32)
  __shared__ __align__(16) float pl[32*360];    // [ch][18*20] padded planes
  int tid = threadIdx.x;
  for (int t = tid; t < 32*360; t += 256) pl[t] = 0.f;
  __syncthreads();
  for (int t = tid; t < 32*196; t += 256){
    int gl = t & 31, s = t >> 5;
    int i = s/14, j = s - i*14;
    pl[gl*360 + (i+2)*20 + j + 2] = x[((size_t)b*196 + s)*256 + g0 + gl];
  }
  __syncthreads();
  for (int t = tid; t < 96*14; t += 256){
    int ocl = t/14, r = t - ocl*14;
    int o  = g0*3 + ocl;          // output channel; uses input channel o/3
    int gl = ocl/3;
    float w25[25];
    #pragma unroll
    for (int u = 0; u < 25; ++u) w25[u] = lw[o*25 + u];
    float acc[14];
    float bv = lb[o];
    #pragma unroll
    for (int j = 0; j < 14; ++j) acc[j] = bv;
    conv5x5_row(&pl[gl*360], r, w25, acc);
    float* dst = Y + ((size_t)b*768 + o)*196 + r*14;
    #pragma unroll
    for (int j = 0; j < 14; ++j) dst[j] = acc[j];
  }
}

// ---------- conv5 via fp16 MFMA implicit GEMM (round-4 version, 124.9us) ----------
// Natural 80B-row addressing: 16B-slot of a b128 access at (row, chunk) is
// (5*row + chunk) mod 8 -- a permutation over any 8-lane phase. A-staging
// packs short8 per (pos,chunk) so writes follow the same permutation.
__global__ __launch_bounds__(256, 2) void k_conv5(const float* __restrict__ Y,
    const ushort_t* __restrict__ Wh, const float* __restrict__ cb, float* __restrict__ V5){
  int b = blockIdx.x >> 2, cog = blockIdx.x & 3;
  int co0 = cog*64;
  __shared__ __align__(16) ushort_t Pt[360*40];     // fp16 A: [pos][4 chunks of 8ci + pad]
  __shared__ __align__(16) ushort_t Wsm[5*64*40];   // fp16 B: [tap-of-row][co][4 chunks + pad]
  __shared__ float T[32*200];                       // epilogue transpose
  int tid  = threadIdx.x;
  int lane = tid & 63, wv = tid >> 6;
  int mrow = lane & 15, quad = lane >> 4;

  // zero-fill Pt once; borders stay zero across chunks
  for (int t = tid; t < 7200; t += 256) ((uint_t*)Pt)[t] = 0;

  // per-lane A plane-row base per m-tile (unpadded base; taps add di*20+dj)
  int prow[4];
  #pragma unroll
  for (int mt = 0; mt < 4; ++mt){
    int s = wv*64 + mt*16 + mrow;
    int p0 = 0;
    if (s < 196){ int i = s/14, j = s - i*14; p0 = i*20 + j; }
    prow[mt] = p0;
  }

  f32x4 acc[4][4];
  #pragma unroll
  for (int mt = 0; mt < 4; ++mt)
    #pragma unroll
    for (int nt = 0; nt < 4; ++nt) acc[mt][nt] = (f32x4){0.f,0.f,0.f,0.f};

  const float* src = Y + (size_t)b*YSTR + VOFF;   // v_raw [ci][s]
  int wco = tid >> 2, wpart = tid & 3;            // W-staging roles

  #pragma unroll 1
  for (int cc = 0; cc < 8; ++cc){
    __syncthreads();              // Pt free to overwrite (prev chunk's reads done)
    // stage A: 784 (pos, chunk) items; each thread packs 8 ci -> one b128 write
    // at slot (5p + ch) mod 8: conflict-free permutation, matches read layout.
    for (int t = tid; t < 784; t += 256){
      int pos = t >> 2, ch = t & 3;
      int i = pos/14, j = pos - i*14;
      int p = (i+2)*20 + j + 2;
      const float* s0 = src + (size_t)(cc*32 + ch*8)*196 + pos;
      short8 pk;
      #pragma unroll
      for (int e = 0; e < 4; ++e){
        float v0 = s0[(2*e)*196];
        float v1 = s0[(2*e+1)*196];
        pk[2*e]   = (short)f2h(v0);
        pk[2*e+1] = (short)f2h(v1);
      }
      *(short8*)&Pt[p*40 + ch*8] = pk;
    }
    #pragma unroll 1
    for (int di = 0; di < 5; ++di){
      __syncthreads();      // Wsm free to overwrite; also fences A writes (di=0)
      // stage W: taps di*5..di*5+4, 64 co x 32 ci fp16 each, natural layout
      #pragma unroll
      for (int tp = 0; tp < 5; ++tp){
        int tap = di*5 + tp;
        const short8 g = *(const short8*)(Wh + ((size_t)tap*256 + co0 + wco)*256 + cc*32 + wpart*8);
        *(short8*)&Wsm[(tp*64 + wco)*40 + wpart*8] = g;
      }
      __syncthreads();
      #pragma unroll
      for (int dj = 0; dj < 5; ++dj){
        half8 a[4], bb[4];
        #pragma unroll
        for (int nt = 0; nt < 4; ++nt){
          int co = nt*16 + mrow;
          bb[nt] = *(const half8*)&Wsm[(dj*64 + co)*40 + quad*8];
        }
        #pragma unroll
        for (int mt = 0; mt < 4; ++mt){
          int p = prow[mt] + di*20 + dj;
          a[mt] = *(const half8*)&Pt[p*40 + quad*8];
        }
        #pragma unroll
        for (int mt = 0; mt < 4; ++mt)
          #pragma unroll
          for (int nt = 0; nt < 4; ++nt)
            acc[mt][nt] = __builtin_amdgcn_mfma_f32_16x16x32_f16(a[mt], bb[nt], acc[mt][nt], 0, 0, 0);
      }
    }
  }

  // epilogue: transpose through LDS, then stores into scrambled v5
  #pragma unroll
  for (int hf = 0; hf < 2; ++hf){
    __syncthreads();
    #pragma unroll
    for (int ntl = 0; ntl < 2; ++ntl){
      int nt = hf*2 + ntl;
      int col = ntl*16 + mrow;            // co local within half (0..31)
      #pragma unroll
      for (int mt = 0; mt < 4; ++mt){
        int sbase = wv*64 + mt*16 + quad*4;
        #pragma unroll
        for (int r = 0; r < 4; ++r){
          int s = sbase + r;
          if (s < 196) T[col*200 + s] = acc[mt][nt][r];
        }
      }
    }
    __syncthreads();
    for (int t = tid; t < 6272; t += 256){
      int cl = t / 196;                   // co local 0..31
      int f = (co0 + hf*32)*196 + t;
      float val = T[t + cl*4] + cb[co0 + hf*32 + cl];
      V5[(size_t)b*50176 + (size_t)(f & 255)*196 + (f >> 8)] = val;
    }
  }
}

// ---------- agent token pooling (256 blocks: channel-half x agent-half split) ----------
__global__ __launch_bounds__(256) void k_pool(const float* __restrict__ Y, float* __restrict__ AT, float* __restrict__ ATK){
  int b = blockIdx.x >> 1, half = blockIdx.x & 1;
  int c = (threadIdx.x & 127) + half*128;
  int a0 = (threadIdx.x >> 7) ? 25 : 0;
  int a1 = (threadIdx.x >> 7) ? 49 : 25;
  const float* qp = Y + ((size_t)b*768 + 512 + c)*196;
  const float* kp = Y + ((size_t)b*768 + c)*196;
  for (int a = a0; a < a1; ++a){
    int p1 = a/7, p2 = a - p1*7;
    int s = p1*28 + p2*2;
    float q0 = qp[s], q1 = qp[s+1], q2 = qp[s+14], q3 = qp[s+15];
    AT[((size_t)b*49 + a)*256 + c] = 0.25f*(q0+q1+q2+q3);
    float k0 = kp[s], k1 = kp[s+1], k2 = kp[s+14], k3 = kp[s+15];
    ATK[((size_t)b*49 + a)*256 + c] = fmaxf(fmaxf(k0,k1), fmaxf(k2,k3));
  }
}

// ---------- cbam stage A: channel gate ----------
__global__ __launch_bounds__(256) void k_cbam_a(const float* __restrict__ V5,
    const float* __restrict__ caa1w, const float* __restrict__ caa1b,
    const float* __restrict__ caa2w, const float* __restrict__ caa2b,
    const float* __restrict__ cam1w, const float* __restrict__ cam1b,
    const float* __restrict__ cam2w, const float* __restrict__ cam2b,
    float* __restrict__ CHG){
  int b = blockIdx.x, c = threadIdx.x;
  __shared__ float avg[256], mx[256], t1[16], t2[16];
  const float* pp = V5 + ((size_t)b*256 + c)*196;
  float s = 0.f, m = -1e30f;
  for (int i = 0; i < 196; ++i){ float v = pp[i]; s += v; m = fmaxf(m, v); }
  avg[c] = s * (1.0f/196.0f); mx[c] = m;
  __syncthreads();
  if (c < 16){
    float a1 = caa1b[c], a2 = cam1b[c];
    #pragma unroll 4
    for (int k = 0; k < 256; ++k){
      a1 = fmaf(caa1w[(c*256 + k)*9 + 4], avg[k], a1);   // 3x3 center tap
      a2 = fmaf(cam1w[c*256 + k], mx[k], a2);            // 1x1
    }
    t1[c] = fmaxf(a1, 0.f);
    t2[c] = fmaxf(a2, 0.f);
  }
  __syncthreads();
  float y1 = caa2b[c], y2 = cam2b[c];
  #pragma unroll
  for (int k = 0; k < 16; ++k){
    y1 = fmaf(caa2w[(c*16 + k)*9 + 4], t1[k], y1);
    y2 = fmaf(cam2w[c*16 + k], t2[k], y2);
  }
  CHG[b*256 + c] = sigmoidf_(sigmoidf_(y1) + sigmoidf_(y2));
}

// ---------- cbam stage B: spatial mask (9x9 pad4 over [mean,max]) + in-place gate ----------
__global__ __launch_bounds__(256) void k_cbam_b(float* __restrict__ V5, const float* __restrict__ CHG,
    const float* __restrict__ saw, const float* __restrict__ sab){
  int b = blockIdx.x; int tid = threadIdx.x;
  __shared__ float chg[256];
  __shared__ float mp[22*22], xp[22*22];
  __shared__ float mk[196];
  chg[tid] = CHG[b*256 + tid];
  for (int t = tid; t < 484; t += 256){ mp[t] = 0.f; xp[t] = 0.f; }
  __syncthreads();
  if (tid < 196){
    int i = tid/14, j = tid - i*14;
    float s = 0.f, m = -1e30f;
    const float* vb = V5 + (size_t)b*256*196 + tid;
    for (int c = 0; c < 256; ++c){
      float v = chg[c] * vb[c*196];
      s += v; m = fmaxf(m, v);
    }
    mp[(i+4)*22 + j+4] = s*(1.f/256.f);
    xp[(i+4)*22 + j+4] = m;
  }
  __syncthreads();
  if (tid < 196){
    int i = tid/14, j = tid - i*14;
    float acc = sab[0];
    for (int di = 0; di < 9; ++di){
      #pragma unroll
      for (int dj = 0; dj < 9; ++dj){
        acc = fmaf(mp[(i+di)*22 + j+dj], saw[di*9+dj], acc);
        acc = fmaf(xp[(i+di)*22 + j+dj], saw[81 + di*9+dj], acc);
      }
    }
    mk[tid] = sigmoidf_(acc);
  }
  __syncthreads();
  if (tid < 196){
    float m = mk[tid];
    float* vb = V5 + (size_t)b*256*196 + tid;
    for (int c = 0; c < 256; ++c) vb[c*196] = chg[c]*vb[c*196]*m;
  }
}

// ---------- big NxN attention via MFMA, 3-segment version ----------
// x1s[c] = (1/196) sum_j w[j] V[j][c],  w[j] = sum_n e[n][j] / l[n].
// n-tiles (13) processed in segments {5,4,4} so E shrinks [196][208]->[80][208]
// (81.5KB -> 33KB; total LDS ~74KB -> 2 blocks/CU instead of 1). Per segment:
// warps 2k/2k+1 split each n-column's 13 mt-tiles 7/6 (both halves of lsum in
// pl2); then wpart row-groups accumulate wj += E*invl. Work identical to the
// single-segment version; only fp32 summation grouping differs.
__global__ __launch_bounds__(512, 4) void k_attn3(const float* __restrict__ Y,
    const float* __restrict__ rpbt, float* __restrict__ X1S){
  int b = blockIdx.x >> 3, h = blockIdx.x & 7;
  __shared__ __align__(16) ushort_t Qh[208*32];    // fp16 q*SCL rows, chunk-swizzled
  __shared__ __align__(16) ushort_t Kh[208*32];    // fp16 k rows, chunk-swizzled
  __shared__ __align__(16) ushort_t E[80*208];     // fp16 exp-scores [n-local][j]
  __shared__ float rp[736];
  __shared__ int   rpo[208];
  __shared__ float pl2[80][2];                     // lsum halves per row
  __shared__ float invl[80];
  __shared__ float wj[208];
  __shared__ float wpart[8][208];
  __shared__ float xpart[16][32];
  int tid = threadIdx.x, wv = tid >> 6, lane = tid & 63;
  int mrow = lane & 15, quad = lane >> 4;
  int sw8 = ((quad ^ ((mrow >> 1) & 3)) << 3);     // 64B-row read swizzle
  const float* yb = Y + (size_t)b*YSTR;

  // ---- tables + staging ----
  for (int t = tid; t < 736; t += 512) rp[t] = (t < 729) ? rpbt[t*8 + h] : 0.f;
  for (int j = tid; j < 208; j += 512){
    int jc = (j < 196) ? j : 195;
    int rj = jc/14;
    rpo[j] = rj*27 + (jc - rj*14);
    wj[j] = 0.f;
  }
  for (int t = tid; t < 384; t += 512){            // zero rows 196..207 of Qh/Kh
    int arr = t >= 192; int u = t - arr*192;
    ((uint_t*)(arr ? Kh : Qh))[3136 + u] = 0;
  }
  for (int t = tid; t < 3136; t += 512){
    int n = t >> 4, w = t & 15;
    int ws = (((w >> 2) ^ ((n >> 1) & 3)) << 2) | (w & 3);
    const float2 qv = *(const float2*)(yb + QOFF + (size_t)n*256 + h*32 + (w << 1));
    ((uint_t*)Qh)[n*16 + ws] = (uint_t)f2h(qv.x*SCL) | ((uint_t)f2h(qv.y*SCL) << 16);
    const float2 kv = *(const float2*)(yb + (size_t)n*256 + h*32 + (w << 1));
    ((uint_t*)Kh)[n*16 + ws] = (uint_t)f2h(kv.x) | ((uint_t)f2h(kv.y) << 16);
  }
  __syncthreads();

  int mt0 = (wv & 1) ? 7 : 0;
  int mt1 = (wv & 1) ? 13 : 7;

  #pragma unroll 1
  for (int seg = 0; seg < 3; ++seg){
    int base = (seg == 0) ? 0 : (seg == 1) ? 80 : 144;
    int ntl  = (seg == 0) ? 5 : 4;
    int segrows = ntl*16;
    int vrows = 196 - base; if (vrows > segrows) vrows = segrows;

    // ---- phase A: logits, E-store, row-sum halves ----
    #pragma unroll 1
    for (int ncl = (wv >> 1); ncl < ntl; ncl += 4){
      int n = base + ncl*16 + mrow;
      half8 bfr = *(const half8*)&Qh[n*32 + sw8];
      int nclamp = (n < 196) ? n : 195;
      int rin = nclamp/14, cin = nclamp - rin*14;
      int bidxn = (rin + 13)*27 + (cin + 13);
      float lsum = 0.f;
      #pragma unroll 1
      for (int mt = mt0; mt < mt1; ++mt){
        half8 afr = *(const half8*)&Kh[(mt*16 + mrow)*32 + sw8];
        f32x4 c = (f32x4){0.f,0.f,0.f,0.f};
        c = __builtin_amdgcn_mfma_f32_16x16x32_f16(afr, bfr, c, 0, 0, 0);
        int j0 = mt*16 + quad*4;
        int4 ro = *(const int4*)&rpo[j0];
        short4v pk;
        #pragma unroll
        for (int r = 0; r < 4; ++r){
          int j = j0 + r;
          int roff = (r == 0) ? ro.x : (r == 1) ? ro.y : (r == 2) ? ro.z : ro.w;
          float e = (j < 196) ? __expf(c[r] + rp[bidxn - roff]) : 0.f;
          lsum += e;
          pk[r] = (short)f2h(e);
        }
        if (n < 196) *(short4v*)&E[(n - base)*208 + j0] = pk;
      }
      lsum += __shfl_xor(lsum, 16);
      lsum += __shfl_xor(lsum, 32);
      if (quad == 0) pl2[n - base][wv & 1] = lsum;
    }
    __syncthreads();
    for (int t = tid; t < vrows; t += 512) invl[t] = 1.f/(pl2[t][0] + pl2[t][1]);
    __syncthreads();

    // ---- phase B: wpart[g][j] = sum over rows (g+8k) of E*invl ----
    {
      int j0 = lane*4;
      if (j0 < 208){
        float a0=0.f,a1=0.f,a2=0.f,a3=0.f;
        #pragma unroll 1
        for (int nl = wv; nl < vrows; nl += 8){
          float iv = invl[nl];
          short4v ev = *(const short4v*)&E[nl*208 + j0];
          a0 = fmaf(h2f((ushort_t)ev[0]), iv, a0);
          a1 = fmaf(h2f((ushort_t)ev[1]), iv, a1);
          a2 = fmaf(h2f((ushort_t)ev[2]), iv, a2);
          a3 = fmaf(h2f((ushort_t)ev[3]), iv, a3);
        }
        *(f32x4*)&wpart[wv][j0] = (f32x4){a0,a1,a2,a3};
      }
    }
    __syncthreads();
    for (int j = tid; j < 208; j += 512){
      float s = wj[j];
      #pragma unroll
      for (int g = 0; g < 8; ++g) s += wpart[g][j];
      wj[j] = s;
    }
    __syncthreads();   // wpart/E/pl2/invl free for next segment
  }

  // ---- X1S[c] = (1/196) sum_j wj[j] * V[j][c] ----
  {
    int d = tid & 31, g = tid >> 5;                // 16 groups x 13 j's
    float s = 0.f;
    #pragma unroll 1
    for (int u = 0; u < 13; ++u){
      int j = g*13 + u;
      s = fmaf(wj[j], yb[VOFF + (size_t)j*256 + h*32 + d], s);
    }
    xpart[g][d] = s;
  }
  __syncthreads();
  if (tid < 32){
    float s = 0.f;
    #pragma unroll
    for (int g2 = 0; g2 < 16; ++g2) s += xpart[g2][tid];
    X1S[(size_t)b*256 + h*32 + tid] = s*(1.f/196.f);
  }
}

// ---------- chan_inter on x1 mean -> sigmoid gate CMAP ----------
__global__ __launch_bounds__(256) void k_cinter(const float* __restrict__ X1S,
    const float* __restrict__ ci1w, const float* __restrict__ ci1b,
    const float* __restrict__ bng, const float* __restrict__ bnb,
    const float* __restrict__ ci2w, const float* __restrict__ ci2b, float* __restrict__ CMAP){
  int b = blockIdx.x, c = threadIdx.x;
  __shared__ float p[256], tt[16];
  p[c] = X1S[b*256 + c];
  __syncthreads();
  if (c < 16){
    float a = ci1b[c];
    #pragma unroll 4
    for (int k = 0; k < 256; ++k) a = fmaf(ci1w[(c*256+k)*25 + 12], p[k], a);  // 5x5 center
    const float invs = 0.9999950000375f;   // 1/sqrt(1+1e-5)
    tt[c] = fmaxf(fmaf(bng[c]*invs, a, bnb[c]), 0.f);
  }
  __syncthreads();
  float a = ci2b[c];
  #pragma unroll
  for (int k = 0; k < 16; ++k) a = fmaf(ci2w[(c*16+k)*25 + 12], tt[k], a);
  CMAP[b*256 + c] = sigmoidf_(a);
}

// ---------- agent_v via fp16 MFMA ----------
// Kh/Ah rows are 64B (even stride): reads use a bijective chunk swizzle
// chunk ^= (row>>1)&3 (write side mirrors it) so an 8-lane b128 phase hits
// 8 distinct 16B slots: slot = 4*(row&1) + quad^((row>>1)&3) is a permutation.
__global__ __launch_bounds__(256) void k_agentv(const float* __restrict__ Y, const float* __restrict__ V5,
    const float* __restrict__ AT, const float* __restrict__ ATK,
    const float* __restrict__ PBT, float* __restrict__ AGV){
  int b = blockIdx.x >> 3, h = blockIdx.x & 7;
  __shared__ __align__(16) ushort_t ST[64*232];   // exp-scores, [a][n pad 232]
  __shared__ __align__(16) ushort_t R[8704];      // staging region (17408 B)
  __shared__ float psum[4*64];
  __shared__ float inv0s[64], inv1s[64];
  int tid = threadIdx.x, wv = tid >> 6, lane = tid & 63;
  int mrow = lane & 15, quad = lane >> 4;
  int sw8 = ((quad ^ ((mrow >> 1) & 3)) << 3);    // read-side chunk swizzle (rows = 16*t + mrow)
  const float* yb = Y + (size_t)b*YSTR;
  ushort_t* Kh = R;            // [208][32] fp16 rows (K or Q), chunk-swizzled
  ushort_t* Ah = R + 6656;     // [64][32] fp16 rows (AT or ATK), chunk-swizzled
  ushort_t* Vt = R;            // [32][232] fp16 rows (V1 or V)
  f32x4 out0[2], out1[2];

  // ---- one-time zero fills: ST cols 208..223 (cols 224-231 never read) ----
  for (int t = tid; t < 512; t += 256){      // 64 rows x 16 cols /2 per uint
    int a = t >> 3, c2 = 208 + ((t & 7) << 1);
    *(uint_t*)&ST[a*232 + c2] = 0;
  }

  #pragma unroll 1
  for (int pass = 0; pass < 2; ++pass){
    // ---- stage rows (K|Q into Kh; AT|ATK into Ah), zero pads ----
    for (int t = tid; t < 192; t += 256) ((uint_t*)Kh)[3136 + t] = 0;   // rows 196-207
    for (int t = tid; t < 240; t += 256) ((uint_t*)Ah)[784 + t] = 0;    // rows 49-63
    {
      const float* rsrc = yb + (pass ? QOFF : 0) + h*32;
      for (int t = tid; t < 3136; t += 256){
        int n = t >> 4, w = t & 15;
        const float2 v = *(const float2*)(rsrc + (size_t)n*256 + (w << 1));
        int ws = (((w >> 2) ^ ((n >> 1) & 3)) << 2) | (w & 3);
        ((uint_t*)Kh)[n*16 + ws] = (uint_t)f2h(v.x) | ((uint_t)f2h(v.y) << 16);
      }
      const float* asrc = (pass ? ATK : AT) + (size_t)b*49*256 + h*32;
      for (int t = tid; t < 784; t += 256){
        int a = t >> 4, w = t & 15;
        const float2 v = *(const float2*)(asrc + (size_t)a*256 + (w << 1));
        int ws = (((w >> 2) ^ ((a >> 1) & 3)) << 2) | (w & 3);
        ((uint_t*)Ah)[a*16 + ws] = (uint_t)f2h(v.x) | ((uint_t)f2h(v.y) << 16);
      }
    }
    __syncthreads();
    // ---- logits: ntile = wv; 13 mtiles; exp(+pb) -> ST[a][n] ----
    {
      float lscl = pass ? 0.03125f : SCL;
      int ag = wv*16 + mrow;                 // agent (C col)
      half8 bfr = *(const half8*)&Ah[ag*32 + sw8];
      #pragma unroll 1
      for (int mt = 0; mt < 13; ++mt){
        half8 afr = *(const half8*)&Kh[(mt*16 + mrow)*32 + sw8];
        f32x4 c = (f32x4){0.f,0.f,0.f,0.f};
        c = __builtin_amdgcn_mfma_f32_16x16x32_f16(afr, bfr, c, 0, 0, 0);
        int n0 = mt*16 + quad*4;
        short4v pk;
        #pragma unroll
        for (int r = 0; r < 4; ++r){
          int n = n0 + r;
          float pb = PBT[((size_t)h*196 + n)*49 + ag];
          float e = (n < 196) ? __expf(fmaf(c[r], lscl, pb)) : 0.f;
          pk[r] = (short)f2h(e);
        }
        *(short4v*)&ST[ag*232 + n0] = pk;
      }
    }
    __syncthreads();
    // ---- denominators + stage V ----
    {
      int a = tid >> 2, q = tid & 3;
      float s = 0.f;
      #pragma unroll
      for (int u = 0; u < 7; ++u){
        short8 v8 = *(const short8*)&ST[a*232 + q*56 + u*8];
        #pragma unroll
        for (int e = 0; e < 8; ++e) s += h2f((ushort_t)v8[e]);
      }
      psum[q*64 + a] = s;
    }
    if (pass == 0){
      const float* vsrc = V5 + (size_t)b*50176 + h*32*196;   // [d][196]
      for (int t = tid; t < 3136; t += 256){
        int d = t / 98, np = t - (t/98)*98;
        const float2 v = *(const float2*)(vsrc + (size_t)d*196 + 2*np);
        *(uint_t*)&Vt[d*232 + 2*np] = (uint_t)f2h(v.x) | ((uint_t)f2h(v.y) << 16);
      }
    } else {
      const float* vsrc = yb + VOFF + h*32;                  // [n][256]
      for (int t = tid; t < 3136; t += 256){
        int d = t / 98, np = t - (t/98)*98;
        float v0 = vsrc[(size_t)(2*np)*256 + d];
        float v1 = vsrc[(size_t)(2*np+1)*256 + d];
        *(uint_t*)&Vt[d*232 + 2*np] = (uint_t)f2h(v0) | ((uint_t)f2h(v1) << 16);
      }
    }
    for (int t = tid; t < 448; t += 256){    // zero V cols 196..223
      int d = t / 14, c2 = 196 + 2*(t - (t/14)*14);
      *(uint_t*)&Vt[d*232 + c2] = 0;
    }
    __syncthreads();
    // ---- PV: mtile = wv (a rows); ntile 0..1 (d cols); 7 k-steps ----
    {
      f32x4* outp = pass ? out1 : out0;
      #pragma unroll
      for (int nt = 0; nt < 2; ++nt){
        f32x4 c = (f32x4){0.f,0.f,0.f,0.f};
        #pragma unroll
        for (int ks = 0; ks < 7; ++ks){
          half8 afr = *(const half8*)&ST[(wv*16 + mrow)*232 + ks*32 + quad*8];
          half8 bfr = *(const half8*)&Vt[(nt*16 + mrow)*232 + ks*32 + quad*8];
          c = __builtin_amdgcn_mfma_f32_16x16x32_f16(afr, bfr, c, 0, 0, 0);
        }
        outp[nt] = c;
      }
      if (tid < 64){
        float s = psum[tid] + psum[64+tid] + psum[128+tid] + psum[192+tid];
        float* invp = pass ? inv1s : inv0s;
        invp[tid] = 1.f / s;
      }
    }
    __syncthreads();   // ST/Vt free for next pass; inv visible
  }
  // ---- epilogue: combine + scatter ----
  #pragma unroll
  for (int nt = 0; nt < 2; ++nt){
    int d = nt*16 + mrow;
    #pragma unroll
    for (int r = 0; r < 4; ++r){
      int a = wv*16 + quad*4 + r;
      if (a < 49)
        AGV[(((size_t)(b*8 + h)*49) + a)*32 + d] = out0[nt][r]*inv0s[a] + out1[nt][r]*inv1s[a];
    }
  }
}

// ---------- xo1 via fp16 MFMA ----------
__global__ __launch_bounds__(256) void k_xo1(const float* __restrict__ Y,
    const float* __restrict__ AT, const float* __restrict__ ATK,
    const float* __restrict__ AB, const float* __restrict__ AGV, float* __restrict__ XO){
  int b = blockIdx.x >> 3, h = blockIdx.x & 7;
  __shared__ __align__(16) ushort_t ST[208*72];   // exp-scores [n][a pad 72]
  __shared__ __align__(16) ushort_t Kh[208*32];   // Q or K rows fp16, chunk-swizzled
  __shared__ __align__(16) ushort_t Ah[64*32];    // AT or ATK rows fp16, chunk-swizzled
  __shared__ __align__(16) ushort_t AGVt[32*64];  // AGV^T [d][a], chunk-swizzled
  __shared__ float invs[208];
  int tid = threadIdx.x, wv = tid >> 6, lane = tid & 63;
  int mrow = lane & 15, quad = lane >> 4;
  int sw8 = ((quad ^ ((mrow >> 1) & 3)) << 3);    // 64B-row read swizzle
  const float* yb = Y + (size_t)b*YSTR;
  f32x4 acc[4][2];
  #pragma unroll
  for (int i = 0; i < 4; ++i){
    acc[i][0] = (f32x4){0.f,0.f,0.f,0.f};
    acc[i][1] = (f32x4){0.f,0.f,0.f,0.f};
  }

  for (int t = tid; t < 1664; t += 256){
    int rw = t >> 3, c2 = 48 + ((t & 7) << 1);
    *(uint_t*)&ST[rw*72 + c2] = 0;
  }
  {
    const float* agvb = AGV + (size_t)(b*8 + h)*49*32;
    for (int t = tid; t < 2048; t += 256){
      int d = t >> 6, a = t & 63;
      int as = ((((a >> 3) ^ (d & 7)) & 7) << 3) | (a & 7);
      AGVt[d*64 + as] = (a < 49) ? f2h(agvb[a*32 + d]) : (ushort_t)0;
    }
  }

  #pragma unroll 1
  for (int pass = 0; pass < 2; ++pass){
    {
      const float* rsrc = yb + (pass ? 0 : QOFF) + h*32;
      for (int t = tid; t < 3136; t += 256){
        int n = t >> 4, w = t & 15;
        const float2 v = *(const float2*)(rsrc + (size_t)n*256 + (w << 1));
        int ws = (((w >> 2) ^ ((n >> 1) & 3)) << 2) | (w & 3);
        ((uint_t*)Kh)[n*16 + ws] = (uint_t)f2h(v.x) | ((uint_t)f2h(v.y) << 16);
      }
      const float* asrc = (pass ? ATK : AT) + (size_t)b*49*256 + h*32;
      for (int t = tid; t < 784; t += 256){
        int a = t >> 4, w = t & 15;
        const float2 v = *(const float2*)(asrc + (size_t)a*256 + (w << 1));
        int ws = (((w >> 2) ^ ((a >> 1) & 3)) << 2) | (w & 3);
        ((uint_t*)Ah)[a*16 + ws] = (uint_t)f2h(v.x) | ((uint_t)f2h(v.y) << 16);
      }
    }
    __syncthreads();
    {
      float lscl = pass ? SCL : 0.03125f;
      int ag = wv*16 + mrow;
      half8 bfr = *(const half8*)&Ah[ag*32 + sw8];
      #pragma unroll 1
      for (int mt = 0; mt < 13; ++mt){
        half8 afr = *(const half8*)&Kh[(mt*16 + mrow)*32 + sw8];
        f32x4 c = (f32x4){0.f,0.f,0.f,0.f};
        c = __builtin_amdgcn_mfma_f32_16x16x32_f16(afr, bfr, c, 0, 0, 0);
        #pragma unroll
        for (int r = 0; r < 4; ++r){
          int n = mt*16 + quad*4 + r;
          if (n < 196 && ag < 49){
            float e = __expf(fmaf(c[r], lscl, AB[((size_t)h*196 + n)*49 + ag]));
            ST[n*72 + ag] = f2h(e);
          }
        }
      }
    }
    __syncthreads();
    if (tid < 196){
      float s = 0.f;
      #pragma unroll
      for (int u = 0; u < 7; ++u){
        short8 v8 = *(const short8*)&ST[tid*72 + u*8];
        #pragma unroll
        for (int e = 0; e < 8; ++e) s += h2f((ushort_t)v8[e]);
      }
      invs[tid] = 1.f / s;
    }
    __syncthreads();
    {
      int i = 0;
      #pragma unroll 1
      for (int mt = wv; mt < 13; mt += 4, ++i){
        #pragma unroll
        for (int nt = 0; nt < 2; ++nt){
          f32x4 c = (f32x4){0.f,0.f,0.f,0.f};
          #pragma unroll
          for (int ks = 0; ks < 2; ++ks){
            half8 afr = *(const half8*)&ST[(mt*16 + mrow)*72 + ks*32 + quad*8];
            half8 bfr = *(const half8*)&AGVt[(nt*16 + mrow)*64 + ((((ks*4 + quad) ^ (mrow & 7)) & 7) << 3)];
            c = __builtin_amdgcn_mfma_f32_16x16x32_f16(afr, bfr, c, 0, 0, 0);
          }
          #pragma unroll
          for (int r = 0; r < 4; ++r){
            int n = mt*16 + quad*4 + r;
            if (n < 196) acc[i][nt][r] = fmaf(c[r], invs[n], acc[i][nt][r]);
          }
        }
      }
    }
    __syncthreads();
  }
  {
    int i = 0;
    #pragma unroll 1
    for (int mt = wv; mt < 13; mt += 4, ++i){
      #pragma unroll
      for (int nt = 0; nt < 2; ++nt){
        #pragma unroll
        for (int r = 0; r < 4; ++r){
          int n = mt*16 + quad*4 + r;
          if (n < 196)
            XO[((size_t)b*196 + n)*256 + h*32 + nt*16 + mrow] = acc[i][nt][r];
        }
      }
    }
  }
}

// ---------- fused depthwise conv: dwc(conv_x2 + qc), bias 2*dwc_b, accumulated into XO ----------
__global__ __launch_bounds__(256) void k_dwc(const float* __restrict__ Y, const float* __restrict__ CMAP,
    const float* __restrict__ dw, const float* __restrict__ db, float* __restrict__ XO){
  int b = blockIdx.x >> 3, cg = blockIdx.x & 7;
  int c0 = cg*32;
  __shared__ __align__(16) float pl[32*360];
  int tid = threadIdx.x;
  for (int t = tid; t < 32*360; t += 256) pl[t] = 0.f;
  __syncthreads();
  const float* yq = Y + (size_t)b*YSTR + QOFF;
  for (int t = tid; t < 32*196; t += 256){
    int cl = t & 31, s = t >> 5;
    int c = c0 + cl;
    int G = s*256 + c;                 // head-major flat index for conv_x2's scramble
    int hh = G / 6272;
    int rem = G - hh*6272;
    int n = rem >> 5, d = rem & 31;
    float cx2 = CMAP[b*256 + c] * yq[n*256 + hh*32 + d];   // sigmoid(cmap)*qs
    float qc  = yq[G];                                     // qc collapses to identity gather
    float v = SCL*(cx2 + qc);
    int i = s/14, j = s - i*14;
    pl[cl*360 + (i+2)*20 + j + 2] = v;
  }
  __syncthreads();
  for (int t = tid; t < 32*14; t += 256){
    int cl = t/14, r = t - cl*14;
    int c = c0 + cl;
    float w25[25];
    #pragma unroll
    for (int u = 0; u < 25; ++u) w25[u] = dw[c*25 + u];
    float acc[14];
    float b2 = 2.f*db[c];
    #pragma unroll
    for (int j = 0; j < 14; ++j) acc[j] = b2;
    conv5x5_row(&pl[cl*360], r, w25, acc);
    float* dst = XO + ((size_t)b*196 + r*14)*256 + c;
    #pragma unroll
    for (int j = 0; j < 14; ++j) dst[j*256] += acc[j];
  }
}

// ---------- final projection: out = XO @ proj_w^T + proj_b ----------
__global__ __launch_bounds__(256) void k_proj(const float* __restrict__ XO, const float* __restrict__ WT,
    const float* __restrict__ pbias, float* __restrict__ OUT){
  int bb = blockIdx.x / 7, nt = blockIdx.x % 7;
  int n0 = nt*28;
  int c = threadIdx.x;
  const float* xb = XO + ((size_t)bb*196 + n0)*256;
  float acc[28];
  #pragma unroll
  for (int r = 0; r < 28; ++r) acc[r] = 0.f;
  for (int k = 0; k < 256; k += 4){
    float w0 = WT[(k+0)*256 + c];
    float w1 = WT[(k+1)*256 + c];
    float w2 = WT[(k+2)*256 + c];
    float w3 = WT[(k+3)*256 + c];
    #pragma unroll
    for (int r = 0; r < 28; ++r){
      float4 xv = *(const float4*)(xb + r*256 + k);   // uniform address -> scalar/L1 path
      acc[r] = fmaf(xv.x, w0, fmaf(xv.y, w1, fmaf(xv.z, w2, fmaf(xv.w, w3, acc[r]))));
    }
  }
  float bv = pbias[c];
  float* dst = OUT + ((size_t)bb*196 + n0)*256 + c;
  #pragma unroll
  for (int r = 0; r < 28; ++r) dst[r*256] = acc[r] + bv;
}

extern "C" void kernel_launch(void* const* d_in, const int* in_sizes, int n_in,
                              void* d_out, int out_size, void* d_ws, size_t ws_size,
                              hipStream_t stream){
  (void)in_sizes; (void)n_in; (void)out_size; (void)ws_size;
  const float* x       = (const float*)d_in[0];
  const float* lka_w   = (const float*)d_in[3];
  const float* lka_b   = (const float*)d_in[4];
  const float* conv5_w = (const float*)d_in[5];
  const float* conv5_b = (const float*)d_in[6];
  const float* caa1_w  = (const float*)d_in[7];
  const float* caa1_b  = (const float*)d_in[8];
  const float* caa2_w  = (const float*)d_in[9];
  const float* caa2_b  = (const float*)d_in[10];
  const float* cam1_w  = (const float*)d_in[11];
  const float* cam1_b  = (const float*)d_in[12];
  const float* cam2_w  = (const float*)d_in[13];
  const float* cam2_b  = (const float*)d_in[14];
  const float* sa_w    = (const float*)d_in[15];
  const float* sa_b    = (const float*)d_in[16];
  const float* ci1_w   = (const float*)d_in[17];
  const float* ci1_b   = (const float*)d_in[18];
  const float* bn_g    = (const float*)d_in[19];
  const float* bn_b    = (const float*)d_in[20];
  const float* ci2_w   = (const float*)d_in[21];
  const float* ci2_b   = (const float*)d_in[22];
  const float* rpbt    = (const float*)d_in[23];
  const float* an_bias = (const float*)d_in[24];
  const float* na_bias = (const float*)d_in[25];
  const float* ah_bias = (const float*)d_in[26];
  const float* aw_bias = (const float*)d_in[27];
  const float* ha_bias = (const float*)d_in[28];
  const float* wa_bias = (const float*)d_in[29];
  const float* dwc_w   = (const float*)d_in[30];
  const float* dwc_b   = (const float*)d_in[31];
  const float* proj_w  = (const float*)d_in[32];
  const float* proj_b  = (const float*)d_in[33];
  float* out = (float*)d_out;
  float* ws = (float*)d_ws;

  float* Y    = ws + WS_Y;
  float* V5   = ws + WS_V5;
  float* AT   = ws + WS_AT;
  float* ATK  = ws + WS_ATK;
  float* CHG  = ws + WS_CHG;
  float* CMAP = ws + WS_CMAP;
  float* PBT  = ws + WS_PBT;
  float* AB   = ws + WS_AB;
  float* X1S  = ws + WS_X1S;
  float* AGV  = ws + WS_AGV;
  float* XO   = ws + WS_XO;
  float* WT   = ws + WS_WT;
  ushort_t* Wh = (ushort_t*)(ws + WS_CWT);

  k_pbab <<<602, 256, 0, stream>>>(an_bias, ah_bias, aw_bias, na_bias, ha_bias, wa_bias, PBT, AB);
  k_wt   <<<256, 256, 0, stream>>>(proj_w, WT);
  k_cw2  <<<6400, 256, 0, stream>>>(conv5_w, Wh);
  k_lka  <<<1024, 256, 0, stream>>>(x, lka_w, lka_b, Y);
  k_conv5<<<512, 256, 0, stream>>>(Y, Wh, conv5_b, V5);
  k_pool <<<256, 256, 0, stream>>>(Y, AT, ATK);
  k_cbam_a<<<128, 256, 0, stream>>>(V5, caa1_w, caa1_b, caa2_w, caa2_b,
                                    cam1_w, cam1_b, cam2_w, cam2_b, CHG);
  k_cbam_b<<<128, 256, 0, stream>>>(V5, CHG, sa_w, sa_b);
  k_attn3<<<1024, 512, 0, stream>>>(Y, rpbt, X1S);
  k_cinter<<<128, 256, 0, stream>>>(X1S, ci1_w, ci1_b, bn_g, bn_b, ci2_w, ci2_b, CMAP);
  k_agentv<<<1024, 256, 0, stream>>>(Y, V5, AT, ATK, PBT, AGV);
  k_xo1  <<<1024, 256, 0, stream>>>(Y, AT, ATK, AB, AGV, XO);
  k_dwc  <<<1024, 256, 0, stream>>>(Y, CMAP, dwc_w, dwc_b, XO);
  k_proj <<<896, 256, 0, stream>>>(XO, WT, proj_b, out);
}

// Round 7
// 803.847 us; speedup vs baseline: 1.0909x; 1.0107x over previous
//
#include <hip/hip_runtime.h>

// Problem constants
#define NB    128
#define NC    256
#define NPOS  196
#define NHEAD 8
#define NAG   49
#define YSTR  150528      // 768*196 per-batch y floats
#define VOFF  50176       // v_raw offset inside y (256*196)
#define QOFF  100352      // q_raw offset inside y (512*196)
#define SCL   0.17677669529663687f   // 32^-0.5

// Workspace layout (floats). Total = 38,885,440 floats = 155.5 MB.
#define WS_Y    0u
#define WS_V5   19267584u
#define WS_AT   25690112u
#define WS_ATK  27295744u
#define WS_CHG  28901376u
#define WS_CMAP 28934144u
#define WS_PBT  28966912u
#define WS_AB   29043744u
#define WS_X1S  29120576u
#define WS_AGV  29153344u
#define WS_XO   30758976u
#define WS_WT   37181504u
#define WS_CWT  37247040u   // Wh: 1.6M ushort (fp16 conv5 weights, [tap][co][ci])

typedef __attribute__((ext_vector_type(8))) _Float16 half8;
typedef __attribute__((ext_vector_type(8))) short short8;
typedef __attribute__((ext_vector_type(4))) short short4v;
typedef __attribute__((ext_vector_type(4))) float f32x4;
typedef unsigned short ushort_t;
typedef unsigned int uint_t;

__device__ __forceinline__ float sigmoidf_(float x){ return 1.0f/(1.0f+__expf(-x)); }

__device__ __forceinline__ ushort_t f2h(float x){
  _Float16 h = (_Float16)x; return __builtin_bit_cast(ushort_t, h);
}
__device__ __forceinline__ float h2f(ushort_t u){
  return (float)__builtin_bit_cast(_Float16, u);
}

// bilinear upsample 7x7 -> 14x14 sample at (i,j), matching reference grid()
__device__ __forceinline__ float bilin7(const float* __restrict__ src, int i, int j){
  float pi = fmaxf(0.5f*(float)i - 0.25f, 0.f);
  int i0 = (int)pi; if (i0 > 6) i0 = 6;
  int i1 = i0 + 1;  if (i1 > 6) i1 = 6;
  float li = pi - (float)i0;
  float pj = fmaxf(0.5f*(float)j - 0.25f, 0.f);
  int j0 = (int)pj; if (j0 > 6) j0 = 6;
  int j1 = j0 + 1;  if (j1 > 6) j1 = 6;
  float lj = pj - (float)j0;
  float v00 = src[i0*7+j0], v01 = src[i0*7+j1];
  float v10 = src[i1*7+j0], v11 = src[i1*7+j1];
  float t0 = v00*(1.f-lj) + v01*lj;
  float t1 = v10*(1.f-lj) + v11*lj;
  return t0*(1.f-li) + t1*li;
}

// 5x5 conv over a zero-padded [18][20] plane, producing one 14-wide output row r.
__device__ __forceinline__ void conv5x5_row(const float* __restrict__ plane, int r,
                                            const float* __restrict__ w25, float* acc14){
  #pragma unroll
  for (int di = 0; di < 5; ++di){
    const float4* pr = (const float4*)(plane + (r+di)*20);
    float4 p0 = pr[0], p1 = pr[1], p2 = pr[2], p3 = pr[3], p4 = pr[4];
    float row[20] = {p0.x,p0.y,p0.z,p0.w, p1.x,p1.y,p1.z,p1.w, p2.x,p2.y,p2.z,p2.w,
                     p3.x,p3.y,p3.z,p3.w, p4.x,p4.y,p4.z,p4.w};
    #pragma unroll
    for (int dj = 0; dj < 5; ++dj){
      float w = w25[di*5+dj];
      #pragma unroll
      for (int j = 0; j < 14; ++j) acc14[j] = fmaf(row[j+dj], w, acc14[j]);
    }
  }
}

// ---------- prep kernels ----------
// merged pb+ab: blocks [0,301) -> PBT, [301,602) -> AB
__global__ void k_pbab(const float* __restrict__ an, const float* __restrict__ ah,
                       const float* __restrict__ aw, const float* __restrict__ na,
                       const float* __restrict__ ha, const float* __restrict__ wa,
                       float* __restrict__ PBT, float* __restrict__ AB){
  int bid = blockIdx.x;
  int which = (bid >= 301);
  int t = (which ? bid - 301 : bid)*256 + threadIdx.x;
  if (t >= NHEAD*NPOS*NAG) return;
  int a = t % NAG;
  int r = t / NAG;
  int n = r % NPOS;
  int h = r / NPOS;
  int i = n/14, j = n - (n/14)*14;
  if (!which){
    float v = bilin7(an + ((size_t)h*NAG + a)*49, i, j);
    v += ah[((size_t)h*NAG + a)*14 + i] + aw[((size_t)h*NAG + a)*14 + j];
    PBT[t] = v;   // [h][n][a]
  } else {
    float v = bilin7(na + ((size_t)h*NAG + a)*49, i, j);
    v += ha[((size_t)h*14 + i)*NAG + a] + wa[((size_t)h*14 + j)*NAG + a];
    AB[t] = v;    // [h][n][a]
  }
}

__global__ void k_wt(const float* __restrict__ pw, float* __restrict__ WT){
  int t = blockIdx.x*256 + threadIdx.x;
  if (t >= 65536) return;
  int k = t >> 8, c = t & 255;
  WT[t] = pw[c*256 + k];          // WT[k][c] = proj_w[c][k]
}

// conv5 weights -> fp16, layout [tap][co][ci]
__global__ void k_cw2(const float* __restrict__ cw, ushort_t* __restrict__ Wh){
  int t = blockIdx.x*256 + threadIdx.x;
  if (t >= 1638400) return;
  int ci = t & 255;
  int r  = t >> 8;
  int co = r & 255;
  int tap = r >> 8;
  Wh[t] = f2h(cw[((size_t)co*256 + ci)*25 + tap]);
}

// ---------- lka depthwise-ish conv (groups=256, 3 outputs per input channel) ----------
__global__ __launch_bounds__(256) void k_lka(const float* __restrict__ x, const float* __restrict__ lw,
                                             const float* __restrict__ lb, float* __restrict__ Y){
  int b = blockIdx.x >> 3, gb = blockIdx.x & 7;
  int g0 = gb*32;                               // input channels [g0,g0+32)
  __shared__ __align__(16) float pl[32*360];    // [ch][18*20] padded planes
  int tid = threadIdx.x;
  for (int t = tid; t < 32*360; t += 256) pl[t] = 0.f;
  __syncthreads();
  for (int t = tid; t < 32*196; t += 256){
    int gl = t & 31, s = t >> 5;
    int i = s/14, j = s - i*14;
    pl[gl*360 + (i+2)*20 + j + 2] = x[((size_t)b*196 + s)*256 + g0 + gl];
  }
  __syncthreads();
  for (int t = tid; t < 96*14; t += 256){
    int ocl = t/14, r = t - ocl*14;
    int o  = g0*3 + ocl;          // output channel; uses input channel o/3
    int gl = ocl/3;
    float w25[25];
    #pragma unroll
    for (int u = 0; u < 25; ++u) w25[u] = lw[o*25 + u];
    float acc[14];
    float bv = lb[o];
    #pragma unroll
    for (int j = 0; j < 14; ++j) acc[j] = bv;
    conv5x5_row(&pl[gl*360], r, w25, acc);
    float* dst = Y + ((size_t)b*768 + o)*196 + r*14;
    #pragma unroll
    for (int j = 0; j < 14; ++j) dst[j] = acc[j];
  }
}

// ---------- conv5 via fp16 MFMA implicit GEMM, W double-buffered ----------
// Round-6 compute (natural 80B-row addressing: 16B-slot = (5*row+chunk) mod 8,
// conflict-free permutation) with ONE barrier per di-step instead of two:
// W for step u+1 is prefetched into registers (latency hides under compute of
// step u) and written into Wsm[(u+1)&1] right after compute(u) -- safe because
// that buffer's last readers (compute(u-1)) are fenced by step u's barrier.
// Barriers/block: 88 -> 48. Epilogue T unions onto Wsm buffer 0 (last read at
// compute(u=38), fenced by the epilogue barrier). LDS total 80.0KB (unchanged
// -> still 2 blocks/CU).
__global__ __launch_bounds__(256, 2) void k_conv5(const float* __restrict__ Y,
    const ushort_t* __restrict__ Wh, const float* __restrict__ cb, float* __restrict__ V5){
  int b = blockIdx.x >> 2, cog = blockIdx.x & 3;
  int co0 = cog*64;
  __shared__ __align__(16) ushort_t Pt[360*40];       // fp16 A: [pos][4 chunks of 8ci + pad]
  __shared__ __align__(16) ushort_t Wsm[2*5*64*40];   // fp16 B, double-buffered
  float* T = (float*)Wsm;                             // epilogue transpose (25600B = buffer 0)
  int tid  = threadIdx.x;
  int lane = tid & 63, wv = tid >> 6;
  int mrow = lane & 15, quad = lane >> 4;

  // zero-fill Pt once; borders stay zero across chunks
  for (int t = tid; t < 7200; t += 256) ((uint_t*)Pt)[t] = 0;

  // per-lane A plane-row base per m-tile (unpadded base; taps add di*20+dj)
  int prow[4];
  #pragma unroll
  for (int mt = 0; mt < 4; ++mt){
    int s = wv*64 + mt*16 + mrow;
    int p0 = 0;
    if (s < 196){ int i = s/14, j = s - i*14; p0 = i*20 + j; }
    prow[mt] = p0;
  }

  f32x4 acc[4][4];
  #pragma unroll
  for (int mt = 0; mt < 4; ++mt)
    #pragma unroll
    for (int nt = 0; nt < 4; ++nt) acc[mt][nt] = (f32x4){0.f,0.f,0.f,0.f};

  const float* src = Y + (size_t)b*YSTR + VOFF;   // v_raw [ci][s]
  int wco = tid >> 2, wpart = tid & 3;            // W-staging roles
  const ushort_t* wbase = Wh + ((size_t)(co0 + wco))*256 + wpart*8;  // + tap*65536 + cc*32

  // prologue: prefetch W for (cc=0, di=0)
  short8 wreg[5];
  #pragma unroll
  for (int tp = 0; tp < 5; ++tp)
    wreg[tp] = *(const short8*)(wbase + (size_t)tp*65536);

  #pragma unroll 1
  for (int cc = 0; cc < 8; ++cc){
    __syncthreads();              // Pt free to overwrite (prev cc compute done)
    // stage A: 784 (pos, chunk) items; each thread packs 8 ci -> one b128 write
    // at slot (5p + ch) mod 8: conflict-free permutation, matches read layout.
    for (int t = tid; t < 784; t += 256){
      int pos = t >> 2, ch = t & 3;
      int i = pos/14, j = pos - i*14;
      int p = (i+2)*20 + j + 2;
      const float* s0 = src + (size_t)(cc*32 + ch*8)*196 + pos;
      short8 pk;
      #pragma unroll
      for (int e = 0; e < 4; ++e){
        float v0 = s0[(2*e)*196];
        float v1 = s0[(2*e+1)*196];
        pk[2*e]   = (short)f2h(v0);
        pk[2*e+1] = (short)f2h(v1);
      }
      *(short8*)&Pt[p*40 + ch*8] = pk;
    }
    #pragma unroll 1
    for (int di = 0; di < 5; ++di){
      int u = cc*5 + di;
      ushort_t* wbuf = Wsm + (u & 1)*12800;
      // write prefetched W regs -> Wsm[u&1] (other buffer in use by compute(u-1))
      #pragma unroll
      for (int tp = 0; tp < 5; ++tp)
        *(short8*)&wbuf[(tp*64 + wco)*40 + wpart*8] = wreg[tp];
      // prefetch W for step u+1 (hides under the compute below)
      if (u < 39){
        int di1 = di + 1, cc1 = cc;
        if (di1 == 5){ di1 = 0; ++cc1; }
        #pragma unroll
        for (int tp = 0; tp < 5; ++tp)
          wreg[tp] = *(const short8*)(wbase + (size_t)(di1*5 + tp)*65536 + cc1*32);
      }
      __syncthreads();      // fences A writes (di=0) and this step's W writes
      #pragma unroll
      for (int dj = 0; dj < 5; ++dj){
        half8 a[4], bb[4];
        #pragma unroll
        for (int nt = 0; nt < 4; ++nt){
          int co = nt*16 + mrow;
          bb[nt] = *(const half8*)&wbuf[(dj*64 + co)*40 + quad*8];
        }
        #pragma unroll
        for (int mt = 0; mt < 4; ++mt){
          int p = prow[mt] + di*20 + dj;
          a[mt] = *(const half8*)&Pt[p*40 + quad*8];
        }
        #pragma unroll
        for (int mt = 0; mt < 4; ++mt)
          #pragma unroll
          for (int nt = 0; nt < 4; ++nt)
            acc[mt][nt] = __builtin_amdgcn_mfma_f32_16x16x32_f16(a[mt], bb[nt], acc[mt][nt], 0, 0, 0);
      }
    }
  }

  // epilogue: transpose through LDS (T = Wsm buffer 0), stores into scrambled v5
  #pragma unroll
  for (int hf = 0; hf < 2; ++hf){
    __syncthreads();
    #pragma unroll
    for (int ntl = 0; ntl < 2; ++ntl){
      int nt = hf*2 + ntl;
      int col = ntl*16 + mrow;            // co local within half (0..31)
      #pragma unroll
      for (int mt = 0; mt < 4; ++mt){
        int sbase = wv*64 + mt*16 + quad*4;
        #pragma unroll
        for (int r = 0; r < 4; ++r){
          int s = sbase + r;
          if (s < 196) T[col*200 + s] = acc[mt][nt][r];
        }
      }
    }
    __syncthreads();
    for (int t = tid; t < 6272; t += 256){
      int cl = t / 196;                   // co local 0..31
      int f = (co0 + hf*32)*196 + t;
      float val = T[t + cl*4] + cb[co0 + hf*32 + cl];
      V5[(size_t)b*50176 + (size_t)(f & 255)*196 + (f >> 8)] = val;
    }
  }
}

// ---------- agent token pooling (256 blocks: channel-half x agent-half split) ----------
__global__ __launch_bounds__(256) void k_pool(const float* __restrict__ Y, float* __restrict__ AT, float* __restrict__ ATK){
  int b = blockIdx.x >> 1, half = blockIdx.x & 1;
  int c = (threadIdx.x & 127) + half*128;
  int a0 = (threadIdx.x >> 7) ? 25 : 0;
  int a1 = (threadIdx.x >> 7) ? 49 : 25;
  const float* qp = Y + ((size_t)b*768 + 512 + c)*196;
  const float* kp = Y + ((size_t)b*768 + c)*196;
  for (int a = a0; a < a1; ++a){
    int p1 = a/7, p2 = a - p1*7;
    int s = p1*28 + p2*2;
    float q0 = qp[s], q1 = qp[s+1], q2 = qp[s+14], q3 = qp[s+15];
    AT[((size_t)b*49 + a)*256 + c] = 0.25f*(q0+q1+q2+q3);
    float k0 = kp[s], k1 = kp[s+1], k2 = kp[s+14], k3 = kp[s+15];
    ATK[((size_t)b*49 + a)*256 + c] = fmaxf(fmaxf(k0,k1), fmaxf(k2,k3));
  }
}

// ---------- cbam stage A: channel gate ----------
__global__ __launch_bounds__(256) void k_cbam_a(const float* __restrict__ V5,
    const float* __restrict__ caa1w, const float* __restrict__ caa1b,
    const float* __restrict__ caa2w, const float* __restrict__ caa2b,
    const float* __restrict__ cam1w, const float* __restrict__ cam1b,
    const float* __restrict__ cam2w, const float* __restrict__ cam2b,
    float* __restrict__ CHG){
  int b = blockIdx.x, c = threadIdx.x;
  __shared__ float avg[256], mx[256], t1[16], t2[16];
  const float* pp = V5 + ((size_t)b*256 + c)*196;
  float s = 0.f, m = -1e30f;
  for (int i = 0; i < 196; ++i){ float v = pp[i]; s += v; m = fmaxf(m, v); }
  avg[c] = s * (1.0f/196.0f); mx[c] = m;
  __syncthreads();
  if (c < 16){
    float a1 = caa1b[c], a2 = cam1b[c];
    #pragma unroll 4
    for (int k = 0; k < 256; ++k){
      a1 = fmaf(caa1w[(c*256 + k)*9 + 4], avg[k], a1);   // 3x3 center tap
      a2 = fmaf(cam1w[c*256 + k], mx[k], a2);            // 1x1
    }
    t1[c] = fmaxf(a1, 0.f);
    t2[c] = fmaxf(a2, 0.f);
  }
  __syncthreads();
  float y1 = caa2b[c], y2 = cam2b[c];
  #pragma unroll
  for (int k = 0; k < 16; ++k){
    y1 = fmaf(caa2w[(c*16 + k)*9 + 4], t1[k], y1);
    y2 = fmaf(cam2w[c*16 + k], t2[k], y2);
  }
  CHG[b*256 + c] = sigmoidf_(sigmoidf_(y1) + sigmoidf_(y2));
}

// ---------- cbam stage B: spatial mask (9x9 pad4 over [mean,max]) + in-place gate ----------
__global__ __launch_bounds__(256) void k_cbam_b(float* __restrict__ V5, const float* __restrict__ CHG,
    const float* __restrict__ saw, const float* __restrict__ sab){
  int b = blockIdx.x; int tid = threadIdx.x;
  __shared__ float chg[256];
  __shared__ float mp[22*22], xp[22*22];
  __shared__ float mk[196];
  chg[tid] = CHG[b*256 + tid];
  for (int t = tid; t < 484; t += 256){ mp[t] = 0.f; xp[t] = 0.f; }
  __syncthreads();
  if (tid < 196){
    int i = tid/14, j = tid - i*14;
    float s = 0.f, m = -1e30f;
    const float* vb = V5 + (size_t)b*256*196 + tid;
    for (int c = 0; c < 256; ++c){
      float v = chg[c] * vb[c*196];
      s += v; m = fmaxf(m, v);
    }
    mp[(i+4)*22 + j+4] = s*(1.f/256.f);
    xp[(i+4)*22 + j+4] = m;
  }
  __syncthreads();
  if (tid < 196){
    int i = tid/14, j = tid - i*14;
    float acc = sab[0];
    for (int di = 0; di < 9; ++di){
      #pragma unroll
      for (int dj = 0; dj < 9; ++dj){
        acc = fmaf(mp[(i+di)*22 + j+dj], saw[di*9+dj], acc);
        acc = fmaf(xp[(i+di)*22 + j+dj], saw[81 + di*9+dj], acc);
      }
    }
    mk[tid] = sigmoidf_(acc);
  }
  __syncthreads();
  if (tid < 196){
    float m = mk[tid];
    float* vb = V5 + (size_t)b*256*196 + tid;
    for (int c = 0; c < 256; ++c) vb[c*196] = chg[c]*vb[c*196]*m;
  }
}

// ---------- big NxN attention via MFMA, 3-segment version ----------
// x1s[c] = (1/196) sum_j w[j] V[j][c],  w[j] = sum_n e[n][j] / l[n].
// n-tiles (13) processed in segments {5,4,4} so E shrinks [196][208]->[80][208]
// (81.5KB -> 33KB; total LDS ~74KB -> 2 blocks/CU instead of 1). Per segment:
// warps 2k/2k+1 split each n-column's 13 mt-tiles 7/6 (both halves of lsum in
// pl2); then wpart row-groups accumulate wj += E*invl. Work identical to the
// single-segment version; only fp32 summation grouping differs.
__global__ __launch_bounds__(512, 4) void k_attn3(const float* __restrict__ Y,
    const float* __restrict__ rpbt, float* __restrict__ X1S){
  int b = blockIdx.x >> 3, h = blockIdx.x & 7;
  __shared__ __align__(16) ushort_t Qh[208*32];    // fp16 q*SCL rows, chunk-swizzled
  __shared__ __align__(16) ushort_t Kh[208*32];    // fp16 k rows, chunk-swizzled
  __shared__ __align__(16) ushort_t E[80*208];     // fp16 exp-scores [n-local][j]
  __shared__ float rp[736];
  __shared__ int   rpo[208];
  __shared__ float pl2[80][2];                     // lsum halves per row
  __shared__ float invl[80];
  __shared__ float wj[208];
  __shared__ float wpart[8][208];
  __shared__ float xpart[16][32];
  int tid = threadIdx.x, wv = tid >> 6, lane = tid & 63;
  int mrow = lane & 15, quad = lane >> 4;
  int sw8 = ((quad ^ ((mrow >> 1) & 3)) << 3);     // 64B-row read swizzle
  const float* yb = Y + (size_t)b*YSTR;

  // ---- tables + staging ----
  for (int t = tid; t < 736; t += 512) rp[t] = (t < 729) ? rpbt[t*8 + h] : 0.f;
  for (int j = tid; j < 208; j += 512){
    int jc = (j < 196) ? j : 195;
    int rj = jc/14;
    rpo[j] = rj*27 + (jc - rj*14);
    wj[j] = 0.f;
  }
  for (int t = tid; t < 384; t += 512){            // zero rows 196..207 of Qh/Kh
    int arr = t >= 192; int u = t - arr*192;
    ((uint_t*)(arr ? Kh : Qh))[3136 + u] = 0;
  }
  for (int t = tid; t < 3136; t += 512){
    int n = t >> 4, w = t & 15;
    int ws = (((w >> 2) ^ ((n >> 1) & 3)) << 2) | (w & 3);
    const float2 qv = *(const float2*)(yb + QOFF + (size_t)n*256 + h*32 + (w << 1));
    ((uint_t*)Qh)[n*16 + ws] = (uint_t)f2h(qv.x*SCL) | ((uint_t)f2h(qv.y*SCL) << 16);
    const float2 kv = *(const float2*)(yb + (size_t)n*256 + h*32 + (w << 1));
    ((uint_t*)Kh)[n*16 + ws] = (uint_t)f2h(kv.x) | ((uint_t)f2h(kv.y) << 16);
  }
  __syncthreads();

  int mt0 = (wv & 1) ? 7 : 0;
  int mt1 = (wv & 1) ? 13 : 7;

  #pragma unroll 1
  for (int seg = 0; seg < 3; ++seg){
    int base = (seg == 0) ? 0 : (seg == 1) ? 80 : 144;
    int ntl  = (seg == 0) ? 5 : 4;
    int segrows = ntl*16;
    int vrows = 196 - base; if (vrows > segrows) vrows = segrows;

    // ---- phase A: logits, E-store, row-sum halves ----
    #pragma unroll 1
    for (int ncl = (wv >> 1); ncl < ntl; ncl += 4){
      int n = base + ncl*16 + mrow;
      half8 bfr = *(const half8*)&Qh[n*32 + sw8];
      int nclamp = (n < 196) ? n : 195;
      int rin = nclamp/14, cin = nclamp - rin*14;
      int bidxn = (rin + 13)*27 + (cin + 13);
      float lsum = 0.f;
      #pragma unroll 1
      for (int mt = mt0; mt < mt1; ++mt){
        half8 afr = *(const half8*)&Kh[(mt*16 + mrow)*32 + sw8];
        f32x4 c = (f32x4){0.f,0.f,0.f,0.f};
        c = __builtin_amdgcn_mfma_f32_16x16x32_f16(afr, bfr, c, 0, 0, 0);
        int j0 = mt*16 + quad*4;
        int4 ro = *(const int4*)&rpo[j0];
        short4v pk;
        #pragma unroll
        for (int r = 0; r < 4; ++r){
          int j = j0 + r;
          int roff = (r == 0) ? ro.x : (r == 1) ? ro.y : (r == 2) ? ro.z : ro.w;
          float e = (j < 196) ? __expf(c[r] + rp[bidxn - roff]) : 0.f;
          lsum += e;
          pk[r] = (short)f2h(e);
        }
        if (n < 196) *(short4v*)&E[(n - base)*208 + j0] = pk;
      }
      lsum += __shfl_xor(lsum, 16);
      lsum += __shfl_xor(lsum, 32);
      if (quad == 0) pl2[n - base][wv & 1] = lsum;
    }
    __syncthreads();
    for (int t = tid; t < vrows; t += 512) invl[t] = 1.f/(pl2[t][0] + pl2[t][1]);
    __syncthreads();

    // ---- phase B: wpart[g][j] = sum over rows (g+8k) of E*invl ----
    {
      int j0 = lane*4;
      if (j0 < 208){
        float a0=0.f,a1=0.f,a2=0.f,a3=0.f;
        #pragma unroll 1
        for (int nl = wv; nl < vrows; nl += 8){
          float iv = invl[nl];
          short4v ev = *(const short4v*)&E[nl*208 + j0];
          a0 = fmaf(h2f((ushort_t)ev[0]), iv, a0);
          a1 = fmaf(h2f((ushort_t)ev[1]), iv, a1);
          a2 = fmaf(h2f((ushort_t)ev[2]), iv, a2);
          a3 = fmaf(h2f((ushort_t)ev[3]), iv, a3);
        }
        *(f32x4*)&wpart[wv][j0] = (f32x4){a0,a1,a2,a3};
      }
    }
    __syncthreads();
    for (int j = tid; j < 208; j += 512){
      float s = wj[j];
      #pragma unroll
      for (int g = 0; g < 8; ++g) s += wpart[g][j];
      wj[j] = s;
    }
    __syncthreads();   // wpart/E/pl2/invl free for next segment
  }

  // ---- X1S[c] = (1/196) sum_j wj[j] * V[j][c] ----
  {
    int d = tid & 31, g = tid >> 5;                // 16 groups x 13 j's
    float s = 0.f;
    #pragma unroll 1
    for (int u = 0; u < 13; ++u){
      int j = g*13 + u;
      s = fmaf(wj[j], yb[VOFF + (size_t)j*256 + h*32 + d], s);
    }
    xpart[g][d] = s;
  }
  __syncthreads();
  if (tid < 32){
    float s = 0.f;
    #pragma unroll
    for (int g2 = 0; g2 < 16; ++g2) s += xpart[g2][tid];
    X1S[(size_t)b*256 + h*32 + tid] = s*(1.f/196.f);
  }
}

// ---------- chan_inter on x1 mean -> sigmoid gate CMAP ----------
__global__ __launch_bounds__(256) void k_cinter(const float* __restrict__ X1S,
    const float* __restrict__ ci1w, const float* __restrict__ ci1b,
    const float* __restrict__ bng, const float* __restrict__ bnb,
    const float* __restrict__ ci2w, const float* __restrict__ ci2b, float* __restrict__ CMAP){
  int b = blockIdx.x, c = threadIdx.x;
  __shared__ float p[256], tt[16];
  p[c] = X1S[b*256 + c];
  __syncthreads();
  if (c < 16){
    float a = ci1b[c];
    #pragma unroll 4
    for (int k = 0; k < 256; ++k) a = fmaf(ci1w[(c*256+k)*25 + 12], p[k], a);  // 5x5 center
    const float invs = 0.9999950000375f;   // 1/sqrt(1+1e-5)
    tt[c] = fmaxf(fmaf(bng[c]*invs, a, bnb[c]), 0.f);
  }
  __syncthreads();
  float a = ci2b[c];
  #pragma unroll
  for (int k = 0; k < 16; ++k) a = fmaf(ci2w[(c*16+k)*25 + 12], tt[k], a);
  CMAP[b*256 + c] = sigmoidf_(a);
}

// ---------- agent_v via fp16 MFMA ----------
// Kh/Ah rows are 64B (even stride): reads use a bijective chunk swizzle
// chunk ^= (row>>1)&3 (write side mirrors it) so an 8-lane b128 phase hits
// 8 distinct 16B slots: slot = 4*(row&1) + quad^((row>>1)&3) is a permutation.
__global__ __launch_bounds__(256) void k_agentv(const float* __restrict__ Y, const float* __restrict__ V5,
    const float* __restrict__ AT, const float* __restrict__ ATK,
    const float* __restrict__ PBT, float* __restrict__ AGV){
  int b = blockIdx.x >> 3, h = blockIdx.x & 7;
  __shared__ __align__(16) ushort_t ST[64*232];   // exp-scores, [a][n pad 232]
  __shared__ __align__(16) ushort_t R[8704];      // staging region (17408 B)
  __shared__ float psum[4*64];
  __shared__ float inv0s[64], inv1s[64];
  int tid = threadIdx.x, wv = tid >> 6, lane = tid & 63;
  int mrow = lane & 15, quad = lane >> 4;
  int sw8 = ((quad ^ ((mrow >> 1) & 3)) << 3);    // read-side chunk swizzle (rows = 16*t + mrow)
  const float* yb = Y + (size_t)b*YSTR;
  ushort_t* Kh = R;            // [208][32] fp16 rows (K or Q), chunk-swizzled
  ushort_t* Ah = R + 6656;     // [64][32] fp16 rows (AT or ATK), chunk-swizzled
  ushort_t* Vt = R;            // [32][232] fp16 rows (V1 or V)
  f32x4 out0[2], out1[2];

  // ---- one-time zero fills: ST cols 208..223 (cols 224-231 never read) ----
  for (int t = tid; t < 512; t += 256){      // 64 rows x 16 cols /2 per uint
    int a = t >> 3, c2 = 208 + ((t & 7) << 1);
    *(uint_t*)&ST[a*232 + c2] = 0;
  }

  #pragma unroll 1
  for (int pass = 0; pass < 2; ++pass){
    // ---- stage rows (K|Q into Kh; AT|ATK into Ah), zero pads ----
    for (int t = tid; t < 192; t += 256) ((uint_t*)Kh)[3136 + t] = 0;   // rows 196-207
    for (int t = tid; t < 240; t += 256) ((uint_t*)Ah)[784 + t] = 0;    // rows 49-63
    {
      const float* rsrc = yb + (pass ? QOFF : 0) + h*32;
      for (int t = tid; t < 3136; t += 256){
        int n = t >> 4, w = t & 15;
        const float2 v = *(const float2*)(rsrc + (size_t)n*256 + (w << 1));
        int ws = (((w >> 2) ^ ((n >> 1) & 3)) << 2) | (w & 3);
        ((uint_t*)Kh)[n*16 + ws] = (uint_t)f2h(v.x) | ((uint_t)f2h(v.y) << 16);
      }
      const float* asrc = (pass ? ATK : AT) + (size_t)b*49*256 + h*32;
      for (int t = tid; t < 784; t += 256){
        int a = t >> 4, w = t & 15;
        const float2 v = *(const float2*)(asrc + (size_t)a*256 + (w << 1));
        int ws = (((w >> 2) ^ ((a >> 1) & 3)) << 2) | (w & 3);
        ((uint_t*)Ah)[a*16 + ws] = (uint_t)f2h(v.x) | ((uint_t)f2h(v.y) << 16);
      }
    }
    __syncthreads();
    // ---- logits: ntile = wv; 13 mtiles; exp(+pb) -> ST[a][n] ----
    {
      float lscl = pass ? 0.03125f : SCL;
      int ag = wv*16 + mrow;                 // agent (C col)
      half8 bfr = *(const half8*)&Ah[ag*32 + sw8];
      #pragma unroll 1
      for (int mt = 0; mt < 13; ++mt){
        half8 afr = *(const half8*)&Kh[(mt*16 + mrow)*32 + sw8];
        f32x4 c = (f32x4){0.f,0.f,0.f,0.f};
        c = __builtin_amdgcn_mfma_f32_16x16x32_f16(afr, bfr, c, 0, 0, 0);
        int n0 = mt*16 + quad*4;
        short4v pk;
        #pragma unroll
        for (int r = 0; r < 4; ++r){
          int n = n0 + r;
          float pb = PBT[((size_t)h*196 + n)*49 + ag];
          float e = (n < 196) ? __expf(fmaf(c[r], lscl, pb)) : 0.f;
          pk[r] = (short)f2h(e);
        }
        *(short4v*)&ST[ag*232 + n0] = pk;
      }
    }
    __syncthreads();
    // ---- denominators + stage V ----
    {
      int a = tid >> 2, q = tid & 3;
      float s = 0.f;
      #pragma unroll
      for (int u = 0; u < 7; ++u){
        short8 v8 = *(const short8*)&ST[a*232 + q*56 + u*8];
        #pragma unroll
        for (int e = 0; e < 8; ++e) s += h2f((ushort_t)v8[e]);
      }
      psum[q*64 + a] = s;
    }
    if (pass == 0){
      const float* vsrc = V5 + (size_t)b*50176 + h*32*196;   // [d][196]
      for (int t = tid; t < 3136; t += 256){
        int d = t / 98, np = t - (t/98)*98;
        const float2 v = *(const float2*)(vsrc + (size_t)d*196 + 2*np);
        *(uint_t*)&Vt[d*232 + 2*np] = (uint_t)f2h(v.x) | ((uint_t)f2h(v.y) << 16);
      }
    } else {
      const float* vsrc = yb + VOFF + h*32;                  // [n][256]
      for (int t = tid; t < 3136; t += 256){
        int d = t / 98, np = t - (t/98)*98;
        float v0 = vsrc[(size_t)(2*np)*256 + d];
        float v1 = vsrc[(size_t)(2*np+1)*256 + d];
        *(uint_t*)&Vt[d*232 + 2*np] = (uint_t)f2h(v0) | ((uint_t)f2h(v1) << 16);
      }
    }
    for (int t = tid; t < 448; t += 256){    // zero V cols 196..223
      int d = t / 14, c2 = 196 + 2*(t - (t/14)*14);
      *(uint_t*)&Vt[d*232 + c2] = 0;
    }
    __syncthreads();
    // ---- PV: mtile = wv (a rows); ntile 0..1 (d cols); 7 k-steps ----
    {
      f32x4* outp = pass ? out1 : out0;
      #pragma unroll
      for (int nt = 0; nt < 2; ++nt){
        f32x4 c = (f32x4){0.f,0.f,0.f,0.f};
        #pragma unroll
        for (int ks = 0; ks < 7; ++ks){
          half8 afr = *(const half8*)&ST[(wv*16 + mrow)*232 + ks*32 + quad*8];
          half8 bfr = *(const half8*)&Vt[(nt*16 + mrow)*232 + ks*32 + quad*8];
          c = __builtin_amdgcn_mfma_f32_16x16x32_f16(afr, bfr, c, 0, 0, 0);
        }
        outp[nt] = c;
      }
      if (tid < 64){
        float s = psum[tid] + psum[64+tid] + psum[128+tid] + psum[192+tid];
        float* invp = pass ? inv1s : inv0s;
        invp[tid] = 1.f / s;
      }
    }
    __syncthreads();   // ST/Vt free for next pass; inv visible
  }
  // ---- epilogue: combine + scatter ----
  #pragma unroll
  for (int nt = 0; nt < 2; ++nt){
    int d = nt*16 + mrow;
    #pragma unroll
    for (int r = 0; r < 4; ++r){
      int a = wv*16 + quad*4 + r;
      if (a < 49)
        AGV[(((size_t)(b*8 + h)*49) + a)*32 + d] = out0[nt][r]*inv0s[a] + out1[nt][r]*inv1s[a];
    }
  }
}

// ---------- xo1 via fp16 MFMA ----------
__global__ __launch_bounds__(256) void k_xo1(const float* __restrict__ Y,
    const float* __restrict__ AT, const float* __restrict__ ATK,
    const float* __restrict__ AB, const float* __restrict__ AGV, float* __restrict__ XO){
  int b = blockIdx.x >> 3, h = blockIdx.x & 7;
  __shared__ __align__(16) ushort_t ST[208*72];   // exp-scores [n][a pad 72]
  __shared__ __align__(16) ushort_t Kh[208*32];   // Q or K rows fp16, chunk-swizzled
  __shared__ __align__(16) ushort_t Ah[64*32];    // AT or ATK rows fp16, chunk-swizzled
  __shared__ __align__(16) ushort_t AGVt[32*64];  // AGV^T [d][a], chunk-swizzled
  __shared__ float invs[208];
  int tid = threadIdx.x, wv = tid >> 6, lane = tid & 63;
  int mrow = lane & 15, quad = lane >> 4;
  int sw8 = ((quad ^ ((mrow >> 1) & 3)) << 3);    // 64B-row read swizzle
  const float* yb = Y + (size_t)b*YSTR;
  f32x4 acc[4][2];
  #pragma unroll
  for (int i = 0; i < 4; ++i){
    acc[i][0] = (f32x4){0.f,0.f,0.f,0.f};
    acc[i][1] = (f32x4){0.f,0.f,0.f,0.f};
  }

  for (int t = tid; t < 1664; t += 256){
    int rw = t >> 3, c2 = 48 + ((t & 7) << 1);
    *(uint_t*)&ST[rw*72 + c2] = 0;
  }
  {
    const float* agvb = AGV + (size_t)(b*8 + h)*49*32;
    for (int t = tid; t < 2048; t += 256){
      int d = t >> 6, a = t & 63;
      int as = ((((a >> 3) ^ (d & 7)) & 7) << 3) | (a & 7);
      AGVt[d*64 + as] = (a < 49) ? f2h(agvb[a*32 + d]) : (ushort_t)0;
    }
  }

  #pragma unroll 1
  for (int pass = 0; pass < 2; ++pass){
    {
      const float* rsrc = yb + (pass ? 0 : QOFF) + h*32;
      for (int t = tid; t < 3136; t += 256){
        int n = t >> 4, w = t & 15;
        const float2 v = *(const float2*)(rsrc + (size_t)n*256 + (w << 1));
        int ws = (((w >> 2) ^ ((n >> 1) & 3)) << 2) | (w & 3);
        ((uint_t*)Kh)[n*16 + ws] = (uint_t)f2h(v.x) | ((uint_t)f2h(v.y) << 16);
      }
      const float* asrc = (pass ? ATK : AT) + (size_t)b*49*256 + h*32;
      for (int t = tid; t < 784; t += 256){
        int a = t >> 4, w = t & 15;
        const float2 v = *(const float2*)(asrc + (size_t)a*256 + (w << 1));
        int ws = (((w >> 2) ^ ((a >> 1) & 3)) << 2) | (w & 3);
        ((uint_t*)Ah)[a*16 + ws] = (uint_t)f2h(v.x) | ((uint_t)f2h(v.y) << 16);
      }
    }
    __syncthreads();
    {
      float lscl = pass ? SCL : 0.03125f;
      int ag = wv*16 + mrow;
      half8 bfr = *(const half8*)&Ah[ag*32 + sw8];
      #pragma unroll 1
      for (int mt = 0; mt < 13; ++mt){
        half8 afr = *(const half8*)&Kh[(mt*16 + mrow)*32 + sw8];
        f32x4 c = (f32x4){0.f,0.f,0.f,0.f};
        c = __builtin_amdgcn_mfma_f32_16x16x32_f16(afr, bfr, c, 0, 0, 0);
        #pragma unroll
        for (int r = 0; r < 4; ++r){
          int n = mt*16 + quad*4 + r;
          if (n < 196 && ag < 49){
            float e = __expf(fmaf(c[r], lscl, AB[((size_t)h*196 + n)*49 + ag]));
            ST[n*72 + ag] = f2h(e);
          }
        }
      }
    }
    __syncthreads();
    if (tid < 196){
      float s = 0.f;
      #pragma unroll
      for (int u = 0; u < 7; ++u){
        short8 v8 = *(const short8*)&ST[tid*72 + u*8];
        #pragma unroll
        for (int e = 0; e < 8; ++e) s += h2f((ushort_t)v8[e]);
      }
      invs[tid] = 1.f / s;
    }
    __syncthreads();
    {
      int i = 0;
      #pragma unroll 1
      for (int mt = wv; mt < 13; mt += 4, ++i){
        #pragma unroll
        for (int nt = 0; nt < 2; ++nt){
          f32x4 c = (f32x4){0.f,0.f,0.f,0.f};
          #pragma unroll
          for (int ks = 0; ks < 2; ++ks){
            half8 afr = *(const half8*)&ST[(mt*16 + mrow)*72 + ks*32 + quad*8];
            half8 bfr = *(const half8*)&AGVt[(nt*16 + mrow)*64 + ((((ks*4 + quad) ^ (mrow & 7)) & 7) << 3)];
            c = __builtin_amdgcn_mfma_f32_16x16x32_f16(afr, bfr, c, 0, 0, 0);
          }
          #pragma unroll
          for (int r = 0; r < 4; ++r){
            int n = mt*16 + quad*4 + r;
            if (n < 196) acc[i][nt][r] = fmaf(c[r], invs[n], acc[i][nt][r]);
          }
        }
      }
    }
    __syncthreads();
  }
  {
    int i = 0;
    #pragma unroll 1
    for (int mt = wv; mt < 13; mt += 4, ++i){
      #pragma unroll
      for (int nt = 0; nt < 2; ++nt){
        #pragma unroll
        for (int r = 0; r < 4; ++r){
          int n = mt*16 + quad*4 + r;
          if (n < 196)
            XO[((size_t)b*196 + n)*256 + h*32 + nt*16 + mrow] = acc[i][nt][r];
        }
      }
    }
  }
}

// ---------- fused depthwise conv: dwc(conv_x2 + qc), bias 2*dwc_b, accumulated into XO ----------
__global__ __launch_bounds__(256) void k_dwc(const float* __restrict__ Y, const float* __restrict__ CMAP,
    const float* __restrict__ dw, const float* __restrict__ db, float* __restrict__ XO){
  int b = blockIdx.x >> 3, cg = blockIdx.x & 7;
  int c0 = cg*32;
  __shared__ __align__(16) float pl[32*360];
  int tid = threadIdx.x;
  for (int t = tid; t < 32*360; t += 256) pl[t] = 0.f;
  __syncthreads();
  const float* yq = Y + (size_t)b*YSTR + QOFF;
  for (int t = tid; t < 32*196; t += 256){
    int cl = t & 31, s = t >> 5;
    int c = c0 + cl;
    int G = s*256 + c;                 // head-major flat index for conv_x2's scramble
    int hh = G / 6272;
    int rem = G - hh*6272;
    int n = rem >> 5, d = rem & 31;
    float cx2 = CMAP[b*256 + c] * yq[n*256 + hh*32 + d];   // sigmoid(cmap)*qs
    float qc  = yq[G];                                     // qc collapses to identity gather
    float v = SCL*(cx2 + qc);
    int i = s/14, j = s - i*14;
    pl[cl*360 + (i+2)*20 + j + 2] = v;
  }
  __syncthreads();
  for (int t = tid; t < 32*14; t += 256){
    int cl = t/14, r = t - cl*14;
    int c = c0 + cl;
    float w25[25];
    #pragma unroll
    for (int u = 0; u < 25; ++u) w25[u] = dw[c*25 + u];
    float acc[14];
    float b2 = 2.f*db[c];
    #pragma unroll
    for (int j = 0; j < 14; ++j) acc[j] = b2;
    conv5x5_row(&pl[cl*360], r, w25, acc);
    float* dst = XO + ((size_t)b*196 + r*14)*256 + c;
    #pragma unroll
    for (int j = 0; j < 14; ++j) dst[j*256] += acc[j];
  }
}

// ---------- final projection: out = XO @ proj_w^T + proj_b ----------
__global__ __launch_bounds__(256) void k_proj(const float* __restrict__ XO, const float* __restrict__ WT,
    const float* __restrict__ pbias, float* __restrict__ OUT){
  int bb = blockIdx.x / 7, nt = blockIdx.x % 7;
  int n0 = nt*28;
  int c = threadIdx.x;
  const float* xb = XO + ((size_t)bb*196 + n0)*256;
  float acc[28];
  #pragma unroll
  for (int r = 0; r < 28; ++r) acc[r] = 0.f;
  for (int k = 0; k < 256; k += 4){
    float w0 = WT[(k+0)*256 + c];
    float w1 = WT[(k+1)*256 + c];
    float w2 = WT[(k+2)*256 + c];
    float w3 = WT[(k+3)*256 + c];
    #pragma unroll
    for (int r = 0; r < 28; ++r){
      float4 xv = *(const float4*)(xb + r*256 + k);   // uniform address -> scalar/L1 path
      acc[r] = fmaf(xv.x, w0, fmaf(xv.y, w1, fmaf(xv.z, w2, fmaf(xv.w, w3, acc[r]))));
    }
  }
  float bv = pbias[c];
  float* dst = OUT + ((size_t)bb*196 + n0)*256 + c;
  #pragma unroll
  for (int r = 0; r < 28; ++r) dst[r*256] = acc[r] + bv;
}

extern "C" void kernel_launch(void* const* d_in, const int* in_sizes, int n_in,
                              void* d_out, int out_size, void* d_ws, size_t ws_size,
                              hipStream_t stream){
  (void)in_sizes; (void)n_in; (void)out_size; (void)ws_size;
  const float* x       = (const float*)d_in[0];
  const float* lka_w   = (const float*)d_in[3];
  const float* lka_b   = (const float*)d_in[4];
  const float* conv5_w = (const float*)d_in[5];
  const float* conv5_b = (const float*)d_in[6];
  const float* caa1_w  = (const float*)d_in[7];
  const float* caa1_b  = (const float*)d_in[8];
  const float* caa2_w  = (const float*)d_in[9];
  const float* caa2_b  = (const float*)d_in[10];
  const float* cam1_w  = (const float*)d_in[11];
  const float* cam1_b  = (const float*)d_in[12];
  const float* cam2_w  = (const float*)d_in[13];
  const float* cam2_b  = (const float*)d_in[14];
  const float* sa_w    = (const float*)d_in[15];
  const float* sa_b    = (const float*)d_in[16];
  const float* ci1_w   = (const float*)d_in[17];
  const float* ci1_b   = (const float*)d_in[18];
  const float* bn_g    = (const float*)d_in[19];
  const float* bn_b    = (const float*)d_in[20];
  const float* ci2_w   = (const float*)d_in[21];
  const float* ci2_b   = (const float*)d_in[22];
  const float* rpbt    = (const float*)d_in[23];
  const float* an_bias = (const float*)d_in[24];
  const float* na_bias = (const float*)d_in[25];
  const float* ah_bias = (const float*)d_in[26];
  const float* aw_bias = (const float*)d_in[27];
  const float* ha_bias = (const float*)d_in[28];
  const float* wa_bias = (const float*)d_in[29];
  const float* dwc_w   = (const float*)d_in[30];
  const float* dwc_b   = (const float*)d_in[31];
  const float* proj_w  = (const float*)d_in[32];
  const float* proj_b  = (const float*)d_in[33];
  float* out = (float*)d_out;
  float* ws = (float*)d_ws;

  float* Y    = ws + WS_Y;
  float* V5   = ws + WS_V5;
  float* AT   = ws + WS_AT;
  float* ATK  = ws + WS_ATK;
  float* CHG  = ws + WS_CHG;
  float* CMAP = ws + WS_CMAP;
  float* PBT  = ws + WS_PBT;
  float* AB   = ws + WS_AB;
  float* X1S  = ws + WS_X1S;
  float* AGV  = ws + WS_AGV;
  float* XO   = ws + WS_XO;
  float* WT   = ws + WS_WT;
  ushort_t* Wh = (ushort_t*)(ws + WS_CWT);

  k_pbab <<<602, 256, 0, stream>>>(an_bias, ah_bias, aw_bias, na_bias, ha_bias, wa_bias, PBT, AB);
  k_wt   <<<256, 256, 0, stream>>>(proj_w, WT);
  k_cw2  <<<6400, 256, 0, stream>>>(conv5_w, Wh);
  k_lka  <<<1024, 256, 0, stream>>>(x, lka_w, lka_b, Y);
  k_conv5<<<512, 256, 0, stream>>>(Y, Wh, conv5_b, V5);
  k_pool <<<256, 256, 0, stream>>>(Y, AT, ATK);
  k_cbam_a<<<128, 256, 0, stream>>>(V5, caa1_w, caa1_b, caa2_w, caa2_b,
                                    cam1_w, cam1_b, cam2_w, cam2_b, CHG);
  k_cbam_b<<<128, 256, 0, stream>>>(V5, CHG, sa_w, sa_b);
  k_attn3<<<1024, 512, 0, stream>>>(Y, rpbt, X1S);
  k_cinter<<<128, 256, 0, stream>>>(X1S, ci1_w, ci1_b, bn_g, bn_b, ci2_w, ci2_b, CMAP);
  k_agentv<<<1024, 256, 0, stream>>>(Y, V5, AT, ATK, PBT, AGV);
  k_xo1  <<<1024, 256, 0, stream>>>(Y, AT, ATK, AB, AGV, XO);
  k_dwc  <<<1024, 256, 0, stream>>>(Y, CMAP, dwc_w, dwc_b, XO);
  k_proj <<<896, 256, 0, stream>>>(XO, WT, proj_b, out);
}

// Round 8
// 794.858 us; speedup vs baseline: 1.1032x; 1.0113x over previous
//
#include <hip/hip_runtime.h>

// Problem constants
#define NB    128
#define NC    256
#define NPOS  196
#define NHEAD 8
#define NAG   49
#define YSTR  150528      // 768*196 per-batch y floats
#define VOFF  50176       // v_raw offset inside y (256*196)
#define QOFF  100352      // q_raw offset inside y (512*196)
#define SCL   0.17677669529663687f   // 32^-0.5

// Workspace layout (floats). Total = 38,885,440 floats = 155.5 MB.
#define WS_Y    0u
#define WS_V5   19267584u
#define WS_AT   25690112u
#define WS_ATK  27295744u
#define WS_CHG  28901376u
#define WS_CMAP 28934144u
#define WS_PBT  28966912u
#define WS_AB   29043744u
#define WS_X1S  29120576u
#define WS_AGV  29153344u
#define WS_XO   30758976u
#define WS_WT   37181504u
#define WS_CWT  37247040u   // Wh: 1.6M ushort (fp16 conv5 weights, [tap][co][ci])

typedef __attribute__((ext_vector_type(8))) _Float16 half8;
typedef __attribute__((ext_vector_type(8))) short short8;
typedef __attribute__((ext_vector_type(4))) short short4v;
typedef __attribute__((ext_vector_type(4))) float f32x4;
typedef unsigned short ushort_t;
typedef unsigned int uint_t;

__device__ __forceinline__ float sigmoidf_(float x){ return 1.0f/(1.0f+__expf(-x)); }

__device__ __forceinline__ ushort_t f2h(float x){
  _Float16 h = (_Float16)x; return __builtin_bit_cast(ushort_t, h);
}
__device__ __forceinline__ float h2f(ushort_t u){
  return (float)__builtin_bit_cast(_Float16, u);
}

// bilinear upsample 7x7 -> 14x14 sample at (i,j), matching reference grid()
__device__ __forceinline__ float bilin7(const float* __restrict__ src, int i, int j){
  float pi = fmaxf(0.5f*(float)i - 0.25f, 0.f);
  int i0 = (int)pi; if (i0 > 6) i0 = 6;
  int i1 = i0 + 1;  if (i1 > 6) i1 = 6;
  float li = pi - (float)i0;
  float pj = fmaxf(0.5f*(float)j - 0.25f, 0.f);
  int j0 = (int)pj; if (j0 > 6) j0 = 6;
  int j1 = j0 + 1;  if (j1 > 6) j1 = 6;
  float lj = pj - (float)j0;
  float v00 = src[i0*7+j0], v01 = src[i0*7+j1];
  float v10 = src[i1*7+j0], v11 = src[i1*7+j1];
  float t0 = v00*(1.f-lj) + v01*lj;
  float t1 = v10*(1.f-lj) + v11*lj;
  return t0*(1.f-li) + t1*li;
}

// 5x5 conv over a zero-padded [18][20] plane, producing one 14-wide output row r.
__device__ __forceinline__ void conv5x5_row(const float* __restrict__ plane, int r,
                                            const float* __restrict__ w25, float* acc14){
  #pragma unroll
  for (int di = 0; di < 5; ++di){
    const float4* pr = (const float4*)(plane + (r+di)*20);
    float4 p0 = pr[0], p1 = pr[1], p2 = pr[2], p3 = pr[3], p4 = pr[4];
    float row[20] = {p0.x,p0.y,p0.z,p0.w, p1.x,p1.y,p1.z,p1.w, p2.x,p2.y,p2.z,p2.w,
                     p3.x,p3.y,p3.z,p3.w, p4.x,p4.y,p4.z,p4.w};
    #pragma unroll
    for (int dj = 0; dj < 5; ++dj){
      float w = w25[di*5+dj];
      #pragma unroll
      for (int j = 0; j < 14; ++j) acc14[j] = fmaf(row[j+dj], w, acc14[j]);
    }
  }
}

// ---------- prep kernels ----------
// merged pb+ab: blocks [0,301) -> PBT, [301,602) -> AB
__global__ void k_pbab(const float* __restrict__ an, const float* __restrict__ ah,
                       const float* __restrict__ aw, const float* __restrict__ na,
                       const float* __restrict__ ha, const float* __restrict__ wa,
                       float* __restrict__ PBT, float* __restrict__ AB){
  int bid = blockIdx.x;
  int which = (bid >= 301);
  int t = (which ? bid - 301 : bid)*256 + threadIdx.x;
  if (t >= NHEAD*NPOS*NAG) return;
  int a = t % NAG;
  int r = t / NAG;
  int n = r % NPOS;
  int h = r / NPOS;
  int i = n/14, j = n - (n/14)*14;
  if (!which){
    float v = bilin7(an + ((size_t)h*NAG + a)*49, i, j);
    v += ah[((size_t)h*NAG + a)*14 + i] + aw[((size_t)h*NAG + a)*14 + j];
    PBT[t] = v;   // [h][n][a]
  } else {
    float v = bilin7(na + ((size_t)h*NAG + a)*49, i, j);
    v += ha[((size_t)h*14 + i)*NAG + a] + wa[((size_t)h*14 + j)*NAG + a];
    AB[t] = v;    // [h][n][a]
  }
}

// merged weight prep: blocks [0,800) -> conv5 fp16 weights (8 elems/thread),
// blocks [800,1056) -> proj_w transpose.
__global__ void k_wprep(const float* __restrict__ cw, ushort_t* __restrict__ Wh,
                        const float* __restrict__ pw, float* __restrict__ WT){
  int bid = blockIdx.x;
  if (bid < 800){
    int base = (bid*256 + threadIdx.x)*8;       // < 1638400; 8 | 256 so r uniform
    int r   = base >> 8;
    int co  = r & 255;
    int tap = r >> 8;
    int ci0 = base & 255;
    const float* srcb = cw + (size_t)co*6400 + (size_t)ci0*25 + tap;
    short8 o;
    #pragma unroll
    for (int e = 0; e < 8; ++e) o[e] = (short)f2h(srcb[e*25]);
    *(short8*)(Wh + base) = o;                  // Wh[tap][co][ci]
  } else {
    int t = (bid - 800)*256 + threadIdx.x;      // < 65536
    int k = t >> 8, c = t & 255;
    WT[t] = pw[c*256 + k];                      // WT[k][c] = proj_w[c][k]
  }
}

// ---------- lka depthwise-ish conv (groups=256, 3 outputs per input channel) ----------
__global__ __launch_bounds__(256) void k_lka(const float* __restrict__ x, const float* __restrict__ lw,
                                             const float* __restrict__ lb, float* __restrict__ Y){
  int b = blockIdx.x >> 3, gb = blockIdx.x & 7;
  int g0 = gb*32;                               // input channels [g0,g0+32)
  __shared__ __align__(16) float pl[32*360];    // [ch][18*20] padded planes
  int tid = threadIdx.x;
  for (int t = tid; t < 32*360; t += 256) pl[t] = 0.f;
  __syncthreads();
  for (int t = tid; t < 32*196; t += 256){
    int gl = t & 31, s = t >> 5;
    int i = s/14, j = s - i*14;
    pl[gl*360 + (i+2)*20 + j + 2] = x[((size_t)b*196 + s)*256 + g0 + gl];
  }
  __syncthreads();
  for (int t = tid; t < 96*14; t += 256){
    int ocl = t/14, r = t - ocl*14;
    int o  = g0*3 + ocl;          // output channel; uses input channel o/3
    int gl = ocl/3;
    float w25[25];
    #pragma unroll
    for (int u = 0; u < 25; ++u) w25[u] = lw[o*25 + u];
    float acc[14];
    float bv = lb[o];
    #pragma unroll
    for (int j = 0; j < 14; ++j) acc[j] = bv;
    conv5x5_row(&pl[gl*360], r, w25, acc);
    float* dst = Y + ((size_t)b*768 + o)*196 + r*14;
    #pragma unroll
    for (int j = 0; j < 14; ++j) dst[j] = acc[j];
  }
}

// ---------- conv5 via fp16 MFMA implicit GEMM, W double-buffered (round-7 winner) ----------
__global__ __launch_bounds__(256, 2) void k_conv5(const float* __restrict__ Y,
    const ushort_t* __restrict__ Wh, const float* __restrict__ cb, float* __restrict__ V5){
  int b = blockIdx.x >> 2, cog = blockIdx.x & 3;
  int co0 = cog*64;
  __shared__ __align__(16) ushort_t Pt[360*40];       // fp16 A: [pos][4 chunks of 8ci + pad]
  __shared__ __align__(16) ushort_t Wsm[2*5*64*40];   // fp16 B, double-buffered
  float* T = (float*)Wsm;                             // epilogue transpose (buffer 0)
  int tid  = threadIdx.x;
  int lane = tid & 63, wv = tid >> 6;
  int mrow = lane & 15, quad = lane >> 4;

  for (int t = tid; t < 7200; t += 256) ((uint_t*)Pt)[t] = 0;

  int prow[4];
  #pragma unroll
  for (int mt = 0; mt < 4; ++mt){
    int s = wv*64 + mt*16 + mrow;
    int p0 = 0;
    if (s < 196){ int i = s/14, j = s - i*14; p0 = i*20 + j; }
    prow[mt] = p0;
  }

  f32x4 acc[4][4];
  #pragma unroll
  for (int mt = 0; mt < 4; ++mt)
    #pragma unroll
    for (int nt = 0; nt < 4; ++nt) acc[mt][nt] = (f32x4){0.f,0.f,0.f,0.f};

  const float* src = Y + (size_t)b*YSTR + VOFF;   // v_raw [ci][s]
  int wco = tid >> 2, wpart = tid & 3;            // W-staging roles
  const ushort_t* wbase = Wh + ((size_t)(co0 + wco))*256 + wpart*8;  // + tap*65536 + cc*32

  short8 wreg[5];
  #pragma unroll
  for (int tp = 0; tp < 5; ++tp)
    wreg[tp] = *(const short8*)(wbase + (size_t)tp*65536);

  #pragma unroll 1
  for (int cc = 0; cc < 8; ++cc){
    __syncthreads();              // Pt free to overwrite (prev cc compute done)
    for (int t = tid; t < 784; t += 256){
      int pos = t >> 2, ch = t & 3;
      int i = pos/14, j = pos - i*14;
      int p = (i+2)*20 + j + 2;
      const float* s0 = src + (size_t)(cc*32 + ch*8)*196 + pos;
      short8 pk;
      #pragma unroll
      for (int e = 0; e < 4; ++e){
        float v0 = s0[(2*e)*196];
        float v1 = s0[(2*e+1)*196];
        pk[2*e]   = (short)f2h(v0);
        pk[2*e+1] = (short)f2h(v1);
      }
      *(short8*)&Pt[p*40 + ch*8] = pk;
    }
    #pragma unroll 1
    for (int di = 0; di < 5; ++di){
      int u = cc*5 + di;
      ushort_t* wbuf = Wsm + (u & 1)*12800;
      #pragma unroll
      for (int tp = 0; tp < 5; ++tp)
        *(short8*)&wbuf[(tp*64 + wco)*40 + wpart*8] = wreg[tp];
      if (u < 39){
        int di1 = di + 1, cc1 = cc;
        if (di1 == 5){ di1 = 0; ++cc1; }
        #pragma unroll
        for (int tp = 0; tp < 5; ++tp)
          wreg[tp] = *(const short8*)(wbase + (size_t)(di1*5 + tp)*65536 + cc1*32);
      }
      __syncthreads();      // fences A writes (di=0) and this step's W writes
      #pragma unroll
      for (int dj = 0; dj < 5; ++dj){
        half8 a[4], bb[4];
        #pragma unroll
        for (int nt = 0; nt < 4; ++nt){
          int co = nt*16 + mrow;
          bb[nt] = *(const half8*)&wbuf[(dj*64 + co)*40 + quad*8];
        }
        #pragma unroll
        for (int mt = 0; mt < 4; ++mt){
          int p = prow[mt] + di*20 + dj;
          a[mt] = *(const half8*)&Pt[p*40 + quad*8];
        }
        #pragma unroll
        for (int mt = 0; mt < 4; ++mt)
          #pragma unroll
          for (int nt = 0; nt < 4; ++nt)
            acc[mt][nt] = __builtin_amdgcn_mfma_f32_16x16x32_f16(a[mt], bb[nt], acc[mt][nt], 0, 0, 0);
      }
    }
  }

  // epilogue: transpose through LDS (T = Wsm buffer 0), stores into scrambled v5
  #pragma unroll
  for (int hf = 0; hf < 2; ++hf){
    __syncthreads();
    #pragma unroll
    for (int ntl = 0; ntl < 2; ++ntl){
      int nt = hf*2 + ntl;
      int col = ntl*16 + mrow;            // co local within half (0..31)
      #pragma unroll
      for (int mt = 0; mt < 4; ++mt){
        int sbase = wv*64 + mt*16 + quad*4;
        #pragma unroll
        for (int r = 0; r < 4; ++r){
          int s = sbase + r;
          if (s < 196) T[col*200 + s] = acc[mt][nt][r];
        }
      }
    }
    __syncthreads();
    for (int t = tid; t < 6272; t += 256){
      int cl = t / 196;                   // co local 0..31
      int f = (co0 + hf*32)*196 + t;
      float val = T[t + cl*4] + cb[co0 + hf*32 + cl];
      V5[(size_t)b*50176 + (size_t)(f & 255)*196 + (f >> 8)] = val;
    }
  }
}

// ---------- agent token pooling (256 blocks: channel-half x agent-half split) ----------
__global__ __launch_bounds__(256) void k_pool(const float* __restrict__ Y, float* __restrict__ AT, float* __restrict__ ATK){
  int b = blockIdx.x >> 1, half = blockIdx.x & 1;
  int c = (threadIdx.x & 127) + half*128;
  int a0 = (threadIdx.x >> 7) ? 25 : 0;
  int a1 = (threadIdx.x >> 7) ? 49 : 25;
  const float* qp = Y + ((size_t)b*768 + 512 + c)*196;
  const float* kp = Y + ((size_t)b*768 + c)*196;
  for (int a = a0; a < a1; ++a){
    int p1 = a/7, p2 = a - p1*7;
    int s = p1*28 + p2*2;
    float q0 = qp[s], q1 = qp[s+1], q2 = qp[s+14], q3 = qp[s+15];
    AT[((size_t)b*49 + a)*256 + c] = 0.25f*(q0+q1+q2+q3);
    float k0 = kp[s], k1 = kp[s+1], k2 = kp[s+14], k3 = kp[s+15];
    ATK[((size_t)b*49 + a)*256 + c] = fmaxf(fmaxf(k0,k1), fmaxf(k2,k3));
  }
}

// ---------- fused cbam: channel stats (coalesced) + MLPs + spatial mask + gate ----------
// Phase 1 replaces cbam_a's 784B-strided per-thread row stream (16x granule
// waste) with wave-per-channel float4 loads + 64-lane shuffle reduce. Phases
// 2-4 are the round-7 cbam_a tail + cbam_b bodies verbatim (chg kept in LDS,
// no CHG global round-trip). V5 re-reads in phases 3/4 are L2-hot.
__global__ __launch_bounds__(256) void k_cbam(float* __restrict__ V5,
    const float* __restrict__ caa1w, const float* __restrict__ caa1b,
    const float* __restrict__ caa2w, const float* __restrict__ caa2b,
    const float* __restrict__ cam1w, const float* __restrict__ cam1b,
    const float* __restrict__ cam2w, const float* __restrict__ cam2b,
    const float* __restrict__ saw, const float* __restrict__ sab){
  int b = blockIdx.x;
  __shared__ float avg[256], mx[256], t1[16], t2[16], chg[256];
  __shared__ float mp[22*22], xp[22*22];
  __shared__ float mk[196];
  int tid = threadIdx.x, wv = tid >> 6, lane = tid & 63;
  float* v5b = V5 + (size_t)b*50176;

  for (int t = tid; t < 484; t += 256){ mp[t] = 0.f; xp[t] = 0.f; }

  // phase 1: per-channel sum/max, coalesced (lane<49 covers 49*4=196 positions)
  for (int c = wv; c < 256; c += 4){
    float s, m;
    if (lane < 49){
      float4 v = *(const float4*)(v5b + c*196 + lane*4);
      s = v.x + v.y + v.z + v.w;
      m = fmaxf(fmaxf(v.x, v.y), fmaxf(v.z, v.w));
    } else { s = 0.f; m = -1e30f; }
    #pragma unroll
    for (int off = 1; off < 64; off <<= 1){
      s += __shfl_xor(s, off);
      m = fmaxf(m, __shfl_xor(m, off));
    }
    if (lane == 0){ avg[c] = s*(1.0f/196.0f); mx[c] = m; }
  }
  __syncthreads();

  // phase 2: channel MLPs -> chg
  if (tid < 16){
    float a1 = caa1b[tid], a2 = cam1b[tid];
    #pragma unroll 4
    for (int k = 0; k < 256; ++k){
      a1 = fmaf(caa1w[(tid*256 + k)*9 + 4], avg[k], a1);   // 3x3 center tap
      a2 = fmaf(cam1w[tid*256 + k], mx[k], a2);            // 1x1
    }
    t1[tid] = fmaxf(a1, 0.f);
    t2[tid] = fmaxf(a2, 0.f);
  }
  __syncthreads();
  {
    float y1 = caa2b[tid], y2 = cam2b[tid];
    #pragma unroll
    for (int k = 0; k < 16; ++k){
      y1 = fmaf(caa2w[(tid*16 + k)*9 + 4], t1[k], y1);
      y2 = fmaf(cam2w[tid*16 + k], t2[k], y2);
    }
    chg[tid] = sigmoidf_(sigmoidf_(y1) + sigmoidf_(y2));
  }
  __syncthreads();

  // phase 3: spatial mean/max over channels (coalesced per-c rows), 9x9 conv
  if (tid < 196){
    int i = tid/14, j = tid - i*14;
    float s = 0.f, m = -1e30f;
    const float* vb = v5b + tid;
    for (int c = 0; c < 256; ++c){
      float v = chg[c] * vb[c*196];
      s += v; m = fmaxf(m, v);
    }
    mp[(i+4)*22 + j+4] = s*(1.f/256.f);
    xp[(i+4)*22 + j+4] = m;
  }
  __syncthreads();
  if (tid < 196){
    int i = tid/14, j = tid - i*14;
    float acc = sab[0];
    for (int di = 0; di < 9; ++di){
      #pragma unroll
      for (int dj = 0; dj < 9; ++dj){
        acc = fmaf(mp[(i+di)*22 + j+dj], saw[di*9+dj], acc);
        acc = fmaf(xp[(i+di)*22 + j+dj], saw[81 + di*9+dj], acc);
      }
    }
    mk[tid] = sigmoidf_(acc);
  }
  __syncthreads();
  if (tid < 196){
    float m = mk[tid];
    float* vb = v5b + tid;
    for (int c = 0; c < 256; ++c) vb[c*196] = chg[c]*vb[c*196]*m;
  }
}

// ---------- big NxN attention via MFMA, 3-segment version (round-6) ----------
__global__ __launch_bounds__(512, 4) void k_attn3(const float* __restrict__ Y,
    const float* __restrict__ rpbt, float* __restrict__ X1S){
  int b = blockIdx.x >> 3, h = blockIdx.x & 7;
  __shared__ __align__(16) ushort_t Qh[208*32];    // fp16 q*SCL rows, chunk-swizzled
  __shared__ __align__(16) ushort_t Kh[208*32];    // fp16 k rows, chunk-swizzled
  __shared__ __align__(16) ushort_t E[80*208];     // fp16 exp-scores [n-local][j]
  __shared__ float rp[736];
  __shared__ int   rpo[208];
  __shared__ float pl2[80][2];                     // lsum halves per row
  __shared__ float invl[80];
  __shared__ float wj[208];
  __shared__ float wpart[8][208];
  __shared__ float xpart[16][32];
  int tid = threadIdx.x, wv = tid >> 6, lane = tid & 63;
  int mrow = lane & 15, quad = lane >> 4;
  int sw8 = ((quad ^ ((mrow >> 1) & 3)) << 3);     // 64B-row read swizzle
  const float* yb = Y + (size_t)b*YSTR;

  for (int t = tid; t < 736; t += 512) rp[t] = (t < 729) ? rpbt[t*8 + h] : 0.f;
  for (int j = tid; j < 208; j += 512){
    int jc = (j < 196) ? j : 195;
    int rj = jc/14;
    rpo[j] = rj*27 + (jc - rj*14);
    wj[j] = 0.f;
  }
  for (int t = tid; t < 384; t += 512){            // zero rows 196..207 of Qh/Kh
    int arr = t >= 192; int u = t - arr*192;
    ((uint_t*)(arr ? Kh : Qh))[3136 + u] = 0;
  }
  for (int t = tid; t < 3136; t += 512){
    int n = t >> 4, w = t & 15;
    int ws = (((w >> 2) ^ ((n >> 1) & 3)) << 2) | (w & 3);
    const float2 qv = *(const float2*)(yb + QOFF + (size_t)n*256 + h*32 + (w << 1));
    ((uint_t*)Qh)[n*16 + ws] = (uint_t)f2h(qv.x*SCL) | ((uint_t)f2h(qv.y*SCL) << 16);
    const float2 kv = *(const float2*)(yb + (size_t)n*256 + h*32 + (w << 1));
    ((uint_t*)Kh)[n*16 + ws] = (uint_t)f2h(kv.x) | ((uint_t)f2h(kv.y) << 16);
  }
  __syncthreads();

  int mt0 = (wv & 1) ? 7 : 0;
  int mt1 = (wv & 1) ? 13 : 7;

  #pragma unroll 1
  for (int seg = 0; seg < 3; ++seg){
    int base = (seg == 0) ? 0 : (seg == 1) ? 80 : 144;
    int ntl  = (seg == 0) ? 5 : 4;
    int segrows = ntl*16;
    int vrows = 196 - base; if (vrows > segrows) vrows = segrows;

    #pragma unroll 1
    for (int ncl = (wv >> 1); ncl < ntl; ncl += 4){
      int n = base + ncl*16 + mrow;
      half8 bfr = *(const half8*)&Qh[n*32 + sw8];
      int nclamp = (n < 196) ? n : 195;
      int rin = nclamp/14, cin = nclamp - rin*14;
      int bidxn = (rin + 13)*27 + (cin + 13);
      float lsum = 0.f;
      #pragma unroll 1
      for (int mt = mt0; mt < mt1; ++mt){
        half8 afr = *(const half8*)&Kh[(mt*16 + mrow)*32 + sw8];
        f32x4 c = (f32x4){0.f,0.f,0.f,0.f};
        c = __builtin_amdgcn_mfma_f32_16x16x32_f16(afr, bfr, c, 0, 0, 0);
        int j0 = mt*16 + quad*4;
        int4 ro = *(const int4*)&rpo[j0];
        short4v pk;
        #pragma unroll
        for (int r = 0; r < 4; ++r){
          int j = j0 + r;
          int roff = (r == 0) ? ro.x : (r == 1) ? ro.y : (r == 2) ? ro.z : ro.w;
          float e = (j < 196) ? __expf(c[r] + rp[bidxn - roff]) : 0.f;
          lsum += e;
          pk[r] = (short)f2h(e);
        }
        if (n < 196) *(short4v*)&E[(n - base)*208 + j0] = pk;
      }
      lsum += __shfl_xor(lsum, 16);
      lsum += __shfl_xor(lsum, 32);
      if (quad == 0) pl2[n - base][wv & 1] = lsum;
    }
    __syncthreads();
    for (int t = tid; t < vrows; t += 512) invl[t] = 1.f/(pl2[t][0] + pl2[t][1]);
    __syncthreads();

    {
      int j0 = lane*4;
      if (j0 < 208){
        float a0=0.f,a1=0.f,a2=0.f,a3=0.f;
        #pragma unroll 1
        for (int nl = wv; nl < vrows; nl += 8){
          float iv = invl[nl];
          short4v ev = *(const short4v*)&E[nl*208 + j0];
          a0 = fmaf(h2f((ushort_t)ev[0]), iv, a0);
          a1 = fmaf(h2f((ushort_t)ev[1]), iv, a1);
          a2 = fmaf(h2f((ushort_t)ev[2]), iv, a2);
          a3 = fmaf(h2f((ushort_t)ev[3]), iv, a3);
        }
        *(f32x4*)&wpart[wv][j0] = (f32x4){a0,a1,a2,a3};
      }
    }
    __syncthreads();
    for (int j = tid; j < 208; j += 512){
      float s = wj[j];
      #pragma unroll
      for (int g = 0; g < 8; ++g) s += wpart[g][j];
      wj[j] = s;
    }
    __syncthreads();   // wpart/E/pl2/invl free for next segment
  }

  {
    int d = tid & 31, g = tid >> 5;                // 16 groups x 13 j's
    float s = 0.f;
    #pragma unroll 1
    for (int u = 0; u < 13; ++u){
      int j = g*13 + u;
      s = fmaf(wj[j], yb[VOFF + (size_t)j*256 + h*32 + d], s);
    }
    xpart[g][d] = s;
  }
  __syncthreads();
  if (tid < 32){
    float s = 0.f;
    #pragma unroll
    for (int g2 = 0; g2 < 16; ++g2) s += xpart[g2][tid];
    X1S[(size_t)b*256 + h*32 + tid] = s*(1.f/196.f);
  }
}

// ---------- chan_inter on x1 mean -> sigmoid gate CMAP ----------
__global__ __launch_bounds__(256) void k_cinter(const float* __restrict__ X1S,
    const float* __restrict__ ci1w, const float* __restrict__ ci1b,
    const float* __restrict__ bng, const float* __restrict__ bnb,
    const float* __restrict__ ci2w, const float* __restrict__ ci2b, float* __restrict__ CMAP){
  int b = blockIdx.x, c = threadIdx.x;
  __shared__ float p[256], tt[16];
  p[c] = X1S[b*256 + c];
  __syncthreads();
  if (c < 16){
    float a = ci1b[c];
    #pragma unroll 4
    for (int k = 0; k < 256; ++k) a = fmaf(ci1w[(c*256+k)*25 + 12], p[k], a);  // 5x5 center
    const float invs = 0.9999950000375f;   // 1/sqrt(1+1e-5)
    tt[c] = fmaxf(fmaf(bng[c]*invs, a, bnb[c]), 0.f);
  }
  __syncthreads();
  float a = ci2b[c];
  #pragma unroll
  for (int k = 0; k < 16; ++k) a = fmaf(ci2w[(c*16+k)*25 + 12], tt[k], a);
  CMAP[b*256 + c] = sigmoidf_(a);
}

// ---------- agent_v via fp16 MFMA ----------
// Kh/Ah rows are 64B (even stride): reads use a bijective chunk swizzle
// chunk ^= (row>>1)&3 (write side mirrors it). Pass-1 V staging now loads
// float2 along d (fully coalesced; was a 1KB-strided scalar gather) and
// writes two b16 LDS elements transposed -- same elements, same values.
__global__ __launch_bounds__(256) void k_agentv(const float* __restrict__ Y, const float* __restrict__ V5,
    const float* __restrict__ AT, const float* __restrict__ ATK,
    const float* __restrict__ PBT, float* __restrict__ AGV){
  int b = blockIdx.x >> 3, h = blockIdx.x & 7;
  __shared__ __align__(16) ushort_t ST[64*232];   // exp-scores, [a][n pad 232]
  __shared__ __align__(16) ushort_t R[8704];      // staging region (17408 B)
  __shared__ float psum[4*64];
  __shared__ float inv0s[64], inv1s[64];
  int tid = threadIdx.x, wv = tid >> 6, lane = tid & 63;
  int mrow = lane & 15, quad = lane >> 4;
  int sw8 = ((quad ^ ((mrow >> 1) & 3)) << 3);    // read-side chunk swizzle (rows = 16*t + mrow)
  const float* yb = Y + (size_t)b*YSTR;
  ushort_t* Kh = R;            // [208][32] fp16 rows (K or Q), chunk-swizzled
  ushort_t* Ah = R + 6656;     // [64][32] fp16 rows (AT or ATK), chunk-swizzled
  ushort_t* Vt = R;            // [32][232] fp16 rows (V1 or V)
  f32x4 out0[2], out1[2];

  // ---- one-time zero fills: ST cols 208..223 (cols 224-231 never read) ----
  for (int t = tid; t < 512; t += 256){      // 64 rows x 16 cols /2 per uint
    int a = t >> 3, c2 = 208 + ((t & 7) << 1);
    *(uint_t*)&ST[a*232 + c2] = 0;
  }

  #pragma unroll 1
  for (int pass = 0; pass < 2; ++pass){
    // ---- stage rows (K|Q into Kh; AT|ATK into Ah), zero pads ----
    for (int t = tid; t < 192; t += 256) ((uint_t*)Kh)[3136 + t] = 0;   // rows 196-207
    for (int t = tid; t < 240; t += 256) ((uint_t*)Ah)[784 + t] = 0;    // rows 49-63
    {
      const float* rsrc = yb + (pass ? QOFF : 0) + h*32;
      for (int t = tid; t < 3136; t += 256){
        int n = t >> 4, w = t & 15;
        const float2 v = *(const float2*)(rsrc + (size_t)n*256 + (w << 1));
        int ws = (((w >> 2) ^ ((n >> 1) & 3)) << 2) | (w & 3);
        ((uint_t*)Kh)[n*16 + ws] = (uint_t)f2h(v.x) | ((uint_t)f2h(v.y) << 16);
      }
      const float* asrc = (pass ? ATK : AT) + (size_t)b*49*256 + h*32;
      for (int t = tid; t < 784; t += 256){
        int a = t >> 4, w = t & 15;
        const float2 v = *(const float2*)(asrc + (size_t)a*256 + (w << 1));
        int ws = (((w >> 2) ^ ((a >> 1) & 3)) << 2) | (w & 3);
        ((uint_t*)Ah)[a*16 + ws] = (uint_t)f2h(v.x) | ((uint_t)f2h(v.y) << 16);
      }
    }
    __syncthreads();
    // ---- logits: ntile = wv; 13 mtiles; exp(+pb) -> ST[a][n] ----
    {
      float lscl = pass ? 0.03125f : SCL;
      int ag = wv*16 + mrow;                 // agent (C col)
      half8 bfr = *(const half8*)&Ah[ag*32 + sw8];
      #pragma unroll 1
      for (int mt = 0; mt < 13; ++mt){
        half8 afr = *(const half8*)&Kh[(mt*16 + mrow)*32 + sw8];
        f32x4 c = (f32x4){0.f,0.f,0.f,0.f};
        c = __builtin_amdgcn_mfma_f32_16x16x32_f16(afr, bfr, c, 0, 0, 0);
        int n0 = mt*16 + quad*4;
        short4v pk;
        #pragma unroll
        for (int r = 0; r < 4; ++r){
          int n = n0 + r;
          float pb = PBT[((size_t)h*196 + n)*49 + ag];
          float e = (n < 196) ? __expf(fmaf(c[r], lscl, pb)) : 0.f;
          pk[r] = (short)f2h(e);
        }
        *(short4v*)&ST[ag*232 + n0] = pk;
      }
    }
    __syncthreads();
    // ---- denominators + stage V ----
    {
      int a = tid >> 2, q = tid & 3;
      float s = 0.f;
      #pragma unroll
      for (int u = 0; u < 7; ++u){
        short8 v8 = *(const short8*)&ST[a*232 + q*56 + u*8];
        #pragma unroll
        for (int e = 0; e < 8; ++e) s += h2f((ushort_t)v8[e]);
      }
      psum[q*64 + a] = s;
    }
    if (pass == 0){
      const float* vsrc = V5 + (size_t)b*50176 + h*32*196;   // [d][196]
      for (int t = tid; t < 3136; t += 256){
        int d = t / 98, np = t - (t/98)*98;
        const float2 v = *(const float2*)(vsrc + (size_t)d*196 + 2*np);
        *(uint_t*)&Vt[d*232 + 2*np] = (uint_t)f2h(v.x) | ((uint_t)f2h(v.y) << 16);
      }
    } else {
      const float* vsrc = yb + VOFF + h*32;                  // [n][256] flat view
      for (int t = tid; t < 3136; t += 256){
        int np = t >> 4, dp = t & 15;
        const float2 v = *(const float2*)(vsrc + (size_t)np*256 + (dp << 1));
        Vt[(2*dp)*232 + np]     = f2h(v.x);
        Vt[(2*dp + 1)*232 + np] = f2h(v.y);
      }
    }
    for (int t = tid; t < 448; t += 256){    // zero V cols 196..223
      int d = t / 14, c2 = 196 + 2*(t - (t/14)*14);
      *(uint_t*)&Vt[d*232 + c2] = 0;
    }
    __syncthreads();
    // ---- PV: mtile = wv (a rows); ntile 0..1 (d cols); 7 k-steps ----
    {
      f32x4* outp = pass ? out1 : out0;
      #pragma unroll
      for (int nt = 0; nt < 2; ++nt){
        f32x4 c = (f32x4){0.f,0.f,0.f,0.f};
        #pragma unroll
        for (int ks = 0; ks < 7; ++ks){
          half8 afr = *(const half8*)&ST[(wv*16 + mrow)*232 + ks*32 + quad*8];
          half8 bfr = *(const half8*)&Vt[(nt*16 + mrow)*232 + ks*32 + quad*8];
          c = __builtin_amdgcn_mfma_f32_16x16x32_f16(afr, bfr, c, 0, 0, 0);
        }
        outp[nt] = c;
      }
      if (tid < 64){
        float s = psum[tid] + psum[64+tid] + psum[128+tid] + psum[192+tid];
        float* invp = pass ? inv1s : inv0s;
        invp[tid] = 1.f / s;
      }
    }
    __syncthreads();   // ST/Vt free for next pass; inv visible
  }
  // ---- epilogue: combine + scatter ----
  #pragma unroll
  for (int nt = 0; nt < 2; ++nt){
    int d = nt*16 + mrow;
    #pragma unroll
    for (int r = 0; r < 4; ++r){
      int a = wv*16 + quad*4 + r;
      if (a < 49)
        AGV[(((size_t)(b*8 + h)*49) + a)*32 + d] = out0[nt][r]*inv0s[a] + out1[nt][r]*inv1s[a];
    }
  }
}

// ---------- xo1 via fp16 MFMA ----------
__global__ __launch_bounds__(256) void k_xo1(const float* __restrict__ Y,
    const float* __restrict__ AT, const float* __restrict__ ATK,
    const float* __restrict__ AB, const float* __restrict__ AGV, float* __restrict__ XO){
  int b = blockIdx.x >> 3, h = blockIdx.x & 7;
  __shared__ __align__(16) ushort_t ST[208*72];   // exp-scores [n][a pad 72]
  __shared__ __align__(16) ushort_t Kh[208*32];   // Q or K rows fp16, chunk-swizzled
  __shared__ __align__(16) ushort_t Ah[64*32];    // AT or ATK rows fp16, chunk-swizzled
  __shared__ __align__(16) ushort_t AGVt[32*64];  // AGV^T [d][a], chunk-swizzled
  __shared__ float invs[208];
  int tid = threadIdx.x, wv = tid >> 6, lane = tid & 63;
  int mrow = lane & 15, quad = lane >> 4;
  int sw8 = ((quad ^ ((mrow >> 1) & 3)) << 3);    // 64B-row read swizzle
  const float* yb = Y + (size_t)b*YSTR;
  f32x4 acc[4][2];
  #pragma unroll
  for (int i = 0; i < 4; ++i){
    acc[i][0] = (f32x4){0.f,0.f,0.f,0.f};
    acc[i][1] = (f32x4){0.f,0.f,0.f,0.f};
  }

  for (int t = tid; t < 1664; t += 256){
    int rw = t >> 3, c2 = 48 + ((t & 7) << 1);
    *(uint_t*)&ST[rw*72 + c2] = 0;
  }
  {
    const float* agvb = AGV + (size_t)(b*8 + h)*49*32;
    for (int t = tid; t < 2048; t += 256){
      int d = t >> 6, a = t & 63;
      int as = ((((a >> 3) ^ (d & 7)) & 7) << 3) | (a & 7);
      AGVt[d*64 + as] = (a < 49) ? f2h(agvb[a*32 + d]) : (ushort_t)0;
    }
  }

  #pragma unroll 1
  for (int pass = 0; pass < 2; ++pass){
    {
      const float* rsrc = yb + (pass ? 0 : QOFF) + h*32;
      for (int t = tid; t < 3136; t += 256){
        int n = t >> 4, w = t & 15;
        const float2 v = *(const float2*)(rsrc + (size_t)n*256 + (w << 1));
        int ws = (((w >> 2) ^ ((n >> 1) & 3)) << 2) | (w & 3);
        ((uint_t*)Kh)[n*16 + ws] = (uint_t)f2h(v.x) | ((uint_t)f2h(v.y) << 16);
      }
      const float* asrc = (pass ? ATK : AT) + (size_t)b*49*256 + h*32;
      for (int t = tid; t < 784; t += 256){
        int a = t >> 4, w = t & 15;
        const float2 v = *(const float2*)(asrc + (size_t)a*256 + (w << 1));
        int ws = (((w >> 2) ^ ((a >> 1) & 3)) << 2) | (w & 3);
        ((uint_t*)Ah)[a*16 + ws] = (uint_t)f2h(v.x) | ((uint_t)f2h(v.y) << 16);
      }
    }
    __syncthreads();
    {
      float lscl = pass ? SCL : 0.03125f;
      int ag = wv*16 + mrow;
      half8 bfr = *(const half8*)&Ah[ag*32 + sw8];
      #pragma unroll 1
      for (int mt = 0; mt < 13; ++mt){
        half8 afr = *(const half8*)&Kh[(mt*16 + mrow)*32 + sw8];
        f32x4 c = (f32x4){0.f,0.f,0.f,0.f};
        c = __builtin_amdgcn_mfma_f32_16x16x32_f16(afr, bfr, c, 0, 0, 0);
        #pragma unroll
        for (int r = 0; r < 4; ++r){
          int n = mt*16 + quad*4 + r;
          if (n < 196 && ag < 49){
            float e = __expf(fmaf(c[r], lscl, AB[((size_t)h*196 + n)*49 + ag]));
            ST[n*72 + ag] = f2h(e);
          }
        }
      }
    }
    __syncthreads();
    if (tid < 196){
      float s = 0.f;
      #pragma unroll
      for (int u = 0; u < 7; ++u){
        short8 v8 = *(const short8*)&ST[tid*72 + u*8];
        #pragma unroll
        for (int e = 0; e < 8; ++e) s += h2f((ushort_t)v8[e]);
      }
      invs[tid] = 1.f / s;
    }
    __syncthreads();
    {
      int i = 0;
      #pragma unroll 1
      for (int mt = wv; mt < 13; mt += 4, ++i){
        #pragma unroll
        for (int nt = 0; nt < 2; ++nt){
          f32x4 c = (f32x4){0.f,0.f,0.f,0.f};
          #pragma unroll
          for (int ks = 0; ks < 2; ++ks){
            half8 afr = *(const half8*)&ST[(mt*16 + mrow)*72 + ks*32 + quad*8];
            half8 bfr = *(const half8*)&AGVt[(nt*16 + mrow)*64 + ((((ks*4 + quad) ^ (mrow & 7)) & 7) << 3)];
            c = __builtin_amdgcn_mfma_f32_16x16x32_f16(afr, bfr, c, 0, 0, 0);
          }
          #pragma unroll
          for (int r = 0; r < 4; ++r){
            int n = mt*16 + quad*4 + r;
            if (n < 196) acc[i][nt][r] = fmaf(c[r], invs[n], acc[i][nt][r]);
          }
        }
      }
    }
    __syncthreads();
  }
  {
    int i = 0;
    #pragma unroll 1
    for (int mt = wv; mt < 13; mt += 4, ++i){
      #pragma unroll
      for (int nt = 0; nt < 2; ++nt){
        #pragma unroll
        for (int r = 0; r < 4; ++r){
          int n = mt*16 + quad*4 + r;
          if (n < 196)
            XO[((size_t)b*196 + n)*256 + h*32 + nt*16 + mrow] = acc[i][nt][r];
        }
      }
    }
  }
}

// ---------- fused depthwise conv: dwc(conv_x2 + qc), bias 2*dwc_b, accumulated into XO ----------
__global__ __launch_bounds__(256) void k_dwc(const float* __restrict__ Y, const float* __restrict__ CMAP,
    const float* __restrict__ dw, const float* __restrict__ db, float* __restrict__ XO){
  int b = blockIdx.x >> 3, cg = blockIdx.x & 7;
  int c0 = cg*32;
  __shared__ __align__(16) float pl[32*360];
  int tid = threadIdx.x;
  for (int t = tid; t < 32*360; t += 256) pl[t] = 0.f;
  __syncthreads();
  const float* yq = Y + (size_t)b*YSTR + QOFF;
  for (int t = tid; t < 32*196; t += 256){
    int cl = t & 31, s = t >> 5;
    int c = c0 + cl;
    int G = s*256 + c;                 // head-major flat index for conv_x2's scramble
    int hh = G / 6272;
    int rem = G - hh*6272;
    int n = rem >> 5, d = rem & 31;
    float cx2 = CMAP[b*256 + c] * yq[n*256 + hh*32 + d];   // sigmoid(cmap)*qs
    float qc  = yq[G];                                     // qc collapses to identity gather
    float v = SCL*(cx2 + qc);
    int i = s/14, j = s - i*14;
    pl[cl*360 + (i+2)*20 + j + 2] = v;
  }
  __syncthreads();
  for (int t = tid; t < 32*14; t += 256){
    int cl = t/14, r = t - cl*14;
    int c = c0 + cl;
    float w25[25];
    #pragma unroll
    for (int u = 0; u < 25; ++u) w25[u] = dw[c*25 + u];
    float acc[14];
    float b2 = 2.f*db[c];
    #pragma unroll
    for (int j = 0; j < 14; ++j) acc[j] = b2;
    conv5x5_row(&pl[cl*360], r, w25, acc);
    float* dst = XO + ((size_t)b*196 + r*14)*256 + c;
    #pragma unroll
    for (int j = 0; j < 14; ++j) dst[j*256] += acc[j];
  }
}

// ---------- final projection: out = XO @ proj_w^T + proj_b ----------
__global__ __launch_bounds__(256) void k_proj(const float* __restrict__ XO, const float* __restrict__ WT,
    const float* __restrict__ pbias, float* __restrict__ OUT){
  int bb = blockIdx.x / 7, nt = blockIdx.x % 7;
  int n0 = nt*28;
  int c = threadIdx.x;
  const float* xb = XO + ((size_t)bb*196 + n0)*256;
  float acc[28];
  #pragma unroll
  for (int r = 0; r < 28; ++r) acc[r] = 0.f;
  for (int k = 0; k < 256; k += 4){
    float w0 = WT[(k+0)*256 + c];
    float w1 = WT[(k+1)*256 + c];
    float w2 = WT[(k+2)*256 + c];
    float w3 = WT[(k+3)*256 + c];
    #pragma unroll
    for (int r = 0; r < 28; ++r){
      float4 xv = *(const float4*)(xb + r*256 + k);   // uniform address -> scalar/L1 path
      acc[r] = fmaf(xv.x, w0, fmaf(xv.y, w1, fmaf(xv.z, w2, fmaf(xv.w, w3, acc[r]))));
    }
  }
  float bv = pbias[c];
  float* dst = OUT + ((size_t)bb*196 + n0)*256 + c;
  #pragma unroll
  for (int r = 0; r < 28; ++r) dst[r*256] = acc[r] + bv;
}

extern "C" void kernel_launch(void* const* d_in, const int* in_sizes, int n_in,
                              void* d_out, int out_size, void* d_ws, size_t ws_size,
                              hipStream_t stream){
  (void)in_sizes; (void)n_in; (void)out_size; (void)ws_size;
  const float* x       = (const float*)d_in[0];
  const float* lka_w   = (const float*)d_in[3];
  const float* lka_b   = (const float*)d_in[4];
  const float* conv5_w = (const float*)d_in[5];
  const float* conv5_b = (const float*)d_in[6];
  const float* caa1_w  = (const float*)d_in[7];
  const float* caa1_b  = (const float*)d_in[8];
  const float* caa2_w  = (const float*)d_in[9];
  const float* caa2_b  = (const float*)d_in[10];
  const float* cam1_w  = (const float*)d_in[11];
  const float* cam1_b  = (const float*)d_in[12];
  const float* cam2_w  = (const float*)d_in[13];
  const float* cam2_b  = (const float*)d_in[14];
  const float* sa_w    = (const float*)d_in[15];
  const float* sa_b    = (const float*)d_in[16];
  const float* ci1_w   = (const float*)d_in[17];
  const float* ci1_b   = (const float*)d_in[18];
  const float* bn_g    = (const float*)d_in[19];
  const float* bn_b    = (const float*)d_in[20];
  const float* ci2_w   = (const float*)d_in[21];
  const float* ci2_b   = (const float*)d_in[22];
  const float* rpbt    = (const float*)d_in[23];
  const float* an_bias = (const float*)d_in[24];
  const float* na_bias = (const float*)d_in[25];
  const float* ah_bias = (const float*)d_in[26];
  const float* aw_bias = (const float*)d_in[27];
  const float* ha_bias = (const float*)d_in[28];
  const float* wa_bias = (const float*)d_in[29];
  const float* dwc_w   = (const float*)d_in[30];
  const float* dwc_b   = (const float*)d_in[31];
  const float* proj_w  = (const float*)d_in[32];
  const float* proj_b  = (const float*)d_in[33];
  float* out = (float*)d_out;
  float* ws = (float*)d_ws;

  float* Y    = ws + WS_Y;
  float* V5   = ws + WS_V5;
  float* AT   = ws + WS_AT;
  float* ATK  = ws + WS_ATK;
  float* CMAP = ws + WS_CMAP;
  float* PBT  = ws + WS_PBT;
  float* AB   = ws + WS_AB;
  float* X1S  = ws + WS_X1S;
  float* AGV  = ws + WS_AGV;
  float* XO   = ws + WS_XO;
  float* WT   = ws + WS_WT;
  ushort_t* Wh = (ushort_t*)(ws + WS_CWT);

  k_pbab <<<602, 256, 0, stream>>>(an_bias, ah_bias, aw_bias, na_bias, ha_bias, wa_bias, PBT, AB);
  k_wprep<<<1056, 256, 0, stream>>>(conv5_w, Wh, proj_w, WT);
  k_lka  <<<1024, 256, 0, stream>>>(x, lka_w, lka_b, Y);
  k_conv5<<<512, 256, 0, stream>>>(Y, Wh, conv5_b, V5);
  k_pool <<<256, 256, 0, stream>>>(Y, AT, ATK);
  k_cbam <<<128, 256, 0, stream>>>(V5, caa1_w, caa1_b, caa2_w, caa2_b,
                                   cam1_w, cam1_b, cam2_w, cam2_b, sa_w, sa_b);
  k_attn3<<<1024, 512, 0, stream>>>(Y, rpbt, X1S);
  k_cinter<<<128, 256, 0, stream>>>(X1S, ci1_w, ci1_b, bn_g, bn_b, ci2_w, ci2_b, CMAP);
  k_agentv<<<1024, 256, 0, stream>>>(Y, V5, AT, ATK, PBT, AGV);
  k_xo1  <<<1024, 256, 0, stream>>>(Y, AT, ATK, AB, AGV, XO);
  k_dwc  <<<1024, 256, 0, stream>>>(Y, CMAP, dwc_w, dwc_b, XO);
  k_proj <<<896, 256, 0, stream>>>(XO, WT, proj_b, out);
}

// Round 9
// 733.844 us; speedup vs baseline: 1.1949x; 1.0831x over previous
//
#include <hip/hip_runtime.h>

// Problem constants
#define NB    128
#define NC    256
#define NPOS  196
#define NHEAD 8
#define NAG   49
#define YSTR  150528      // 768*196 per-batch y floats
#define VOFF  50176       // v_raw offset inside y (256*196)
#define QOFF  100352      // q_raw offset inside y (512*196)
#define SCL   0.17677669529663687f   // 32^-0.5

// Workspace layout (floats). Total = 38,885,440 floats = 155.5 MB.
#define WS_Y    0u
#define WS_V5   19267584u
#define WS_AT   25690112u
#define WS_ATK  27295744u
#define WS_CHG  28901376u   // avg -> overwritten in-place by chg (per-b partition)
#define WS_CMAP 28934144u
#define WS_PBT  28966912u
#define WS_AB   29043744u
#define WS_X1S  29120576u
#define WS_AGV  29153344u
#define WS_XO   30758976u
#define WS_WT   37181504u
#define WS_CWT  37247040u   // Wh: 1.6M ushort (fp16 conv5 weights, [tap][co][ci]) -> ends 38066240
#define WS_MX   38066240u   // [128][256] channel max (spare tail)
#define WS_MK   38099008u   // [128][196] spatial mask (spare tail; ends 38124096 < total)

typedef __attribute__((ext_vector_type(8))) _Float16 half8;
typedef __attribute__((ext_vector_type(8))) short short8;
typedef __attribute__((ext_vector_type(4))) short short4v;
typedef __attribute__((ext_vector_type(4))) float f32x4;
typedef unsigned short ushort_t;
typedef unsigned int uint_t;

__device__ __forceinline__ float sigmoidf_(float x){ return 1.0f/(1.0f+__expf(-x)); }

__device__ __forceinline__ ushort_t f2h(float x){
  _Float16 h = (_Float16)x; return __builtin_bit_cast(ushort_t, h);
}
__device__ __forceinline__ float h2f(ushort_t u){
  return (float)__builtin_bit_cast(_Float16, u);
}

// bilinear upsample 7x7 -> 14x14 sample at (i,j), matching reference grid()
__device__ __forceinline__ float bilin7(const float* __restrict__ src, int i, int j){
  float pi = fmaxf(0.5f*(float)i - 0.25f, 0.f);
  int i0 = (int)pi; if (i0 > 6) i0 = 6;
  int i1 = i0 + 1;  if (i1 > 6) i1 = 6;
  float li = pi - (float)i0;
  float pj = fmaxf(0.5f*(float)j - 0.25f, 0.f);
  int j0 = (int)pj; if (j0 > 6) j0 = 6;
  int j1 = j0 + 1;  if (j1 > 6) j1 = 6;
  float lj = pj - (float)j0;
  float v00 = src[i0*7+j0], v01 = src[i0*7+j1];
  float v10 = src[i1*7+j0], v11 = src[i1*7+j1];
  float t0 = v00*(1.f-lj) + v01*lj;
  float t1 = v10*(1.f-lj) + v11*lj;
  return t0*(1.f-li) + t1*li;
}

// 5x5 conv over a zero-padded [18][20] plane, producing one 14-wide output row r.
__device__ __forceinline__ void conv5x5_row(const float* __restrict__ plane, int r,
                                            const float* __restrict__ w25, float* acc14){
  #pragma unroll
  for (int di = 0; di < 5; ++di){
    const float4* pr = (const float4*)(plane + (r+di)*20);
    float4 p0 = pr[0], p1 = pr[1], p2 = pr[2], p3 = pr[3], p4 = pr[4];
    float row[20] = {p0.x,p0.y,p0.z,p0.w, p1.x,p1.y,p1.z,p1.w, p2.x,p2.y,p2.z,p2.w,
                     p3.x,p3.y,p3.z,p3.w, p4.x,p4.y,p4.z,p4.w};
    #pragma unroll
    for (int dj = 0; dj < 5; ++dj){
      float w = w25[di*5+dj];
      #pragma unroll
      for (int j = 0; j < 14; ++j) acc14[j] = fmaf(row[j+dj], w, acc14[j]);
    }
  }
}

// ---------- prep kernels ----------
// merged pb+ab: blocks [0,301) -> PBT, [301,602) -> AB
__global__ void k_pbab(const float* __restrict__ an, const float* __restrict__ ah,
                       const float* __restrict__ aw, const float* __restrict__ na,
                       const float* __restrict__ ha, const float* __restrict__ wa,
                       float* __restrict__ PBT, float* __restrict__ AB){
  int bid = blockIdx.x;
  int which = (bid >= 301);
  int t = (which ? bid - 301 : bid)*256 + threadIdx.x;
  if (t >= NHEAD*NPOS*NAG) return;
  int a = t % NAG;
  int r = t / NAG;
  int n = r % NPOS;
  int h = r / NPOS;
  int i = n/14, j = n - (n/14)*14;
  if (!which){
    float v = bilin7(an + ((size_t)h*NAG + a)*49, i, j);
    v += ah[((size_t)h*NAG + a)*14 + i] + aw[((size_t)h*NAG + a)*14 + j];
    PBT[t] = v;   // [h][n][a]
  } else {
    float v = bilin7(na + ((size_t)h*NAG + a)*49, i, j);
    v += ha[((size_t)h*14 + i)*NAG + a] + wa[((size_t)h*14 + j)*NAG + a];
    AB[t] = v;    // [h][n][a]
  }
}

// merged weight prep: blocks [0,800) -> conv5 fp16 weights (8 elems/thread),
// blocks [800,1056) -> proj_w transpose.
__global__ void k_wprep(const float* __restrict__ cw, ushort_t* __restrict__ Wh,
                        const float* __restrict__ pw, float* __restrict__ WT){
  int bid = blockIdx.x;
  if (bid < 800){
    int base = (bid*256 + threadIdx.x)*8;       // < 1638400; 8 | 256 so r uniform
    int r   = base >> 8;
    int co  = r & 255;
    int tap = r >> 8;
    int ci0 = base & 255;
    const float* srcb = cw + (size_t)co*6400 + (size_t)ci0*25 + tap;
    short8 o;
    #pragma unroll
    for (int e = 0; e < 8; ++e) o[e] = (short)f2h(srcb[e*25]);
    *(short8*)(Wh + base) = o;                  // Wh[tap][co][ci]
  } else {
    int t = (bid - 800)*256 + threadIdx.x;      // < 65536
    int k = t >> 8, c = t & 255;
    WT[t] = pw[c*256 + k];                      // WT[k][c] = proj_w[c][k]
  }
}

// ---------- lka depthwise-ish conv (groups=256, 3 outputs per input channel) ----------
__global__ __launch_bounds__(256) void k_lka(const float* __restrict__ x, const float* __restrict__ lw,
                                             const float* __restrict__ lb, float* __restrict__ Y){
  int b = blockIdx.x >> 3, gb = blockIdx.x & 7;
  int g0 = gb*32;                               // input channels [g0,g0+32)
  __shared__ __align__(16) float pl[32*360];    // [ch][18*20] padded planes
  int tid = threadIdx.x;
  for (int t = tid; t < 32*360; t += 256) pl[t] = 0.f;
  __syncthreads();
  for (int t = tid; t < 32*196; t += 256){
    int gl = t & 31, s = t >> 5;
    int i = s/14, j = s - i*14;
    pl[gl*360 + (i+2)*20 + j + 2] = x[((size_t)b*196 + s)*256 + g0 + gl];
  }
  __syncthreads();
  for (int t = tid; t < 96*14; t += 256){
    int ocl = t/14, r = t - ocl*14;
    int o  = g0*3 + ocl;          // output channel; uses input channel o/3
    int gl = ocl/3;
    float w25[25];
    #pragma unroll
    for (int u = 0; u < 25; ++u) w25[u] = lw[o*25 + u];
    float acc[14];
    float bv = lb[o];
    #pragma unroll
    for (int j = 0; j < 14; ++j) acc[j] = bv;
    conv5x5_row(&pl[gl*360], r, w25, acc);
    float* dst = Y + ((size_t)b*768 + o)*196 + r*14;
    #pragma unroll
    for (int j = 0; j < 14; ++j) dst[j] = acc[j];
  }
}

// ---------- conv5 via fp16 MFMA implicit GEMM, W double-buffered (round-7 winner) ----------
__global__ __launch_bounds__(256, 2) void k_conv5(const float* __restrict__ Y,
    const ushort_t* __restrict__ Wh, const float* __restrict__ cb, float* __restrict__ V5){
  int b = blockIdx.x >> 2, cog = blockIdx.x & 3;
  int co0 = cog*64;
  __shared__ __align__(16) ushort_t Pt[360*40];       // fp16 A: [pos][4 chunks of 8ci + pad]
  __shared__ __align__(16) ushort_t Wsm[2*5*64*40];   // fp16 B, double-buffered
  float* T = (float*)Wsm;                             // epilogue transpose (buffer 0)
  int tid  = threadIdx.x;
  int lane = tid & 63, wv = tid >> 6;
  int mrow = lane & 15, quad = lane >> 4;

  for (int t = tid; t < 7200; t += 256) ((uint_t*)Pt)[t] = 0;

  int prow[4];
  #pragma unroll
  for (int mt = 0; mt < 4; ++mt){
    int s = wv*64 + mt*16 + mrow;
    int p0 = 0;
    if (s < 196){ int i = s/14, j = s - i*14; p0 = i*20 + j; }
    prow[mt] = p0;
  }

  f32x4 acc[4][4];
  #pragma unroll
  for (int mt = 0; mt < 4; ++mt)
    #pragma unroll
    for (int nt = 0; nt < 4; ++nt) acc[mt][nt] = (f32x4){0.f,0.f,0.f,0.f};

  const float* src = Y + (size_t)b*YSTR + VOFF;   // v_raw [ci][s]
  int wco = tid >> 2, wpart = tid & 3;            // W-staging roles
  const ushort_t* wbase = Wh + ((size_t)(co0 + wco))*256 + wpart*8;  // + tap*65536 + cc*32

  short8 wreg[5];
  #pragma unroll
  for (int tp = 0; tp < 5; ++tp)
    wreg[tp] = *(const short8*)(wbase + (size_t)tp*65536);

  #pragma unroll 1
  for (int cc = 0; cc < 8; ++cc){
    __syncthreads();              // Pt free to overwrite (prev cc compute done)
    for (int t = tid; t < 784; t += 256){
      int pos = t >> 2, ch = t & 3;
      int i = pos/14, j = pos - i*14;
      int p = (i+2)*20 + j + 2;
      const float* s0 = src + (size_t)(cc*32 + ch*8)*196 + pos;
      short8 pk;
      #pragma unroll
      for (int e = 0; e < 4; ++e){
        float v0 = s0[(2*e)*196];
        float v1 = s0[(2*e+1)*196];
        pk[2*e]   = (short)f2h(v0);
        pk[2*e+1] = (short)f2h(v1);
      }
      *(short8*)&Pt[p*40 + ch*8] = pk;
    }
    #pragma unroll 1
    for (int di = 0; di < 5; ++di){
      int u = cc*5 + di;
      ushort_t* wbuf = Wsm + (u & 1)*12800;
      #pragma unroll
      for (int tp = 0; tp < 5; ++tp)
        *(short8*)&wbuf[(tp*64 + wco)*40 + wpart*8] = wreg[tp];
      if (u < 39){
        int di1 = di + 1, cc1 = cc;
        if (di1 == 5){ di1 = 0; ++cc1; }
        #pragma unroll
        for (int tp = 0; tp < 5; ++tp)
          wreg[tp] = *(const short8*)(wbase + (size_t)(di1*5 + tp)*65536 + cc1*32);
      }
      __syncthreads();      // fences A writes (di=0) and this step's W writes
      #pragma unroll
      for (int dj = 0; dj < 5; ++dj){
        half8 a[4], bb[4];
        #pragma unroll
        for (int nt = 0; nt < 4; ++nt){
          int co = nt*16 + mrow;
          bb[nt] = *(const half8*)&wbuf[(dj*64 + co)*40 + quad*8];
        }
        #pragma unroll
        for (int mt = 0; mt < 4; ++mt){
          int p = prow[mt] + di*20 + dj;
          a[mt] = *(const half8*)&Pt[p*40 + quad*8];
        }
        #pragma unroll
        for (int mt = 0; mt < 4; ++mt)
          #pragma unroll
          for (int nt = 0; nt < 4; ++nt)
            acc[mt][nt] = __builtin_amdgcn_mfma_f32_16x16x32_f16(a[mt], bb[nt], acc[mt][nt], 0, 0, 0);
      }
    }
  }

  // epilogue: transpose through LDS (T = Wsm buffer 0), stores into scrambled v5
  #pragma unroll
  for (int hf = 0; hf < 2; ++hf){
    __syncthreads();
    #pragma unroll
    for (int ntl = 0; ntl < 2; ++ntl){
      int nt = hf*2 + ntl;
      int col = ntl*16 + mrow;            // co local within half (0..31)
      #pragma unroll
      for (int mt = 0; mt < 4; ++mt){
        int sbase = wv*64 + mt*16 + quad*4;
        #pragma unroll
        for (int r = 0; r < 4; ++r){
          int s = sbase + r;
          if (s < 196) T[col*200 + s] = acc[mt][nt][r];
        }
      }
    }
    __syncthreads();
    for (int t = tid; t < 6272; t += 256){
      int cl = t / 196;                   // co local 0..31
      int f = (co0 + hf*32)*196 + t;
      float val = T[t + cl*4] + cb[co0 + hf*32 + cl];
      V5[(size_t)b*50176 + (size_t)(f & 255)*196 + (f >> 8)] = val;
    }
  }
}

// ---------- agent token pooling (256 blocks: channel-half x agent-half split) ----------
__global__ __launch_bounds__(256) void k_pool(const float* __restrict__ Y, float* __restrict__ AT, float* __restrict__ ATK){
  int b = blockIdx.x >> 1, half = blockIdx.x & 1;
  int c = (threadIdx.x & 127) + half*128;
  int a0 = (threadIdx.x >> 7) ? 25 : 0;
  int a1 = (threadIdx.x >> 7) ? 49 : 25;
  const float* qp = Y + ((size_t)b*768 + 512 + c)*196;
  const float* kp = Y + ((size_t)b*768 + c)*196;
  for (int a = a0; a < a1; ++a){
    int p1 = a/7, p2 = a - p1*7;
    int s = p1*28 + p2*2;
    float q0 = qp[s], q1 = qp[s+1], q2 = qp[s+14], q3 = qp[s+15];
    AT[((size_t)b*49 + a)*256 + c] = 0.25f*(q0+q1+q2+q3);
    float k0 = kp[s], k1 = kp[s+1], k2 = kp[s+14], k3 = kp[s+15];
    ATK[((size_t)b*49 + a)*256 + c] = fmaxf(fmaxf(k0,k1), fmaxf(k2,k3));
  }
}

// ---------- cbam stage A: per-channel stats, high parallelism (1024 blocks) ----------
// 32 channels per block (8 iters/wave), coalesced float4 + 64-lane shuffle reduce.
__global__ __launch_bounds__(256) void k_cbam_a2(const float* __restrict__ V5,
    float* __restrict__ AVG, float* __restrict__ MX){
  int b = blockIdx.x >> 3, oct = blockIdx.x & 7;
  int tid = threadIdx.x, wv = tid >> 6, lane = tid & 63;
  const float* v5b = V5 + (size_t)b*50176;
  #pragma unroll
  for (int i = 0; i < 8; ++i){
    int c = oct*32 + i*4 + wv;
    float s, m;
    if (lane < 49){
      float4 v = *(const float4*)(v5b + c*196 + lane*4);
      s = v.x + v.y + v.z + v.w;
      m = fmaxf(fmaxf(v.x, v.y), fmaxf(v.z, v.w));
    } else { s = 0.f; m = -1e30f; }
    #pragma unroll
    for (int off = 1; off < 64; off <<= 1){
      s += __shfl_xor(s, off);
      m = fmaxf(m, __shfl_xor(m, off));
    }
    if (lane == 0){
      AVG[b*256 + c] = s*(1.0f/196.0f);
      MX[b*256 + c]  = m;
    }
  }
}

// ---------- cbam stage B: MLP -> chg, spatial mask -> MK. V5 NOT modified ----------
// (the gate chg[c]*v*mk[pos] is applied by k_agentv during its fp16 V staging,
// eliminating the 25.7MB gated write-back + re-read entirely). AVG region is
// overwritten in-place with chg (per-b partition, read-before-write in-block).
__global__ __launch_bounds__(512) void k_cbam_b2(const float* __restrict__ V5,
    float* __restrict__ AVGCHG, const float* __restrict__ MX,
    const float* __restrict__ caa1w, const float* __restrict__ caa1b,
    const float* __restrict__ caa2w, const float* __restrict__ caa2b,
    const float* __restrict__ cam1w, const float* __restrict__ cam1b,
    const float* __restrict__ cam2w, const float* __restrict__ cam2b,
    const float* __restrict__ saw, const float* __restrict__ sab,
    float* __restrict__ MK){
  int b = blockIdx.x;
  __shared__ float avg[256], mx[256], t1[16], t2[16], chg[256];
  __shared__ float sp[2][196], sx[2][196];
  __shared__ float mp[22*22], xp[22*22];
  int tid = threadIdx.x;
  if (tid < 256) avg[tid] = AVGCHG[b*256 + tid];
  else           mx[tid - 256] = MX[b*256 + tid - 256];
  for (int t = tid; t < 484; t += 512){ mp[t] = 0.f; xp[t] = 0.f; }
  __syncthreads();

  if (tid < 16){
    float a1 = caa1b[tid], a2 = cam1b[tid];
    #pragma unroll 4
    for (int k = 0; k < 256; ++k){
      a1 = fmaf(caa1w[(tid*256 + k)*9 + 4], avg[k], a1);   // 3x3 center tap
      a2 = fmaf(cam1w[tid*256 + k], mx[k], a2);            // 1x1
    }
    t1[tid] = fmaxf(a1, 0.f);
    t2[tid] = fmaxf(a2, 0.f);
  }
  __syncthreads();
  if (tid < 256){
    float y1 = caa2b[tid], y2 = cam2b[tid];
    #pragma unroll
    for (int k = 0; k < 16; ++k){
      y1 = fmaf(caa2w[(tid*16 + k)*9 + 4], t1[k], y1);
      y2 = fmaf(cam2w[tid*16 + k], t2[k], y2);
    }
    float g = sigmoidf_(sigmoidf_(y1) + sigmoidf_(y2));
    chg[tid] = g;
    AVGCHG[b*256 + tid] = g;            // chg overwrites avg (avg already in LDS)
  }
  __syncthreads();

  // spatial mean/max over channels, split across 2 half-channel groups
  {
    int g = tid >> 8, pos = tid & 255;
    if (pos < 196){
      const float* vb = V5 + (size_t)b*50176 + pos;
      float s = 0.f, m = -1e30f;
      for (int c = g*128; c < g*128 + 128; ++c){
        float v = chg[c] * vb[c*196];
        s += v; m = fmaxf(m, v);
      }
      sp[g][pos] = s; sx[g][pos] = m;
    }
  }
  __syncthreads();
  if (tid < 196){
    int i = tid/14, j = tid - i*14;
    mp[(i+4)*22 + j+4] = (sp[0][tid] + sp[1][tid])*(1.f/256.f);
    xp[(i+4)*22 + j+4] = fmaxf(sx[0][tid], sx[1][tid]);
  }
  __syncthreads();
  if (tid < 196){
    int i = tid/14, j = tid - i*14;
    float acc = sab[0];
    for (int di = 0; di < 9; ++di){
      #pragma unroll
      for (int dj = 0; dj < 9; ++dj){
        acc = fmaf(mp[(i+di)*22 + j+dj], saw[di*9+dj], acc);
        acc = fmaf(xp[(i+di)*22 + j+dj], saw[81 + di*9+dj], acc);
      }
    }
    MK[(size_t)b*196 + tid] = sigmoidf_(acc);
  }
}

// ---------- big NxN attention via MFMA, 3-segment version (round-6) ----------
__global__ __launch_bounds__(512, 4) void k_attn3(const float* __restrict__ Y,
    const float* __restrict__ rpbt, float* __restrict__ X1S){
  int b = blockIdx.x >> 3, h = blockIdx.x & 7;
  __shared__ __align__(16) ushort_t Qh[208*32];    // fp16 q*SCL rows, chunk-swizzled
  __shared__ __align__(16) ushort_t Kh[208*32];    // fp16 k rows, chunk-swizzled
  __shared__ __align__(16) ushort_t E[80*208];     // fp16 exp-scores [n-local][j]
  __shared__ float rp[736];
  __shared__ int   rpo[208];
  __shared__ float pl2[80][2];                     // lsum halves per row
  __shared__ float invl[80];
  __shared__ float wj[208];
  __shared__ float wpart[8][208];
  __shared__ float xpart[16][32];
  int tid = threadIdx.x, wv = tid >> 6, lane = tid & 63;
  int mrow = lane & 15, quad = lane >> 4;
  int sw8 = ((quad ^ ((mrow >> 1) & 3)) << 3);     // 64B-row read swizzle
  const float* yb = Y + (size_t)b*YSTR;

  for (int t = tid; t < 736; t += 512) rp[t] = (t < 729) ? rpbt[t*8 + h] : 0.f;
  for (int j = tid; j < 208; j += 512){
    int jc = (j < 196) ? j : 195;
    int rj = jc/14;
    rpo[j] = rj*27 + (jc - rj*14);
    wj[j] = 0.f;
  }
  for (int t = tid; t < 384; t += 512){            // zero rows 196..207 of Qh/Kh
    int arr = t >= 192; int u = t - arr*192;
    ((uint_t*)(arr ? Kh : Qh))[3136 + u] = 0;
  }
  for (int t = tid; t < 3136; t += 512){
    int n = t >> 4, w = t & 15;
    int ws = (((w >> 2) ^ ((n >> 1) & 3)) << 2) | (w & 3);
    const float2 qv = *(const float2*)(yb + QOFF + (size_t)n*256 + h*32 + (w << 1));
    ((uint_t*)Qh)[n*16 + ws] = (uint_t)f2h(qv.x*SCL) | ((uint_t)f2h(qv.y*SCL) << 16);
    const float2 kv = *(const float2*)(yb + (size_t)n*256 + h*32 + (w << 1));
    ((uint_t*)Kh)[n*16 + ws] = (uint_t)f2h(kv.x) | ((uint_t)f2h(kv.y) << 16);
  }
  __syncthreads();

  int mt0 = (wv & 1) ? 7 : 0;
  int mt1 = (wv & 1) ? 13 : 7;

  #pragma unroll 1
  for (int seg = 0; seg < 3; ++seg){
    int base = (seg == 0) ? 0 : (seg == 1) ? 80 : 144;
    int ntl  = (seg == 0) ? 5 : 4;
    int segrows = ntl*16;
    int vrows = 196 - base; if (vrows > segrows) vrows = segrows;

    #pragma unroll 1
    for (int ncl = (wv >> 1); ncl < ntl; ncl += 4){
      int n = base + ncl*16 + mrow;
      half8 bfr = *(const half8*)&Qh[n*32 + sw8];
      int nclamp = (n < 196) ? n : 195;
      int rin = nclamp/14, cin = nclamp - rin*14;
      int bidxn = (rin + 13)*27 + (cin + 13);
      float lsum = 0.f;
      #pragma unroll 1
      for (int mt = mt0; mt < mt1; ++mt){
        half8 afr = *(const half8*)&Kh[(mt*16 + mrow)*32 + sw8];
        f32x4 c = (f32x4){0.f,0.f,0.f,0.f};
        c = __builtin_amdgcn_mfma_f32_16x16x32_f16(afr, bfr, c, 0, 0, 0);
        int j0 = mt*16 + quad*4;
        int4 ro = *(const int4*)&rpo[j0];
        short4v pk;
        #pragma unroll
        for (int r = 0; r < 4; ++r){
          int j = j0 + r;
          int roff = (r == 0) ? ro.x : (r == 1) ? ro.y : (r == 2) ? ro.z : ro.w;
          float e = (j < 196) ? __expf(c[r] + rp[bidxn - roff]) : 0.f;
          lsum += e;
          pk[r] = (short)f2h(e);
        }
        if (n < 196) *(short4v*)&E[(n - base)*208 + j0] = pk;
      }
      lsum += __shfl_xor(lsum, 16);
      lsum += __shfl_xor(lsum, 32);
      if (quad == 0) pl2[n - base][wv & 1] = lsum;
    }
    __syncthreads();
    for (int t = tid; t < vrows; t += 512) invl[t] = 1.f/(pl2[t][0] + pl2[t][1]);
    __syncthreads();

    {
      int j0 = lane*4;
      if (j0 < 208){
        float a0=0.f,a1=0.f,a2=0.f,a3=0.f;
        #pragma unroll 1
        for (int nl = wv; nl < vrows; nl += 8){
          float iv = invl[nl];
          short4v ev = *(const short4v*)&E[nl*208 + j0];
          a0 = fmaf(h2f((ushort_t)ev[0]), iv, a0);
          a1 = fmaf(h2f((ushort_t)ev[1]), iv, a1);
          a2 = fmaf(h2f((ushort_t)ev[2]), iv, a2);
          a3 = fmaf(h2f((ushort_t)ev[3]), iv, a3);
        }
        *(f32x4*)&wpart[wv][j0] = (f32x4){a0,a1,a2,a3};
      }
    }
    __syncthreads();
    for (int j = tid; j < 208; j += 512){
      float s = wj[j];
      #pragma unroll
      for (int g = 0; g < 8; ++g) s += wpart[g][j];
      wj[j] = s;
    }
    __syncthreads();   // wpart/E/pl2/invl free for next segment
  }

  {
    int d = tid & 31, g = tid >> 5;                // 16 groups x 13 j's
    float s = 0.f;
    #pragma unroll 1
    for (int u = 0; u < 13; ++u){
      int j = g*13 + u;
      s = fmaf(wj[j], yb[VOFF + (size_t)j*256 + h*32 + d], s);
    }
    xpart[g][d] = s;
  }
  __syncthreads();
  if (tid < 32){
    float s = 0.f;
    #pragma unroll
    for (int g2 = 0; g2 < 16; ++g2) s += xpart[g2][tid];
    X1S[(size_t)b*256 + h*32 + tid] = s*(1.f/196.f);
  }
}

// ---------- chan_inter on x1 mean -> sigmoid gate CMAP ----------
__global__ __launch_bounds__(256) void k_cinter(const float* __restrict__ X1S,
    const float* __restrict__ ci1w, const float* __restrict__ ci1b,
    const float* __restrict__ bng, const float* __restrict__ bnb,
    const float* __restrict__ ci2w, const float* __restrict__ ci2b, float* __restrict__ CMAP){
  int b = blockIdx.x, c = threadIdx.x;
  __shared__ float p[256], tt[16];
  p[c] = X1S[b*256 + c];
  __syncthreads();
  if (c < 16){
    float a = ci1b[c];
    #pragma unroll 4
    for (int k = 0; k < 256; ++k) a = fmaf(ci1w[(c*256+k)*25 + 12], p[k], a);  // 5x5 center
    const float invs = 0.9999950000375f;   // 1/sqrt(1+1e-5)
    tt[c] = fmaxf(fmaf(bng[c]*invs, a, bnb[c]), 0.f);
  }
  __syncthreads();
  float a = ci2b[c];
  #pragma unroll
  for (int k = 0; k < 16; ++k) a = fmaf(ci2w[(c*16+k)*25 + 12], tt[k], a);
  CMAP[b*256 + c] = sigmoidf_(a);
}

// ---------- agent_v via fp16 MFMA ----------
// Kh/Ah rows are 64B (even stride): reads use a bijective chunk swizzle
// chunk ^= (row>>1)&3 (write side mirrors it). Pass-0 V staging applies the
// cbam gate on the fly: Vt = f2h((chg[c]*v)*mk[pos]) -- identical multiply
// order to the old in-place V5 gate, without the global write-back/re-read.
__global__ __launch_bounds__(256) void k_agentv(const float* __restrict__ Y, const float* __restrict__ V5,
    const float* __restrict__ CHG, const float* __restrict__ MK,
    const float* __restrict__ AT, const float* __restrict__ ATK,
    const float* __restrict__ PBT, float* __restrict__ AGV){
  int b = blockIdx.x >> 3, h = blockIdx.x & 7;
  __shared__ __align__(16) ushort_t ST[64*232];   // exp-scores, [a][n pad 232]
  __shared__ __align__(16) ushort_t R[8704];      // staging region (17408 B)
  __shared__ float psum[4*64];
  __shared__ float inv0s[64], inv1s[64];
  __shared__ float mks[196];
  __shared__ float chgs[32];
  int tid = threadIdx.x, wv = tid >> 6, lane = tid & 63;
  int mrow = lane & 15, quad = lane >> 4;
  int sw8 = ((quad ^ ((mrow >> 1) & 3)) << 3);    // read-side chunk swizzle (rows = 16*t + mrow)
  const float* yb = Y + (size_t)b*YSTR;
  ushort_t* Kh = R;            // [208][32] fp16 rows (K or Q), chunk-swizzled
  ushort_t* Ah = R + 6656;     // [64][32] fp16 rows (AT or ATK), chunk-swizzled
  ushort_t* Vt = R;            // [32][232] fp16 rows (V1 or V)
  f32x4 out0[2], out1[2];

  // ---- one-time: gate tables + zero fills of ST cols 208..223 ----
  if (tid < 196) mks[tid] = MK[(size_t)b*196 + tid];
  if (tid >= 224) chgs[tid - 224] = CHG[(size_t)b*256 + h*32 + (tid - 224)];
  for (int t = tid; t < 512; t += 256){      // 64 rows x 16 cols /2 per uint
    int a = t >> 3, c2 = 208 + ((t & 7) << 1);
    *(uint_t*)&ST[a*232 + c2] = 0;
  }

  #pragma unroll 1
  for (int pass = 0; pass < 2; ++pass){
    // ---- stage rows (K|Q into Kh; AT|ATK into Ah), zero pads ----
    for (int t = tid; t < 192; t += 256) ((uint_t*)Kh)[3136 + t] = 0;   // rows 196-207
    for (int t = tid; t < 240; t += 256) ((uint_t*)Ah)[784 + t] = 0;    // rows 49-63
    {
      const float* rsrc = yb + (pass ? QOFF : 0) + h*32;
      for (int t = tid; t < 3136; t += 256){
        int n = t >> 4, w = t & 15;
        const float2 v = *(const float2*)(rsrc + (size_t)n*256 + (w << 1));
        int ws = (((w >> 2) ^ ((n >> 1) & 3)) << 2) | (w & 3);
        ((uint_t*)Kh)[n*16 + ws] = (uint_t)f2h(v.x) | ((uint_t)f2h(v.y) << 16);
      }
      const float* asrc = (pass ? ATK : AT) + (size_t)b*49*256 + h*32;
      for (int t = tid; t < 784; t += 256){
        int a = t >> 4, w = t & 15;
        const float2 v = *(const float2*)(asrc + (size_t)a*256 + (w << 1));
        int ws = (((w >> 2) ^ ((a >> 1) & 3)) << 2) | (w & 3);
        ((uint_t*)Ah)[a*16 + ws] = (uint_t)f2h(v.x) | ((uint_t)f2h(v.y) << 16);
      }
    }
    __syncthreads();
    // ---- logits: ntile = wv; 13 mtiles; exp(+pb) -> ST[a][n] ----
    {
      float lscl = pass ? 0.03125f : SCL;
      int ag = wv*16 + mrow;                 // agent (C col)
      half8 bfr = *(const half8*)&Ah[ag*32 + sw8];
      #pragma unroll 1
      for (int mt = 0; mt < 13; ++mt){
        half8 afr = *(const half8*)&Kh[(mt*16 + mrow)*32 + sw8];
        f32x4 c = (f32x4){0.f,0.f,0.f,0.f};
        c = __builtin_amdgcn_mfma_f32_16x16x32_f16(afr, bfr, c, 0, 0, 0);
        int n0 = mt*16 + quad*4;
        short4v pk;
        #pragma unroll
        for (int r = 0; r < 4; ++r){
          int n = n0 + r;
          float pb = PBT[((size_t)h*196 + n)*49 + ag];
          float e = (n < 196) ? __expf(fmaf(c[r], lscl, pb)) : 0.f;
          pk[r] = (short)f2h(e);
        }
        *(short4v*)&ST[ag*232 + n0] = pk;
      }
    }
    __syncthreads();
    // ---- denominators + stage V ----
    {
      int a = tid >> 2, q = tid & 3;
      float s = 0.f;
      #pragma unroll
      for (int u = 0; u < 7; ++u){
        short8 v8 = *(const short8*)&ST[a*232 + q*56 + u*8];
        #pragma unroll
        for (int e = 0; e < 8; ++e) s += h2f((ushort_t)v8[e]);
      }
      psum[q*64 + a] = s;
    }
    if (pass == 0){
      const float* vsrc = V5 + (size_t)b*50176 + h*32*196;   // [d][196] raw v5
      for (int t = tid; t < 3136; t += 256){
        int d = t / 98, np = t - (t/98)*98;
        const float2 v = *(const float2*)(vsrc + (size_t)d*196 + 2*np);
        float g = chgs[d];
        float a0 = (g*v.x)*mks[2*np];
        float a1 = (g*v.y)*mks[2*np + 1];
        *(uint_t*)&Vt[d*232 + 2*np] = (uint_t)f2h(a0) | ((uint_t)f2h(a1) << 16);
      }
    } else {
      const float* vsrc = yb + VOFF + h*32;                  // [n][256] flat view
      for (int t = tid; t < 3136; t += 256){
        int np = t >> 4, dp = t & 15;
        const float2 v = *(const float2*)(vsrc + (size_t)np*256 + (dp << 1));
        Vt[(2*dp)*232 + np]     = f2h(v.x);
        Vt[(2*dp + 1)*232 + np] = f2h(v.y);
      }
    }
    for (int t = tid; t < 448; t += 256){    // zero V cols 196..223
      int d = t / 14, c2 = 196 + 2*(t - (t/14)*14);
      *(uint_t*)&Vt[d*232 + c2] = 0;
    }
    __syncthreads();
    // ---- PV: mtile = wv (a rows); ntile 0..1 (d cols); 7 k-steps ----
    {
      f32x4* outp = pass ? out1 : out0;
      #pragma unroll
      for (int nt = 0; nt < 2; ++nt){
        f32x4 c = (f32x4){0.f,0.f,0.f,0.f};
        #pragma unroll
        for (int ks = 0; ks < 7; ++ks){
          half8 afr = *(const half8*)&ST[(wv*16 + mrow)*232 + ks*32 + quad*8];
          half8 bfr = *(const half8*)&Vt[(nt*16 + mrow)*232 + ks*32 + quad*8];
          c = __builtin_amdgcn_mfma_f32_16x16x32_f16(afr, bfr, c, 0, 0, 0);
        }
        outp[nt] = c;
      }
      if (tid < 64){
        float s = psum[tid] + psum[64+tid] + psum[128+tid] + psum[192+tid];
        float* invp = pass ? inv1s : inv0s;
        invp[tid] = 1.f / s;
      }
    }
    __syncthreads();   // ST/Vt free for next pass; inv visible
  }
  // ---- epilogue: combine + scatter ----
  #pragma unroll
  for (int nt = 0; nt < 2; ++nt){
    int d = nt*16 + mrow;
    #pragma unroll
    for (int r = 0; r < 4; ++r){
      int a = wv*16 + quad*4 + r;
      if (a < 49)
        AGV[(((size_t)(b*8 + h)*49) + a)*32 + d] = out0[nt][r]*inv0s[a] + out1[nt][r]*inv1s[a];
    }
  }
}

// ---------- xo1 via fp16 MFMA ----------
__global__ __launch_bounds__(256) void k_xo1(const float* __restrict__ Y,
    const float* __restrict__ AT, const float* __restrict__ ATK,
    const float* __restrict__ AB, const float* __restrict__ AGV, float* __restrict__ XO){
  int b = blockIdx.x >> 3, h = blockIdx.x & 7;
  __shared__ __align__(16) ushort_t ST[208*72];   // exp-scores [n][a pad 72]
  __shared__ __align__(16) ushort_t Kh[208*32];   // Q or K rows fp16, chunk-swizzled
  __shared__ __align__(16) ushort_t Ah[64*32];    // AT or ATK rows fp16, chunk-swizzled
  __shared__ __align__(16) ushort_t AGVt[32*64];  // AGV^T [d][a], chunk-swizzled
  __shared__ float invs[208];
  int tid = threadIdx.x, wv = tid >> 6, lane = tid & 63;
  int mrow = lane & 15, quad = lane >> 4;
  int sw8 = ((quad ^ ((mrow >> 1) & 3)) << 3);    // 64B-row read swizzle
  const float* yb = Y + (size_t)b*YSTR;
  f32x4 acc[4][2];
  #pragma unroll
  for (int i = 0; i < 4; ++i){
    acc[i][0] = (f32x4){0.f,0.f,0.f,0.f};
    acc[i][1] = (f32x4){0.f,0.f,0.f,0.f};
  }

  for (int t = tid; t < 1664; t += 256){
    int rw = t >> 3, c2 = 48 + ((t & 7) << 1);
    *(uint_t*)&ST[rw*72 + c2] = 0;
  }
  {
    const float* agvb = AGV + (size_t)(b*8 + h)*49*32;
    for (int t = tid; t < 2048; t += 256){
      int d = t >> 6, a = t & 63;
      int as = ((((a >> 3) ^ (d & 7)) & 7) << 3) | (a & 7);
      AGVt[d*64 + as] = (a < 49) ? f2h(agvb[a*32 + d]) : (ushort_t)0;
    }
  }

  #pragma unroll 1
  for (int pass = 0; pass < 2; ++pass){
    {
      const float* rsrc = yb + (pass ? 0 : QOFF) + h*32;
      for (int t = tid; t < 3136; t += 256){
        int n = t >> 4, w = t & 15;
        const float2 v = *(const float2*)(rsrc + (size_t)n*256 + (w << 1));
        int ws = (((w >> 2) ^ ((n >> 1) & 3)) << 2) | (w & 3);
        ((uint_t*)Kh)[n*16 + ws] = (uint_t)f2h(v.x) | ((uint_t)f2h(v.y) << 16);
      }
      const float* asrc = (pass ? ATK : AT) + (size_t)b*49*256 + h*32;
      for (int t = tid; t < 784; t += 256){
        int a = t >> 4, w = t & 15;
        const float2 v = *(const float2*)(asrc + (size_t)a*256 + (w << 1));
        int ws = (((w >> 2) ^ ((a >> 1) & 3)) << 2) | (w & 3);
        ((uint_t*)Ah)[a*16 + ws] = (uint_t)f2h(v.x) | ((uint_t)f2h(v.y) << 16);
      }
    }
    __syncthreads();
    {
      float lscl = pass ? SCL : 0.03125f;
      int ag = wv*16 + mrow;
      half8 bfr = *(const half8*)&Ah[ag*32 + sw8];
      #pragma unroll 1
      for (int mt = 0; mt < 13; ++mt){
        half8 afr = *(const half8*)&Kh[(mt*16 + mrow)*32 + sw8];
        f32x4 c = (f32x4){0.f,0.f,0.f,0.f};
        c = __builtin_amdgcn_mfma_f32_16x16x32_f16(afr, bfr, c, 0, 0, 0);
        #pragma unroll
        for (int r = 0; r < 4; ++r){
          int n = mt*16 + quad*4 + r;
          if (n < 196 && ag < 49){
            float e = __expf(fmaf(c[r], lscl, AB[((size_t)h*196 + n)*49 + ag]));
            ST[n*72 + ag] = f2h(e);
          }
        }
      }
    }
    __syncthreads();
    if (tid < 196){
      float s = 0.f;
      #pragma unroll
      for (int u = 0; u < 7; ++u){
        short8 v8 = *(const short8*)&ST[tid*72 + u*8];
        #pragma unroll
        for (int e = 0; e < 8; ++e) s += h2f((ushort_t)v8[e]);
      }
      invs[tid] = 1.f / s;
    }
    __syncthreads();
    {
      int i = 0;
      #pragma unroll 1
      for (int mt = wv; mt < 13; mt += 4, ++i){
        #pragma unroll
        for (int nt = 0; nt < 2; ++nt){
          f32x4 c = (f32x4){0.f,0.f,0.f,0.f};
          #pragma unroll
          for (int ks = 0; ks < 2; ++ks){
            half8 afr = *(const half8*)&ST[(mt*16 + mrow)*72 + ks*32 + quad*8];
            half8 bfr = *(const half8*)&AGVt[(nt*16 + mrow)*64 + ((((ks*4 + quad) ^ (mrow & 7)) & 7) << 3)];
            c = __builtin_amdgcn_mfma_f32_16x16x32_f16(afr, bfr, c, 0, 0, 0);
          }
          #pragma unroll
          for (int r = 0; r < 4; ++r){
            int n = mt*16 + quad*4 + r;
            if (n < 196) acc[i][nt][r] = fmaf(c[r], invs[n], acc[i][nt][r]);
          }
        }
      }
    }
    __syncthreads();
  }
  {
    int i = 0;
    #pragma unroll 1
    for (int mt = wv; mt < 13; mt += 4, ++i){
      #pragma unroll
      for (int nt = 0; nt < 2; ++nt){
        #pragma unroll
        for (int r = 0; r < 4; ++r){
          int n = mt*16 + quad*4 + r;
          if (n < 196)
            XO[((size_t)b*196 + n)*256 + h*32 + nt*16 + mrow] = acc[i][nt][r];
        }
      }
    }
  }
}

// ---------- fused depthwise conv: dwc(conv_x2 + qc), bias 2*dwc_b, accumulated into XO ----------
__global__ __launch_bounds__(256) void k_dwc(const float* __restrict__ Y, const float* __restrict__ CMAP,
    const float* __restrict__ dw, const float* __restrict__ db, float* __restrict__ XO){
  int b = blockIdx.x >> 3, cg = blockIdx.x & 7;
  int c0 = cg*32;
  __shared__ __align__(16) float pl[32*360];
  int tid = threadIdx.x;
  for (int t = tid; t < 32*360; t += 256) pl[t] = 0.f;
  __syncthreads();
  const float* yq = Y + (size_t)b*YSTR + QOFF;
  for (int t = tid; t < 32*196; t += 256){
    int cl = t & 31, s = t >> 5;
    int c = c0 + cl;
    int G = s*256 + c;                 // head-major flat index for conv_x2's scramble
    int hh = G / 6272;
    int rem = G - hh*6272;
    int n = rem >> 5, d = rem & 31;
    float cx2 = CMAP[b*256 + c] * yq[n*256 + hh*32 + d];   // sigmoid(cmap)*qs
    float qc  = yq[G];                                     // qc collapses to identity gather
    float v = SCL*(cx2 + qc);
    int i = s/14, j = s - i*14;
    pl[cl*360 + (i+2)*20 + j + 2] = v;
  }
  __syncthreads();
  for (int t = tid; t < 32*14; t += 256){
    int cl = t/14, r = t - cl*14;
    int c = c0 + cl;
    float w25[25];
    #pragma unroll
    for (int u = 0; u < 25; ++u) w25[u] = dw[c*25 + u];
    float acc[14];
    float b2 = 2.f*db[c];
    #pragma unroll
    for (int j = 0; j < 14; ++j) acc[j] = b2;
    conv5x5_row(&pl[cl*360], r, w25, acc);
    float* dst = XO + ((size_t)b*196 + r*14)*256 + c;
    #pragma unroll
    for (int j = 0; j < 14; ++j) dst[j*256] += acc[j];
  }
}

// ---------- final projection: out = XO @ proj_w^T + proj_b ----------
__global__ __launch_bounds__(256) void k_proj(const float* __restrict__ XO, const float* __restrict__ WT,
    const float* __restrict__ pbias, float* __restrict__ OUT){
  int bb = blockIdx.x / 7, nt = blockIdx.x % 7;
  int n0 = nt*28;
  int c = threadIdx.x;
  const float* xb = XO + ((size_t)bb*196 + n0)*256;
  float acc[28];
  #pragma unroll
  for (int r = 0; r < 28; ++r) acc[r] = 0.f;
  for (int k = 0; k < 256; k += 4){
    float w0 = WT[(k+0)*256 + c];
    float w1 = WT[(k+1)*256 + c];
    float w2 = WT[(k+2)*256 + c];
    float w3 = WT[(k+3)*256 + c];
    #pragma unroll
    for (int r = 0; r < 28; ++r){
      float4 xv = *(const float4*)(xb + r*256 + k);   // uniform address -> scalar/L1 path
      acc[r] = fmaf(xv.x, w0, fmaf(xv.y, w1, fmaf(xv.z, w2, fmaf(xv.w, w3, acc[r]))));
    }
  }
  float bv = pbias[c];
  float* dst = OUT + ((size_t)bb*196 + n0)*256 + c;
  #pragma unroll
  for (int r = 0; r < 28; ++r) dst[r*256] = acc[r] + bv;
}

extern "C" void kernel_launch(void* const* d_in, const int* in_sizes, int n_in,
                              void* d_out, int out_size, void* d_ws, size_t ws_size,
                              hipStream_t stream){
  (void)in_sizes; (void)n_in; (void)out_size; (void)ws_size;
  const float* x       = (const float*)d_in[0];
  const float* lka_w   = (const float*)d_in[3];
  const float* lka_b   = (const float*)d_in[4];
  const float* conv5_w = (const float*)d_in[5];
  const float* conv5_b = (const float*)d_in[6];
  const float* caa1_w  = (const float*)d_in[7];
  const float* caa1_b  = (const float*)d_in[8];
  const float* caa2_w  = (const float*)d_in[9];
  const float* caa2_b  = (const float*)d_in[10];
  const float* cam1_w  = (const float*)d_in[11];
  const float* cam1_b  = (const float*)d_in[12];
  const float* cam2_w  = (const float*)d_in[13];
  const float* cam2_b  = (const float*)d_in[14];
  const float* sa_w    = (const float*)d_in[15];
  const float* sa_b    = (const float*)d_in[16];
  const float* ci1_w   = (const float*)d_in[17];
  const float* ci1_b   = (const float*)d_in[18];
  const float* bn_g    = (const float*)d_in[19];
  const float* bn_b    = (const float*)d_in[20];
  const float* ci2_w   = (const float*)d_in[21];
  const float* ci2_b   = (const float*)d_in[22];
  const float* rpbt    = (const float*)d_in[23];
  const float* an_bias = (const float*)d_in[24];
  const float* na_bias = (const float*)d_in[25];
  const float* ah_bias = (const float*)d_in[26];
  const float* aw_bias = (const float*)d_in[27];
  const float* ha_bias = (const float*)d_in[28];
  const float* wa_bias = (const float*)d_in[29];
  const float* dwc_w   = (const float*)d_in[30];
  const float* dwc_b   = (const float*)d_in[31];
  const float* proj_w  = (const float*)d_in[32];
  const float* proj_b  = (const float*)d_in[33];
  float* out = (float*)d_out;
  float* ws = (float*)d_ws;

  float* Y    = ws + WS_Y;
  float* V5   = ws + WS_V5;
  float* AT   = ws + WS_AT;
  float* ATK  = ws + WS_ATK;
  float* CHG  = ws + WS_CHG;   // avg, then chg in-place
  float* CMAP = ws + WS_CMAP;
  float* PBT  = ws + WS_PBT;
  float* AB   = ws + WS_AB;
  float* X1S  = ws + WS_X1S;
  float* AGV  = ws + WS_AGV;
  float* XO   = ws + WS_XO;
  float* WT   = ws + WS_WT;
  ushort_t* Wh = (ushort_t*)(ws + WS_CWT);
  float* MXp  = ws + WS_MX;
  float* MKp  = ws + WS_MK;

  k_pbab <<<602, 256, 0, stream>>>(an_bias, ah_bias, aw_bias, na_bias, ha_bias, wa_bias, PBT, AB);
  k_wprep<<<1056, 256, 0, stream>>>(conv5_w, Wh, proj_w, WT);
  k_lka  <<<1024, 256, 0, stream>>>(x, lka_w, lka_b, Y);
  k_conv5<<<512, 256, 0, stream>>>(Y, Wh, conv5_b, V5);
  k_pool <<<256, 256, 0, stream>>>(Y, AT, ATK);
  k_cbam_a2<<<1024, 256, 0, stream>>>(V5, CHG, MXp);
  k_cbam_b2<<<128, 512, 0, stream>>>(V5, CHG, MXp, caa1_w, caa1_b, caa2_w, caa2_b,
                                     cam1_w, cam1_b, cam2_w, cam2_b, sa_w, sa_b, MKp);
  k_attn3<<<1024, 512, 0, stream>>>(Y, rpbt, X1S);
  k_cinter<<<128, 256, 0, stream>>>(X1S, ci1_w, ci1_b, bn_g, bn_b, ci2_w, ci2_b, CMAP);
  k_agentv<<<1024, 256, 0, stream>>>(Y, V5, CHG, MKp, AT, ATK, PBT, AGV);
  k_xo1  <<<1024, 256, 0, stream>>>(Y, AT, ATK, AB, AGV, XO);
  k_dwc  <<<1024, 256, 0, stream>>>(Y, CMAP, dwc_w, dwc_b, XO);
  k_proj <<<896, 256, 0, stream>>>(XO, WT, proj_b, out);
}